// Round 3
// baseline (4785.955 us; speedup 1.0000x reference)
//
#include <hip/hip_runtime.h>
#include <cstdint>
#include <cstddef>

namespace {

constexpr int B = 16, S = 768, BS = B * S, D = 512, FF = 2048, L = 6;
constexpr float EPS = 1e-5f;

typedef float f32x4 __attribute__((ext_vector_type(4)));
typedef short bf16x8 __attribute__((ext_vector_type(8)));

__device__ __forceinline__ float wave_sum(float v) {
#pragma unroll
  for (int o = 32; o > 0; o >>= 1) v += __shfl_xor(v, o, 64);
  return v;
}

// ---- bf16 split helpers (RTNE) ------------------------------------------
__device__ __forceinline__ short bfhi(float x) {
  uint32_t u = __float_as_uint(x);
  u += 0x7fffu + ((u >> 16) & 1u);
  return (short)(u >> 16);
}
__device__ __forceinline__ float bf2f(short h) {
  return __uint_as_float(((uint32_t)(unsigned short)h) << 16);
}
__device__ __forceinline__ void split_bf(float x, short& hi, short& lo) {
  hi = bfhi(x);
  lo = bfhi(x - bf2f(hi));
}

// ---- async global->LDS, 16B per lane ------------------------------------
__device__ __forceinline__ void gload16(const void* g, void* l) {
  __builtin_amdgcn_global_load_lds(
      (const __attribute__((address_space(1))) void*)g,
      (__attribute__((address_space(3))) void*)l, 16, 0, 0);
}

// Bank-conflict swizzle: LDS tile [rows][4 slots of 16B]; slot ^= (row>>1)&3.
// Stagers fetch the swizzled global column so LDS dest stays linear (rule #21:
// source permutation == read permutation, both-sides-or-neither).
__device__ __forceinline__ int swz_slot(int row, int sl) {
  return sl ^ ((row >> 1) & 3);
}

// =========================================================================
// Split-bf16 GEMM, merged segments.  A: (M,2K) [hi(K)|lo(K)] row-major.
// Wt: (N,2K) [hi|lo] (B^T, N-major).  acc += aH*bH + aL*bH + aH*bL.
// Tile 128x128, BK=32, 4 waves; 48 MFMA per barrier-pair.
// OMODE 0: C=f32 (+resid); OMODE 1: split-pack to ph/pl.
// =========================================================================
template <bool RELU, int OMODE>
__global__ __launch_bounds__(256) void gemm_sp3(
    const short* __restrict__ A, const short* __restrict__ Wt, int K,
    const float* __restrict__ bias, const float* __restrict__ resid, int ldr,
    int rmod, float* __restrict__ C, int ldc, short* __restrict__ ph,
    short* __restrict__ pl, int ldp) {
  __shared__ alignas(16) short sAh[4096], sAl[4096], sBh[4096], sBl[4096];
  const int tid = threadIdx.x;
  // bijective XCD swizzle (nwg % 8 == 0 for all our grids)
  const unsigned Nt = gridDim.x;
  const unsigned lin = blockIdx.y * Nt + blockIdx.x;
  const unsigned cpx = (Nt * gridDim.y) >> 3;
  const unsigned swz = (lin & 7) * cpx + (lin >> 3);
  const int bn = (int)(swz % Nt) * 128, bm = (int)(swz / Nt) * 128;
  const int wave = tid >> 6, lane = tid & 63;
  const int wr = (wave >> 1) * 64, wc = (wave & 1) * 64;
  const int lr = lane & 15, sl = lane >> 4;
  const int str = tid >> 2, ssl = tid & 3;
  const int lda = 2 * K;
  const short* Ab = A + (size_t)bm * lda;
  const short* Wb = Wt + (size_t)bn * lda;
  f32x4 acc[4][4] = {};
  for (int k0 = 0; k0 < K; k0 += 32) {
#pragma unroll
    for (int i = 0; i < 2; ++i) {
      const int row = i * 64 + str;
      const int cs = swz_slot(row, ssl) * 8;
      const size_t ro = (size_t)row * lda + k0 + cs;
      const int dst = (i * 256 + tid) * 8;
      gload16(Ab + ro, &sAh[dst]);
      gload16(Ab + ro + K, &sAl[dst]);
      gload16(Wb + ro, &sBh[dst]);
      gload16(Wb + ro + K, &sBl[dst]);
    }
    __syncthreads();
    bf16x8 aH[4], aL[4], bH[4], bL[4];
#pragma unroll
    for (int m = 0; m < 4; ++m) {
      const int r = wr + m * 16 + lr;
      const int o = r * 32 + swz_slot(r, sl) * 8;
      aH[m] = *(const bf16x8*)&sAh[o];
      aL[m] = *(const bf16x8*)&sAl[o];
    }
#pragma unroll
    for (int n = 0; n < 4; ++n) {
      const int r = wc + n * 16 + lr;
      const int o = r * 32 + swz_slot(r, sl) * 8;
      bH[n] = *(const bf16x8*)&sBh[o];
      bL[n] = *(const bf16x8*)&sBl[o];
    }
#pragma unroll
    for (int m = 0; m < 4; ++m)
#pragma unroll
      for (int n = 0; n < 4; ++n)
        acc[m][n] = __builtin_amdgcn_mfma_f32_16x16x32_bf16(aH[m], bH[n],
                                                            acc[m][n], 0, 0, 0);
#pragma unroll
    for (int m = 0; m < 4; ++m)
#pragma unroll
      for (int n = 0; n < 4; ++n)
        acc[m][n] = __builtin_amdgcn_mfma_f32_16x16x32_bf16(aL[m], bH[n],
                                                            acc[m][n], 0, 0, 0);
#pragma unroll
    for (int m = 0; m < 4; ++m)
#pragma unroll
      for (int n = 0; n < 4; ++n)
        acc[m][n] = __builtin_amdgcn_mfma_f32_16x16x32_bf16(aH[m], bL[n],
                                                            acc[m][n], 0, 0, 0);
    __syncthreads();
  }
  const int r4 = sl * 4;
#pragma unroll
  for (int m = 0; m < 4; ++m) {
#pragma unroll
    for (int r = 0; r < 4; ++r) {
      const int mm = bm + wr + m * 16 + r4 + r;
#pragma unroll
      for (int n = 0; n < 4; ++n) {
        const int col = bn + wc + n * 16 + lr;
        float v = acc[m][n][r] + bias[col];
        if (RELU) v = fmaxf(v, 0.f);
        if (OMODE == 0) {
          if (resid) {
            const int rr = rmod ? (mm % rmod) : mm;
            v += resid[(size_t)rr * ldr + col];
          }
          C[(size_t)mm * ldc + col] = v;
        } else {
          short hi, lo;
          split_bf(v, hi, lo);
          ph[(size_t)mm * ldp + col] = hi;
          pl[(size_t)mm * ldp + col] = lo;
        }
      }
    }
  }
}

// =========================================================================
// Fused multi-scale conv: all 4 scales + alpha mix + cb + residual, one pass.
// Per z: flat-K GEMM, K = 3 taps x 512, tap row-shift applied at staging.
// out = h + sum_z alpha[b,z]*(conv_z + cb_z).
// =========================================================================
__global__ __launch_bounds__(256) void conv_fused_k(
    const short* __restrict__ hp, const short* __restrict__ wt,
    const float* __restrict__ hres, const float* __restrict__ cb,
    const float* __restrict__ alpha, const short* __restrict__ zpadS,
    float* __restrict__ out) {
  __shared__ alignas(16) short sAh[4096], sAl[4096], sBh[4096], sBl[4096];
  const int tid = threadIdx.x;
  const unsigned lin = blockIdx.x;                 // 384 = 96 bm x 4 bn
  const unsigned swz = (lin & 7) * 48 + (lin >> 3);  // XCD-contiguous
  const int bn = (int)(swz & 3) * 128;
  const int bmt = (int)(swz >> 2);                 // 0..95
  const int b = bmt / 6;
  const int s0 = (bmt % 6) * 128;
  const int gm0 = bmt * 128;
  const int wave = tid >> 6, lane = tid & 63;
  const int wr = (wave >> 1) * 64, wc = (wave & 1) * 64;
  const int lr = lane & 15, sl = lane >> 4;
  const int str = tid >> 2, ssl = tid & 3;
  const short* hb = hp + (size_t)b * S * 1024;
  f32x4 accF[4][4] = {};
  for (int z = 0; z < 4; ++z) {
    f32x4 acc[4][4] = {};
    for (int kk = 0; kk < 1536; kk += 32) {
      const int tap = kk >> 9;
      const int koff = kk & 511;
      const int off = (tap - 1) << z;
#pragma unroll
      for (int i = 0; i < 2; ++i) {
        const int row = i * 64 + str;
        const int cs = swz_slot(row, ssl) * 8;
        const int gs = s0 + row + off;
        const bool inb = ((unsigned)gs < (unsigned)S);
        const short* base = hb + (size_t)gs * 1024 + koff + cs;
        const short* gaH = inb ? base : zpadS;
        const short* gaL = inb ? base + 512 : zpadS;
        const short* gw =
            wt + ((size_t)((z * 3 + tap) * 512 + bn + row)) * 1024 + koff + cs;
        const int dst = (i * 256 + tid) * 8;
        gload16(gaH, &sAh[dst]);
        gload16(gaL, &sAl[dst]);
        gload16(gw, &sBh[dst]);
        gload16(gw + 512, &sBl[dst]);
      }
      __syncthreads();
      bf16x8 aH[4], aL[4], bH[4], bL[4];
#pragma unroll
      for (int m = 0; m < 4; ++m) {
        const int r = wr + m * 16 + lr;
        const int o = r * 32 + swz_slot(r, sl) * 8;
        aH[m] = *(const bf16x8*)&sAh[o];
        aL[m] = *(const bf16x8*)&sAl[o];
      }
#pragma unroll
      for (int n = 0; n < 4; ++n) {
        const int r = wc + n * 16 + lr;
        const int o = r * 32 + swz_slot(r, sl) * 8;
        bH[n] = *(const bf16x8*)&sBh[o];
        bL[n] = *(const bf16x8*)&sBl[o];
      }
#pragma unroll
      for (int m = 0; m < 4; ++m)
#pragma unroll
        for (int n = 0; n < 4; ++n)
          acc[m][n] = __builtin_amdgcn_mfma_f32_16x16x32_bf16(
              aH[m], bH[n], acc[m][n], 0, 0, 0);
#pragma unroll
      for (int m = 0; m < 4; ++m)
#pragma unroll
        for (int n = 0; n < 4; ++n)
          acc[m][n] = __builtin_amdgcn_mfma_f32_16x16x32_bf16(
              aL[m], bH[n], acc[m][n], 0, 0, 0);
#pragma unroll
      for (int m = 0; m < 4; ++m)
#pragma unroll
        for (int n = 0; n < 4; ++n)
          acc[m][n] = __builtin_amdgcn_mfma_f32_16x16x32_bf16(
              aH[m], bL[n], acc[m][n], 0, 0, 0);
      __syncthreads();
    }
    const float al = alpha[b * 4 + z];
#pragma unroll
    for (int n = 0; n < 4; ++n) {
      const float cbv = cb[z * D + bn + wc + n * 16 + lr];
#pragma unroll
      for (int m = 0; m < 4; ++m)
#pragma unroll
        for (int r = 0; r < 4; ++r)
          accF[m][n][r] += al * (acc[m][n][r] + cbv);
    }
  }
  const int r4 = sl * 4;
#pragma unroll
  for (int m = 0; m < 4; ++m)
#pragma unroll
    for (int r = 0; r < 4; ++r) {
      const int mm = gm0 + wr + m * 16 + r4 + r;
#pragma unroll
      for (int n = 0; n < 4; ++n) {
        const int col = bn + wc + n * 16 + lr;
        out[(size_t)mm * D + col] =
            accF[m][n][r] + hres[(size_t)mm * D + col];
      }
    }
}

// ---- fused pack (h -> [hi|lo]) + partial column sums (8 x 96 rows) -------
__global__ __launch_bounds__(256) void pack_stats_k(
    const float* __restrict__ x, short* __restrict__ pk,
    float* __restrict__ part) {
  const int b = blockIdx.x, c = blockIdx.y;
  const int s0 = c * 96;
  for (int d = threadIdx.x; d < D; d += 256) {
    float s = 0.f;
    for (int si = 0; si < 96; ++si) {
      const size_t row = (size_t)b * S + s0 + si;
      const float v = x[row * D + d];
      s += v;
      short hi, lo;
      split_bf(v, hi, lo);
      short* o = pk + row * 1024;
      o[d] = hi;
      o[D + d] = lo;
    }
    part[((size_t)b * 8 + c) * D + d] = s;
  }
}

// ---- W-pack: (K,N) f32 -> (N,2K) [hi|lo] (B^T layout) --------------------
__global__ __launch_bounds__(256) void pack_w_k(const float* __restrict__ W,
                                                short* __restrict__ out,
                                                int K, int N, int ln2N) {
  const int idx = blockIdx.x * 256 + threadIdx.x;
  const int n = idx & (N - 1), k = idx >> ln2N;
  if (k >= K) return;
  short hi, lo;
  split_bf(W[(size_t)k * N + n], hi, lo);
  out[(size_t)n * 2 * K + k] = hi;
  out[(size_t)n * 2 * K + K + k] = lo;
}

// ---- conv W-pack: (4,O,I,3) -> (12=[z*3+t], O, [hi(I)|lo(I)]) ------------
__global__ __launch_bounds__(256) void pack_convw_k(
    const float* __restrict__ cw, short* __restrict__ out) {
  const int idx = blockIdx.x * 256 + threadIdx.x;  // 12*512*512
  const int c = idx & 511, o = (idx >> 9) & 511, seg = idx >> 18;
  const int i = seg / 3, t = seg % 3;
  short hi, lo;
  split_bf(cw[(((size_t)i * D + o) * D + c) * 3 + t], hi, lo);
  short* dst = out + ((size_t)seg * D + o) * 1024;
  dst[c] = hi;
  dst[D + c] = lo;
}

// ---- zero page for conv OOB rows ----------------------------------------
__global__ __launch_bounds__(256) void zero_k(float* __restrict__ p) {
  p[threadIdx.x] = 0.f;
  p[threadIdx.x + 256] = 0.f;
}

// ---- fused LN1 -> LN2 (h1 feeds only LN2; SSM y cancels) -----------------
__global__ __launch_bounds__(256) void ln_fused_k(
    const float* __restrict__ x, const float* __restrict__ g1,
    const float* __restrict__ b1, const float* __restrict__ g2,
    const float* __restrict__ b2, float* __restrict__ fout,
    short* __restrict__ pout) {
  const int row = blockIdx.x * 4 + (threadIdx.x >> 6);
  const int lane = threadIdx.x & 63;
  const float* xr = x + (size_t)row * D;
  float v[8];
  float s = 0.f;
#pragma unroll
  for (int j = 0; j < 8; ++j) { v[j] = xr[lane + 64 * j]; s += v[j]; }
  s = wave_sum(s);
  const float m1 = s * (1.f / D);
  float q = 0.f;
#pragma unroll
  for (int j = 0; j < 8; ++j) { const float d = v[j] - m1; q += d * d; }
  q = wave_sum(q);
  const float r1 = rsqrtf(q * (1.f / D) + EPS);
  float y[8];
  float s2 = 0.f;
#pragma unroll
  for (int j = 0; j < 8; ++j) {
    const int c = lane + 64 * j;
    y[j] = (v[j] - m1) * r1 * g1[c] + b1[c];
    s2 += y[j];
  }
  s2 = wave_sum(s2);
  const float m2 = s2 * (1.f / D);
  float q2 = 0.f;
#pragma unroll
  for (int j = 0; j < 8; ++j) { const float d = y[j] - m2; q2 += d * d; }
  q2 = wave_sum(q2);
  const float r2 = rsqrtf(q2 * (1.f / D) + EPS);
  float* frow = fout + (size_t)row * D;
  short* prow = pout + (size_t)row * 1024;
#pragma unroll
  for (int j = 0; j < 8; ++j) {
    const int c = lane + 64 * j;
    const float o = (y[j] - m2) * r2 * g2[c] + b2[c];
    frow[c] = o;
    short hi, lo;
    split_bf(o, hi, lo);
    prow[c] = hi;
    prow[D + c] = lo;
  }
}

// ---- partial column sums over S for the head -----------------------------
__global__ __launch_bounds__(256) void colmean_part_k(
    const float* __restrict__ x, float* __restrict__ part) {
  const int b = blockIdx.x, c = blockIdx.y;
  const int s0 = c * 96;
  for (int d = threadIdx.x; d < D; d += 256) {
    float s = 0.f;
    for (int si = 0; si < 96; ++si)
      s += x[((size_t)b * S + s0 + si) * D + d];
    part[((size_t)b * 8 + c) * D + d] = s;
  }
}

// ---- alpha = softmax(mean_s(h) @ wmw + wmb) ------------------------------
__global__ __launch_bounds__(64) void alpha_k(const float* __restrict__ part,
                                              const float* __restrict__ wmw,
                                              const float* __restrict__ wmb,
                                              float* __restrict__ alpha) {
  const int b = blockIdx.x, t = threadIdx.x;
  float p0 = 0, p1 = 0, p2 = 0, p3 = 0;
  for (int d = t; d < D; d += 64) {
    float xm = 0;
#pragma unroll
    for (int c = 0; c < 8; ++c) xm += part[((size_t)b * 8 + c) * D + d];
    xm *= (1.f / S);
    p0 += xm * wmw[d * 4 + 0];
    p1 += xm * wmw[d * 4 + 1];
    p2 += xm * wmw[d * 4 + 2];
    p3 += xm * wmw[d * 4 + 3];
  }
  p0 = wave_sum(p0); p1 = wave_sum(p1);
  p2 = wave_sum(p2); p3 = wave_sum(p3);
  if (t == 0) {
    const float l0 = p0 + wmb[0], l1 = p1 + wmb[1];
    const float l2 = p2 + wmb[2], l3 = p3 + wmb[3];
    const float mx = fmaxf(fmaxf(l0, l1), fmaxf(l2, l3));
    const float e0 = expf(l0 - mx), e1 = expf(l1 - mx);
    const float e2 = expf(l2 - mx), e3 = expf(l3 - mx);
    const float inv = 1.f / (e0 + e1 + e2 + e3);
    alpha[b * 4 + 0] = e0 * inv;
    alpha[b * 4 + 1] = e1 * inv;
    alpha[b * 4 + 2] = e2 * inv;
    alpha[b * 4 + 3] = e3 * inv;
  }
}

// ---- embedding gather-mean, packed out -----------------------------------
__global__ __launch_bounds__(256) void embed_k(const int* __restrict__ xe,
                                               const float* __restrict__ emb,
                                               short* __restrict__ out) {
  const int r = blockIdx.x;
  int idx[8];
#pragma unroll
  for (int j = 0; j < 8; ++j) idx[j] = xe[r * 8 + j];
  short* o = out + (size_t)r * 1024;
  for (int d = threadIdx.x; d < D; d += 256) {
    float s = 0.f;
#pragma unroll
    for (int j = 0; j < 8; ++j) s += emb[(size_t)idx[j] * D + d];
    short hi, lo;
    split_bf(s * 0.125f, hi, lo);
    o[d] = hi;
    o[D + d] = lo;
  }
}

// ---- L2-normalize rows of (BS,64), packed out ----------------------------
__global__ __launch_bounds__(256) void norml2_k(const float* __restrict__ x,
                                                short* __restrict__ out) {
  const int r = blockIdx.x * 4 + (threadIdx.x >> 6);
  const int lane = threadIdx.x & 63;
  const float v = x[(size_t)r * 64 + lane];
  const float s = wave_sum(v * v);
  const float nrm = fmaxf(sqrtf(s), 1e-12f);
  short hi, lo;
  split_bf(v / nrm, hi, lo);
  out[(size_t)r * 128 + lane] = hi;
  out[(size_t)r * 128 + 64 + lane] = lo;
}

// ---- classifier head -----------------------------------------------------
__global__ __launch_bounds__(256) void head_k(
    const float* __restrict__ part, const float* __restrict__ pw1,
    const float* __restrict__ pb1, const float* __restrict__ pw2,
    const float* __restrict__ pb2, float* __restrict__ out) {
  __shared__ float hg[D];
  __shared__ float red[256];
  const int b = blockIdx.x, t = threadIdx.x;
  for (int d = t; d < D; d += 256) {
    float s = 0.f;
#pragma unroll
    for (int c = 0; c < 8; ++c) s += part[((size_t)b * 8 + c) * D + d];
    hg[d] = s * (1.f / S);
  }
  __syncthreads();
  float s = pb1[t];
  for (int d = 0; d < D; ++d) s = fmaf(hg[d], pw1[(size_t)d * 256 + t], s);
  s = fmaxf(s, 0.f);
  red[t] = s * pw2[t];
  __syncthreads();
  for (int o = 128; o > 0; o >>= 1) {
    if (t < o) red[t] += red[t + o];
    __syncthreads();
  }
  if (t == 0) out[b] = red[0] + pb2[0];
}

}  // namespace

extern "C" void kernel_launch(void* const* d_in, const int* in_sizes, int n_in,
                              void* d_out, int out_size, void* d_ws,
                              size_t ws_size, hipStream_t stream) {
  const float* x_cog = (const float*)d_in[0];
  const float* cw1 = (const float*)d_in[1];
  const float* cb1 = (const float*)d_in[2];
  const float* cw2 = (const float*)d_in[3];
  const float* cb2 = (const float*)d_in[4];
  const float* env_emb = (const float*)d_in[5];
  const float* ew1 = (const float*)d_in[6];
  const float* eb1 = (const float*)d_in[7];
  const float* ew2 = (const float*)d_in[8];
  const float* eb2 = (const float*)d_in[9];
  const float* fw1 = (const float*)d_in[10];
  const float* fb1 = (const float*)d_in[11];
  const float* fw2 = (const float*)d_in[12];
  const float* fb2 = (const float*)d_in[13];
  const float* pos_enc = (const float*)d_in[14];
  const float* conv_w = (const float*)d_in[15];
  const float* conv_b = (const float*)d_in[16];
  const float* wm_w = (const float*)d_in[17];
  const float* wm_b = (const float*)d_in[18];
  // d_in[19..21] = ssm_w/ssm_b/A_log: no-ops (y is scalar-per-row; LayerNorm
  // shift invariance cancels it exactly).
  const float* ffw1 = (const float*)d_in[22];
  const float* ffb1 = (const float*)d_in[23];
  const float* ffw2 = (const float*)d_in[24];
  const float* ffb2 = (const float*)d_in[25];
  const float* g1 = (const float*)d_in[26];
  const float* be1 = (const float*)d_in[27];
  const float* g2 = (const float*)d_in[28];
  const float* be2 = (const float*)d_in[29];
  const float* pw1 = (const float*)d_in[30];
  const float* pb1 = (const float*)d_in[31];
  const float* pw2 = (const float*)d_in[32];
  const float* pb2 = (const float*)d_in[33];
  const int* x_env = (const int*)d_in[34];
  float* out = (float*)d_out;

  // ---- workspace arena (same 189.0 MB footprint as round 2) --------------
  float* ws = (float*)d_ws;
  float* Hbuf = ws;                       // 12288x512 f32
  float* TBuf = ws + 6291456;             // 12288x512 f32
  float* PARTb = ws + 2 * 6291456;        // 16x8x512 f32
  float* ALPHAB = PARTb + 65536;          // 64
  float* ZPADF = ALPHAB + 64;             // 512 f32 zero page
  short* WP = (short*)(ZPADF + 512);      // 6,291,456 shorts (W packs)
  short* R1 = WP + 6291456;               // 62,914,560 shorts aliased region
  // frontend phase:
  short* CONC = R1;                       // 12288x2048
  short* PK1 = R1 + 25165824;             // 12288x1024
  short* PK2 = R1 + 37748736;             // 12288x1024
  // layer phase:
  short* APFF = R1;                       // 12288x4096 (FF hidden pack)
  short* HPACK = R1 + 50331648;           // 12288x1024 (h pack; aliases APD)
  short* APD = R1 + 50331648;             // 12288x1024 (h2 pack)

  const dim3 blk(256);
  const dim3 gN4(4, BS / 128);    // N=512
  const dim3 gN16(16, BS / 128);  // N=2048

  zero_k<<<1, blk, 0, stream>>>(ZPADF);

  // ---- frontend -----------------------------------------------------------
  norml2_k<<<BS / 4, blk, 0, stream>>>(x_cog, PK1);
  pack_w_k<<<64 * 512 / 256, blk, 0, stream>>>(cw1, WP, 64, 512, 9);
  gemm_sp3<true, 1><<<gN4, blk, 0, stream>>>(PK1, WP, 64, cb1, nullptr, 0, 0,
                                             nullptr, 0, PK2, PK2 + 512, 1024);
  pack_w_k<<<512 * 512 / 256, blk, 0, stream>>>(cw2, WP, 512, 512, 9);
  gemm_sp3<false, 1><<<gN4, blk, 0, stream>>>(PK2, WP, 512, cb2, nullptr, 0, 0,
                                              nullptr, 0, CONC, CONC + 1024,
                                              2048);
  embed_k<<<BS, blk, 0, stream>>>(x_env, env_emb, PK1);
  pack_w_k<<<512 * 512 / 256, blk, 0, stream>>>(ew1, WP, 512, 512, 9);
  gemm_sp3<true, 1><<<gN4, blk, 0, stream>>>(PK1, WP, 512, eb1, nullptr, 0, 0,
                                             nullptr, 0, PK2, PK2 + 512, 1024);
  pack_w_k<<<512 * 512 / 256, blk, 0, stream>>>(ew2, WP, 512, 512, 9);
  gemm_sp3<false, 1><<<gN4, blk, 0, stream>>>(PK2, WP, 512, eb2, nullptr, 0, 0,
                                              nullptr, 0, CONC + 512,
                                              CONC + 1536, 2048);
  pack_w_k<<<1024 * 512 / 256, blk, 0, stream>>>(fw1, WP, 1024, 512, 9);
  gemm_sp3<true, 1><<<gN4, blk, 0, stream>>>(CONC, WP, 1024, fb1, nullptr, 0,
                                             0, nullptr, 0, PK1, PK1 + 512,
                                             1024);
  pack_w_k<<<512 * 512 / 256, blk, 0, stream>>>(fw2, WP, 512, 512, 9);
  gemm_sp3<false, 0><<<gN4, blk, 0, stream>>>(PK1, WP, 512, fb2, pos_enc, D, S,
                                              Hbuf, D, nullptr, nullptr, 0);

  // ---- layers -------------------------------------------------------------
  for (int l = 0; l < L; ++l) {
    pack_stats_k<<<dim3(B, 8), blk, 0, stream>>>(Hbuf, HPACK, PARTb);
    alpha_k<<<B, dim3(64), 0, stream>>>(PARTb, wm_w + (size_t)l * D * 4,
                                        wm_b + l * 4, ALPHAB);
    pack_convw_k<<<12 * 512 * 512 / 256, blk, 0, stream>>>(
        conv_w + (size_t)l * 4 * D * D * 3, WP);
    conv_fused_k<<<384, blk, 0, stream>>>(HPACK, WP, Hbuf,
                                          conv_b + (size_t)l * 4 * D, ALPHAB,
                                          (const short*)ZPADF, TBuf);
    ln_fused_k<<<BS / 4, blk, 0, stream>>>(TBuf, g1 + l * D, be1 + l * D,
                                           g2 + l * D, be2 + l * D, TBuf, APD);
    pack_w_k<<<512 * 2048 / 256, blk, 0, stream>>>(ffw1 + (size_t)l * D * FF,
                                                   WP, 512, 2048, 11);
    gemm_sp3<true, 1><<<gN16, blk, 0, stream>>>(APD, WP, 512,
                                                ffb1 + (size_t)l * FF, nullptr,
                                                0, 0, nullptr, 0, APFF,
                                                APFF + 2048, 4096);
    pack_w_k<<<2048 * 512 / 256, blk, 0, stream>>>(ffw2 + (size_t)l * FF * D,
                                                   WP, 2048, 512, 9);
    gemm_sp3<false, 0><<<gN4, blk, 0, stream>>>(APFF, WP, 2048,
                                                ffb2 + (size_t)l * D, TBuf, D,
                                                0, Hbuf, D, nullptr, nullptr,
                                                0);
  }

  // ---- head ---------------------------------------------------------------
  colmean_part_k<<<dim3(B, 8), blk, 0, stream>>>(Hbuf, PARTb);
  head_k<<<B, blk, 0, stream>>>(PARTb, pw1, pb1, pw2, pb2, out);
}

// Round 5
// 2327.456 us; speedup vs baseline: 2.0563x; 2.0563x over previous
//
#include <hip/hip_runtime.h>
#include <cstdint>
#include <cstddef>

namespace {

constexpr int B = 16, S = 768, BS = B * S, D = 512, FF = 2048, L = 6;
constexpr float EPS = 1e-5f;

typedef float f32x4 __attribute__((ext_vector_type(4)));
typedef _Float16 f16x8 __attribute__((ext_vector_type(8)));
typedef short short4v __attribute__((ext_vector_type(4)));

__device__ __forceinline__ float wave_sum(float v) {
#pragma unroll
  for (int o = 32; o > 0; o >>= 1) v += __shfl_xor(v, o, 64);
  return v;
}

// ---- fp16 split (RTNE): x ~= hi + lo, each fp16 --------------------------
__device__ __forceinline__ void split_f16(float x, short& hi, short& lo) {
  _Float16 h = (_Float16)x;
  _Float16 l = (_Float16)(x - (float)h);
  hi = __builtin_bit_cast(short, h);
  lo = __builtin_bit_cast(short, l);
}

// ---- async global->LDS, 16B per lane ------------------------------------
__device__ __forceinline__ void gload16(const void* g, void* l) {
  __builtin_amdgcn_global_load_lds(
      (const __attribute__((address_space(1))) void*)g,
      (__attribute__((address_space(3))) void*)l, 16, 0, 0);
}

// LDS tile [128 rows][8 slots of 16B] (BK=64 halfs). Bank fix: global slot
// gsl = sl0 ^ (row&7); LDS stays linear (global_load_lds rule #21: swizzle
// the SOURCE, match on the READ). Read: slot = g ^ (row&7) -> 2-way = free.
// Stage dst byte = granule*16 = wave-base + lane*16  (HW contiguity rule).

// =========================================================================
// Split-fp16 2-product GEMM. A: (M, 2Kfull) [hi|lo] halfs; Wt: (N,Kfull) hi.
// acc += aH*bH + aL*bH  (W-lo dropped: ~2^-12 rel). blockIdx.z = K-split.
// OMODE 1: bias/relu + split-pack to ph/pl. OMODE 2: raw f32 partial to
// C + kz*pstride. Tile 128x128, BK=64, 4 waves, 64 MFMA/barrier-pair/wave.
// =========================================================================
template <bool RELU, int OMODE>
__global__ __launch_bounds__(256, 3) void gemm_h(
    const short* __restrict__ A, int lda, int aLoff,
    const short* __restrict__ Wt, int ldw, int Klen,
    const float* __restrict__ bias, float* __restrict__ C, int ldc,
    ptrdiff_t pstride, short* __restrict__ ph, short* __restrict__ pl,
    int ldp) {
  __shared__ alignas(16) short sAh[8192], sAl[8192], sBh[8192];
  const int tid = threadIdx.x;
  const unsigned Nt = gridDim.x;
  const unsigned lin = blockIdx.y * Nt + blockIdx.x;
  const unsigned cpx = (Nt * gridDim.y) >> 3;
  const unsigned swz = (lin & 7) * cpx + (lin >> 3);
  const int bn = (int)(swz % Nt) * 128, bm = (int)(swz / Nt) * 128;
  const int kz = blockIdx.z;
  const int wave = tid >> 6, lane = tid & 63;
  const int wr = (wave >> 1) * 64, wc = (wave & 1) * 64;
  const int lr = lane & 15, sl = lane >> 4;
  const short* Ab = A + (size_t)bm * lda + (size_t)kz * Klen;
  const short* Wb = Wt + (size_t)bn * ldw + (size_t)kz * Klen;
  f32x4 acc[4][4] = {};
  for (int kk = 0; kk < Klen; kk += 64) {
#pragma unroll
    for (int jj = 0; jj < 4; ++jj) {
      const int G = jj * 256 + tid;
      const int srow = G >> 3, sl0 = G & 7;
      const int gsl = sl0 ^ (srow & 7);
      const int dst = G * 8;
      const size_t ra = (size_t)srow * lda + kk + gsl * 8;
      gload16(Ab + ra, &sAh[dst]);
      gload16(Ab + ra + aLoff, &sAl[dst]);
      gload16(Wb + (size_t)srow * ldw + kk + gsl * 8, &sBh[dst]);
    }
    __syncthreads();
#pragma unroll
    for (int ks = 0; ks < 2; ++ks) {
      f16x8 aH[4], aL[4], bH[4];
#pragma unroll
      for (int m = 0; m < 4; ++m) {
        const int r = wr + m * 16 + lr;
        const int o = r * 64 + (((ks * 4 + sl) ^ (r & 7)) * 8);
        aH[m] = *(const f16x8*)&sAh[o];
        aL[m] = *(const f16x8*)&sAl[o];
      }
#pragma unroll
      for (int n = 0; n < 4; ++n) {
        const int r = wc + n * 16 + lr;
        const int o = r * 64 + (((ks * 4 + sl) ^ (r & 7)) * 8);
        bH[n] = *(const f16x8*)&sBh[o];
      }
#pragma unroll
      for (int m = 0; m < 4; ++m)
#pragma unroll
        for (int n = 0; n < 4; ++n)
          acc[m][n] = __builtin_amdgcn_mfma_f32_16x16x32_f16(aH[m], bH[n],
                                                             acc[m][n], 0, 0, 0);
#pragma unroll
      for (int m = 0; m < 4; ++m)
#pragma unroll
        for (int n = 0; n < 4; ++n)
          acc[m][n] = __builtin_amdgcn_mfma_f32_16x16x32_f16(aL[m], bH[n],
                                                             acc[m][n], 0, 0, 0);
    }
    __syncthreads();
  }
  const int r4 = sl * 4;
#pragma unroll
  for (int m = 0; m < 4; ++m) {
#pragma unroll
    for (int r = 0; r < 4; ++r) {
      const int mm = bm + wr + m * 16 + r4 + r;
#pragma unroll
      for (int n = 0; n < 4; ++n) {
        const int col = bn + wc + n * 16 + lr;
        if (OMODE == 2) {
          (C + (ptrdiff_t)kz * pstride)[(size_t)mm * ldc + col] = acc[m][n][r];
        } else {
          float v = acc[m][n][r] + bias[col];
          if (RELU) v = fmaxf(v, 0.f);
          short hi, lo;
          split_f16(v, hi, lo);
          ph[(size_t)mm * ldp + col] = hi;
          pl[(size_t)mm * ldp + col] = lo;
        }
      }
    }
  }
}

// =========================================================================
// Conv z-pair: block computes 2 scales (zp*2, zp*2+1) over K=3x512 each,
// accF = sum_z alpha[b,z]*(conv_z + cb_z)  ->  P[zp]  (f32 partial).
// grid 768 = 2 zp x 4 bn x 96 bm, bijective XCD swizzle (weights L2-fit).
// =========================================================================
__global__ __launch_bounds__(256, 3) void conv_zp_k(
    const short* __restrict__ hp, const short* __restrict__ wt,
    const float* __restrict__ cb, const float* __restrict__ alpha,
    const short* __restrict__ zpadS, float* __restrict__ P) {
  __shared__ alignas(16) short sAh[8192], sAl[8192], sBh[8192];
  const int tid = threadIdx.x;
  const unsigned lin = blockIdx.x;
  const unsigned swz = (lin & 7) * 96 + (lin >> 3);
  const int zp = (int)(swz / 384);
  const unsigned rem = swz % 384;
  const int bn = (int)(rem & 3) * 128;
  const int bmt = (int)(rem >> 2);
  const int b = bmt / 6, s0 = (bmt % 6) * 128, gm0 = bmt * 128;
  const int wave = tid >> 6, lane = tid & 63;
  const int wr = (wave >> 1) * 64, wc = (wave & 1) * 64;
  const int lr = lane & 15, sl = lane >> 4;
  const short* hb = hp + (size_t)b * S * 1024;
  f32x4 accF[4][4] = {};
#pragma unroll
  for (int zi = 0; zi < 2; ++zi) {
    const int z = zp * 2 + zi;
    f32x4 acc[4][4] = {};
    for (int kk = 0; kk < 1536; kk += 64) {
      const int tap = kk >> 9;
      const int koff = kk & 511;
      const int off = (tap - 1) << z;
#pragma unroll
      for (int jj = 0; jj < 4; ++jj) {
        const int G = jj * 256 + tid;
        const int srow = G >> 3, sl0 = G & 7;
        const int gsl = sl0 ^ (srow & 7);
        const int dst = G * 8;
        const int gs = s0 + srow + off;
        const bool inb = ((unsigned)gs < (unsigned)S);
        const short* aBase = hb + (size_t)gs * 1024 + koff + gsl * 8;
        gload16(inb ? aBase : zpadS, &sAh[dst]);
        gload16(inb ? aBase + 512 : zpadS, &sAl[dst]);
        gload16(wt + ((size_t)((z * 3 + tap) * 512 + bn + srow)) * 512 + koff +
                    gsl * 8,
                &sBh[dst]);
      }
      __syncthreads();
#pragma unroll
      for (int ks = 0; ks < 2; ++ks) {
        f16x8 aH[4], aL[4], bH[4];
#pragma unroll
        for (int m = 0; m < 4; ++m) {
          const int r = wr + m * 16 + lr;
          const int o = r * 64 + (((ks * 4 + sl) ^ (r & 7)) * 8);
          aH[m] = *(const f16x8*)&sAh[o];
          aL[m] = *(const f16x8*)&sAl[o];
        }
#pragma unroll
        for (int n = 0; n < 4; ++n) {
          const int r = wc + n * 16 + lr;
          const int o = r * 64 + (((ks * 4 + sl) ^ (r & 7)) * 8);
          bH[n] = *(const f16x8*)&sBh[o];
        }
#pragma unroll
        for (int m = 0; m < 4; ++m)
#pragma unroll
          for (int n = 0; n < 4; ++n)
            acc[m][n] = __builtin_amdgcn_mfma_f32_16x16x32_f16(
                aH[m], bH[n], acc[m][n], 0, 0, 0);
#pragma unroll
        for (int m = 0; m < 4; ++m)
#pragma unroll
          for (int n = 0; n < 4; ++n)
            acc[m][n] = __builtin_amdgcn_mfma_f32_16x16x32_f16(
                aL[m], bH[n], acc[m][n], 0, 0, 0);
      }
      __syncthreads();
    }
    const float al = alpha[b * 4 + z];
#pragma unroll
    for (int n = 0; n < 4; ++n) {
      const float cbv = cb[z * D + bn + wc + n * 16 + lr];
#pragma unroll
      for (int m = 0; m < 4; ++m)
#pragma unroll
        for (int r = 0; r < 4; ++r)
          accF[m][n][r] += al * (acc[m][n][r] + cbv);
    }
  }
  float* Pz = P + (size_t)zp * ((size_t)BS * D);
  const int r4 = sl * 4;
#pragma unroll
  for (int m = 0; m < 4; ++m)
#pragma unroll
    for (int r = 0; r < 4; ++r) {
      const int mm = gm0 + wr + m * 16 + r4 + r;
#pragma unroll
      for (int n = 0; n < 4; ++n)
        Pz[(size_t)mm * D + bn + wc + n * 16 + lr] = accF[m][n][r];
    }
}

// ---- combine: v = P0+P1+bias; relu?; +resid?; -> f32 and/or fp16 pack ----
template <bool RELU, bool PACK, bool FOUT>
__global__ __launch_bounds__(256) void comb2_k(
    const float* __restrict__ P0, const float* __restrict__ P1,
    const float* __restrict__ bias, const float* __restrict__ resid, int ldr,
    int rmod, float* __restrict__ fout, short* __restrict__ ph,
    short* __restrict__ pl, int ldp, int ln2N) {
  const size_t e = ((size_t)blockIdx.x * 256 + threadIdx.x) * 4;
  const int col = (int)(e & ((1u << ln2N) - 1));
  const size_t row = e >> ln2N;
  f32x4 v = *(const f32x4*)(P0 + e);
  const f32x4 w = *(const f32x4*)(P1 + e);
  const f32x4 bb = *(const f32x4*)(bias + col);
#pragma unroll
  for (int j = 0; j < 4; ++j) {
    v[j] += w[j] + bb[j];
    if (RELU) v[j] = fmaxf(v[j], 0.f);
  }
  if (resid) {
    const size_t rr = rmod ? (row % (size_t)rmod) : row;
    const f32x4 rv = *(const f32x4*)(resid + rr * ldr + col);
#pragma unroll
    for (int j = 0; j < 4; ++j) v[j] += rv[j];
  }
  if (FOUT) *(f32x4*)(fout + e) = v;
  if (PACK) {
    short4v h4, l4;
#pragma unroll
    for (int j = 0; j < 4; ++j) {
      short hh, ll;
      split_f16(v[j], hh, ll);
      h4[j] = hh;
      l4[j] = ll;
    }
    *(short4v*)(ph + row * ldp + col) = h4;
    *(short4v*)(pl + row * ldp + col) = l4;
  }
}

// ---- fused pack (h -> fp16 [hi|lo]) + partial column sums ----------------
__global__ __launch_bounds__(256) void pack_stats_k(
    const float* __restrict__ x, short* __restrict__ pk,
    float* __restrict__ part) {
  const int b = blockIdx.x, c = blockIdx.y;
  const int s0 = c * 96;
  for (int d = threadIdx.x; d < D; d += 256) {
    float s = 0.f;
    for (int si = 0; si < 96; ++si) {
      const size_t row = (size_t)b * S + s0 + si;
      const float v = x[row * D + d];
      s += v;
      short hi, lo;
      split_f16(v, hi, lo);
      short* o = pk + row * 1024;
      o[d] = hi;
      o[D + d] = lo;
    }
    part[((size_t)b * 8 + c) * D + d] = s;
  }
}

// ---- W-pack hi-only: (K,N) f32 -> (N,K) fp16 bits ------------------------
__global__ __launch_bounds__(256) void pack_wh_k(const float* __restrict__ W,
                                                 short* __restrict__ out,
                                                 int K, int N, int ln2N) {
  const int idx = blockIdx.x * 256 + threadIdx.x;
  const int n = idx & (N - 1), k = idx >> ln2N;
  if (k >= K) return;
  const _Float16 h = (_Float16)W[(size_t)k * N + n];
  out[(size_t)n * K + k] = __builtin_bit_cast(short, h);
}

// ---- conv W-pack hi-only: (4,O,I,3) -> (12, O, I) fp16 bits --------------
__global__ __launch_bounds__(256) void pack_convw_k(
    const float* __restrict__ cw, short* __restrict__ out) {
  const int idx = blockIdx.x * 256 + threadIdx.x;  // 12*512*512
  const int c = idx & 511, o = (idx >> 9) & 511, seg = idx >> 18;
  const int i = seg / 3, t = seg % 3;
  const _Float16 h = (_Float16)cw[(((size_t)i * D + o) * D + c) * 3 + t];
  out[((size_t)seg * D + o) * D + c] = __builtin_bit_cast(short, h);
}

__global__ __launch_bounds__(256) void zero_k(float* __restrict__ p) {
  p[threadIdx.x] = 0.f;
  p[threadIdx.x + 256] = 0.f;
}

// ---- fused LN1 -> LN2 (SSM y cancels by LN shift-invariance) -------------
__global__ __launch_bounds__(256) void ln_fused_k(
    const float* __restrict__ x, const float* __restrict__ g1,
    const float* __restrict__ b1, const float* __restrict__ g2,
    const float* __restrict__ b2, float* __restrict__ fout,
    short* __restrict__ pout) {
  const int row = blockIdx.x * 4 + (threadIdx.x >> 6);
  const int lane = threadIdx.x & 63;
  const float* xr = x + (size_t)row * D;
  float v[8];
  float s = 0.f;
#pragma unroll
  for (int j = 0; j < 8; ++j) { v[j] = xr[lane + 64 * j]; s += v[j]; }
  s = wave_sum(s);
  const float m1 = s * (1.f / D);
  float q = 0.f;
#pragma unroll
  for (int j = 0; j < 8; ++j) { const float d = v[j] - m1; q += d * d; }
  q = wave_sum(q);
  const float r1 = rsqrtf(q * (1.f / D) + EPS);
  float y[8];
  float s2 = 0.f;
#pragma unroll
  for (int j = 0; j < 8; ++j) {
    const int c = lane + 64 * j;
    y[j] = (v[j] - m1) * r1 * g1[c] + b1[c];
    s2 += y[j];
  }
  s2 = wave_sum(s2);
  const float m2 = s2 * (1.f / D);
  float q2 = 0.f;
#pragma unroll
  for (int j = 0; j < 8; ++j) { const float d = y[j] - m2; q2 += d * d; }
  q2 = wave_sum(q2);
  const float r2 = rsqrtf(q2 * (1.f / D) + EPS);
  float* frow = fout + (size_t)row * D;
  short* prow = pout + (size_t)row * 1024;
#pragma unroll
  for (int j = 0; j < 8; ++j) {
    const int c = lane + 64 * j;
    const float o = (y[j] - m2) * r2 * g2[c] + b2[c];
    frow[c] = o;
    short hi, lo;
    split_f16(o, hi, lo);
    prow[c] = hi;
    prow[D + c] = lo;
  }
}

// ---- partial column sums (head) ------------------------------------------
__global__ __launch_bounds__(256) void colmean_part_k(
    const float* __restrict__ x, float* __restrict__ part) {
  const int b = blockIdx.x, c = blockIdx.y;
  const int s0 = c * 96;
  for (int d = threadIdx.x; d < D; d += 256) {
    float s = 0.f;
    for (int si = 0; si < 96; ++si)
      s += x[((size_t)b * S + s0 + si) * D + d];
    part[((size_t)b * 8 + c) * D + d] = s;
  }
}

// ---- alpha = softmax(mean_s(h) @ wmw + wmb) ------------------------------
__global__ __launch_bounds__(64) void alpha_k(const float* __restrict__ part,
                                              const float* __restrict__ wmw,
                                              const float* __restrict__ wmb,
                                              float* __restrict__ alpha) {
  const int b = blockIdx.x, t = threadIdx.x;
  float p0 = 0, p1 = 0, p2 = 0, p3 = 0;
  for (int d = t; d < D; d += 64) {
    float xm = 0;
#pragma unroll
    for (int c = 0; c < 8; ++c) xm += part[((size_t)b * 8 + c) * D + d];
    xm *= (1.f / S);
    p0 += xm * wmw[d * 4 + 0];
    p1 += xm * wmw[d * 4 + 1];
    p2 += xm * wmw[d * 4 + 2];
    p3 += xm * wmw[d * 4 + 3];
  }
  p0 = wave_sum(p0); p1 = wave_sum(p1);
  p2 = wave_sum(p2); p3 = wave_sum(p3);
  if (t == 0) {
    const float l0 = p0 + wmb[0], l1 = p1 + wmb[1];
    const float l2 = p2 + wmb[2], l3 = p3 + wmb[3];
    const float mx = fmaxf(fmaxf(l0, l1), fmaxf(l2, l3));
    const float e0 = expf(l0 - mx), e1 = expf(l1 - mx);
    const float e2 = expf(l2 - mx), e3 = expf(l3 - mx);
    const float inv = 1.f / (e0 + e1 + e2 + e3);
    alpha[b * 4 + 0] = e0 * inv;
    alpha[b * 4 + 1] = e1 * inv;
    alpha[b * 4 + 2] = e2 * inv;
    alpha[b * 4 + 3] = e3 * inv;
  }
}

// ---- embedding gather-mean, packed out -----------------------------------
__global__ __launch_bounds__(256) void embed_k(const int* __restrict__ xe,
                                               const float* __restrict__ emb,
                                               short* __restrict__ out) {
  const int r = blockIdx.x;
  int idx[8];
#pragma unroll
  for (int j = 0; j < 8; ++j) idx[j] = xe[r * 8 + j];
  short* o = out + (size_t)r * 1024;
  for (int d = threadIdx.x; d < D; d += 256) {
    float s = 0.f;
#pragma unroll
    for (int j = 0; j < 8; ++j) s += emb[(size_t)idx[j] * D + d];
    short hi, lo;
    split_f16(s * 0.125f, hi, lo);
    o[d] = hi;
    o[D + d] = lo;
  }
}

// ---- L2-normalize rows of (BS,64), packed out ----------------------------
__global__ __launch_bounds__(256) void norml2_k(const float* __restrict__ x,
                                                short* __restrict__ out) {
  const int r = blockIdx.x * 4 + (threadIdx.x >> 6);
  const int lane = threadIdx.x & 63;
  const float v = x[(size_t)r * 64 + lane];
  const float s = wave_sum(v * v);
  const float nrm = fmaxf(sqrtf(s), 1e-12f);
  short hi, lo;
  split_f16(v / nrm, hi, lo);
  out[(size_t)r * 128 + lane] = hi;
  out[(size_t)r * 128 + 64 + lane] = lo;
}

// ---- classifier head -----------------------------------------------------
__global__ __launch_bounds__(256) void head_k(
    const float* __restrict__ part, const float* __restrict__ pw1,
    const float* __restrict__ pb1, const float* __restrict__ pw2,
    const float* __restrict__ pb2, float* __restrict__ out) {
  __shared__ float hg[D];
  __shared__ float red[256];
  const int b = blockIdx.x, t = threadIdx.x;
  for (int d = t; d < D; d += 256) {
    float s = 0.f;
#pragma unroll
    for (int c = 0; c < 8; ++c) s += part[((size_t)b * 8 + c) * D + d];
    hg[d] = s * (1.f / S);
  }
  __syncthreads();
  float s = pb1[t];
  for (int d = 0; d < D; ++d) s = fmaf(hg[d], pw1[(size_t)d * 256 + t], s);
  s = fmaxf(s, 0.f);
  red[t] = s * pw2[t];
  __syncthreads();
  for (int o = 128; o > 0; o >>= 1) {
    if (t < o) red[t] += red[t + o];
    __syncthreads();
  }
  if (t == 0) out[b] = red[0] + pb2[0];
}

}  // namespace

extern "C" void kernel_launch(void* const* d_in, const int* in_sizes, int n_in,
                              void* d_out, int out_size, void* d_ws,
                              size_t ws_size, hipStream_t stream) {
  const float* x_cog = (const float*)d_in[0];
  const float* cw1 = (const float*)d_in[1];
  const float* cb1 = (const float*)d_in[2];
  const float* cw2 = (const float*)d_in[3];
  const float* cb2 = (const float*)d_in[4];
  const float* env_emb = (const float*)d_in[5];
  const float* ew1 = (const float*)d_in[6];
  const float* eb1 = (const float*)d_in[7];
  const float* ew2 = (const float*)d_in[8];
  const float* eb2 = (const float*)d_in[9];
  const float* fw1 = (const float*)d_in[10];
  const float* fb1 = (const float*)d_in[11];
  const float* fw2 = (const float*)d_in[12];
  const float* fb2 = (const float*)d_in[13];
  const float* pos_enc = (const float*)d_in[14];
  const float* conv_w = (const float*)d_in[15];
  const float* conv_b = (const float*)d_in[16];
  const float* wm_w = (const float*)d_in[17];
  const float* wm_b = (const float*)d_in[18];
  // d_in[19..21] = ssm_w/ssm_b/A_log: no-ops (y scalar-per-row cancels in LN2)
  const float* ffw1 = (const float*)d_in[22];
  const float* ffb1 = (const float*)d_in[23];
  const float* ffw2 = (const float*)d_in[24];
  const float* ffb2 = (const float*)d_in[25];
  const float* g1 = (const float*)d_in[26];
  const float* be1 = (const float*)d_in[27];
  const float* g2 = (const float*)d_in[28];
  const float* be2 = (const float*)d_in[29];
  const float* pw1 = (const float*)d_in[30];
  const float* pb1 = (const float*)d_in[31];
  const float* pw2 = (const float*)d_in[32];
  const float* pb2 = (const float*)d_in[33];
  const int* x_env = (const int*)d_in[34];
  float* out = (float*)d_out;

  // ---- arena (182.7 MB) ---------------------------------------------------
  float* ws = (float*)d_ws;
  float* Hbuf = ws;                        // 6,291,456 f32
  float* TBuf = Hbuf + 6291456;            // 6,291,456 f32
  float* PARTb = TBuf + 6291456;           // 65,536
  float* ALPHAB = PARTb + 65536;           // 64
  float* ZPADF = ALPHAB + 64;              // 512 (zero page + zero bias)
  short* WPB = (short*)(ZPADF + 512);      // 3,145,728 shorts
  short* R = WPB + 3145728;                // 62,914,560 shorts
  // frontend: CONC | PK1 | PK2
  short* CONC = R;                         // 12288x2048
  short* PK1 = R + 25165824;               // 12288x1024
  short* PK2 = R + 37748736;               // 12288x1024
  // layers:
  short* APFF = R;                         // 12288x4096 (FF hidden pack)
  short* HPA = R + 50331648;               // 12288x1024 (HPACK / APD / FF2-P0)
  float* convP = (float*)R;                // 2 x 6,291,456 f32 (conv partials)
  float* ff2P0 = (float*)HPA;              // 6,291,456 f32
  // frontend split-K partials: P0=Hbuf, P1=TBuf (dead during frontend)

  const dim3 blk(256);
  const dim3 gS1(4, 96, 1);   // N=512 direct
  const dim3 gS2(4, 96, 2);   // N=512 split-K
  const dim3 gF1(16, 96, 1);  // N=2048 direct
  const ptrdiff_t PSfr = 6291456;  // Hbuf->TBuf

  zero_k<<<1, blk, 0, stream>>>(ZPADF);

  // ---- frontend -----------------------------------------------------------
  norml2_k<<<BS / 4, blk, 0, stream>>>(x_cog, PK1);
  pack_wh_k<<<64 * 512 / 256, blk, 0, stream>>>(cw1, WPB, 64, 512, 9);
  gemm_h<true, 1><<<gS1, blk, 0, stream>>>(PK1, 128, 64, WPB, 64, 64, cb1,
                                           nullptr, 0, 0, PK2, PK2 + 512, 1024);
  pack_wh_k<<<512 * 512 / 256, blk, 0, stream>>>(cw2, WPB, 512, 512, 9);
  gemm_h<false, 2><<<gS2, blk, 0, stream>>>(PK2, 1024, 512, WPB, 512, 256,
                                            nullptr, Hbuf, 512, PSfr, nullptr,
                                            nullptr, 0);
  comb2_k<false, true, false><<<6144, blk, 0, stream>>>(
      Hbuf, TBuf, cb2, nullptr, 0, 0, nullptr, CONC, CONC + 1024, 2048, 9);
  embed_k<<<BS, blk, 0, stream>>>(x_env, env_emb, PK1);
  pack_wh_k<<<512 * 512 / 256, blk, 0, stream>>>(ew1, WPB, 512, 512, 9);
  gemm_h<false, 2><<<gS2, blk, 0, stream>>>(PK1, 1024, 512, WPB, 512, 256,
                                            nullptr, Hbuf, 512, PSfr, nullptr,
                                            nullptr, 0);
  comb2_k<true, true, false><<<6144, blk, 0, stream>>>(
      Hbuf, TBuf, eb1, nullptr, 0, 0, nullptr, PK2, PK2 + 512, 1024, 9);
  pack_wh_k<<<512 * 512 / 256, blk, 0, stream>>>(ew2, WPB, 512, 512, 9);
  gemm_h<false, 2><<<gS2, blk, 0, stream>>>(PK2, 1024, 512, WPB, 512, 256,
                                            nullptr, Hbuf, 512, PSfr, nullptr,
                                            nullptr, 0);
  comb2_k<false, true, false><<<6144, blk, 0, stream>>>(
      Hbuf, TBuf, eb2, nullptr, 0, 0, nullptr, CONC + 512, CONC + 1536, 2048,
      9);
  pack_wh_k<<<1024 * 512 / 256, blk, 0, stream>>>(fw1, WPB, 1024, 512, 9);
  gemm_h<false, 2><<<gS2, blk, 0, stream>>>(CONC, 2048, 1024, WPB, 1024, 512,
                                            nullptr, Hbuf, 512, PSfr, nullptr,
                                            nullptr, 0);
  comb2_k<true, true, false><<<6144, blk, 0, stream>>>(
      Hbuf, TBuf, fb1, nullptr, 0, 0, nullptr, PK1, PK1 + 512, 1024, 9);
  pack_wh_k<<<512 * 512 / 256, blk, 0, stream>>>(fw2, WPB, 512, 512, 9);
  gemm_h<false, 2><<<gS2, blk, 0, stream>>>(PK1, 1024, 512, WPB, 512, 256,
                                            nullptr, Hbuf, 512, PSfr, nullptr,
                                            nullptr, 0);
  comb2_k<false, false, true><<<6144, blk, 0, stream>>>(
      Hbuf, TBuf, fb2, pos_enc, D, S, Hbuf, nullptr, nullptr, 0, 9);

  // ---- layers -------------------------------------------------------------
  for (int l = 0; l < L; ++l) {
    pack_stats_k<<<dim3(B, 8), blk, 0, stream>>>(Hbuf, HPA, PARTb);
    alpha_k<<<B, dim3(64), 0, stream>>>(PARTb, wm_w + (size_t)l * D * 4,
                                        wm_b + l * 4, ALPHAB);
    pack_convw_k<<<12 * 512 * 512 / 256, blk, 0, stream>>>(
        conv_w + (size_t)l * 4 * D * D * 3, WPB);
    conv_zp_k<<<768, blk, 0, stream>>>(HPA, WPB, conv_b + (size_t)l * 4 * D,
                                       ALPHAB, (const short*)ZPADF, convP);
    comb2_k<false, false, true><<<6144, blk, 0, stream>>>(
        convP, convP + 6291456, ZPADF, Hbuf, D, 0, TBuf, nullptr, nullptr, 0,
        9);
    ln_fused_k<<<BS / 4, blk, 0, stream>>>(TBuf, g1 + l * D, be1 + l * D,
                                           g2 + l * D, be2 + l * D, TBuf, HPA);
    pack_wh_k<<<512 * 2048 / 256, blk, 0, stream>>>(ffw1 + (size_t)l * D * FF,
                                                    WPB, 512, 2048, 11);
    gemm_h<true, 1><<<gF1, blk, 0, stream>>>(HPA, 1024, 512, WPB, 512, 512,
                                             ffb1 + (size_t)l * FF, nullptr, 0,
                                             0, APFF, APFF + 2048, 4096);
    pack_wh_k<<<2048 * 512 / 256, blk, 0, stream>>>(ffw2 + (size_t)l * FF * D,
                                                    WPB, 2048, 512, 9);
    gemm_h<false, 2><<<gS2, blk, 0, stream>>>(APFF, 4096, 2048, WPB, 2048,
                                              1024, nullptr, ff2P0, 512,
                                              (ptrdiff_t)(Hbuf - ff2P0),
                                              nullptr, nullptr, 0);
    comb2_k<false, false, true><<<6144, blk, 0, stream>>>(
        ff2P0, Hbuf, ffb2 + (size_t)l * D, TBuf, D, 0, Hbuf, nullptr, nullptr,
        0, 9);
  }

  // ---- head ---------------------------------------------------------------
  colmean_part_k<<<dim3(B, 8), blk, 0, stream>>>(Hbuf, PARTb);
  head_k<<<B, blk, 0, stream>>>(PARTb, pw1, pb1, pw2, pb2, out);
}

// Round 6
// 1602.408 us; speedup vs baseline: 2.9867x; 1.4525x over previous
//
#include <hip/hip_runtime.h>
#include <cstdint>
#include <cstddef>

namespace {

constexpr int B = 16, S = 768, BS = B * S, D = 512, FF = 2048, L = 6;
constexpr float EPS = 1e-5f;

typedef float f32x4 __attribute__((ext_vector_type(4)));
typedef _Float16 f16x8 __attribute__((ext_vector_type(8)));
typedef short short4v __attribute__((ext_vector_type(4)));

__device__ __forceinline__ float wave_sum(float v) {
#pragma unroll
  for (int o = 32; o > 0; o >>= 1) v += __shfl_xor(v, o, 64);
  return v;
}

// ---- fp16 split (RTNE): x ~= hi + lo, each fp16 --------------------------
__device__ __forceinline__ void split_f16(float x, short& hi, short& lo) {
  _Float16 h = (_Float16)x;
  _Float16 l = (_Float16)(x - (float)h);
  hi = __builtin_bit_cast(short, h);
  lo = __builtin_bit_cast(short, l);
}

// ---- async global->LDS, 16B per lane ------------------------------------
__device__ __forceinline__ void gload16(const void* g, void* l) {
  __builtin_amdgcn_global_load_lds(
      (const __attribute__((address_space(1))) void*)g,
      (__attribute__((address_space(3))) void*)l, 16, 0, 0);
}

// LDS tile [128 rows][8 slots of 16B] (BK=64 halfs). Bank fix: global slot
// gsl = sl0 ^ (row&7); LDS stays linear (rule #21: swizzle the SOURCE,
// match on the READ). Proven conflicts=0 in rounds 3/5.

// =========================================================================
// fp16 GEMM. A: hi plane (lda), optional lo plane at A+aLoff (ALO).
// Wt: (N,ldw) hi (B^T, N-major). acc += aH*bH [+ aL*bH if ALO].
// blockIdx.z = K-split. OMODE 1: bias/relu + pack hi (and lo if ALO) to
// ph/pl. OMODE 2: raw f32 partial to C + kz*pstride.
// Tile 128x128, BK=64, 4 waves.
// =========================================================================
template <bool RELU, int OMODE, bool ALO>
__global__ __launch_bounds__(256, 3) void gemm_h(
    const short* __restrict__ A, int lda, int aLoff,
    const short* __restrict__ Wt, int ldw, int Klen,
    const float* __restrict__ bias, float* __restrict__ C, int ldc,
    ptrdiff_t pstride, short* __restrict__ ph, short* __restrict__ pl,
    int ldp) {
  __shared__ alignas(16) short sAh[8192], sBh[8192];
  __shared__ alignas(16) short sAl[ALO ? 8192 : 16];
  const int tid = threadIdx.x;
  const unsigned Nt = gridDim.x;
  const unsigned lin = blockIdx.y * Nt + blockIdx.x;
  const unsigned cpx = (Nt * gridDim.y) >> 3;
  const unsigned swz = (lin & 7) * cpx + (lin >> 3);
  const int bn = (int)(swz % Nt) * 128, bm = (int)(swz / Nt) * 128;
  const int kz = blockIdx.z;
  const int wave = tid >> 6, lane = tid & 63;
  const int wr = (wave >> 1) * 64, wc = (wave & 1) * 64;
  const int lr = lane & 15, sl = lane >> 4;
  const short* Ab = A + (size_t)bm * lda + (size_t)kz * Klen;
  const short* Wb = Wt + (size_t)bn * ldw + (size_t)kz * Klen;
  f32x4 acc[4][4] = {};
  for (int kk = 0; kk < Klen; kk += 64) {
#pragma unroll
    for (int jj = 0; jj < 4; ++jj) {
      const int G = jj * 256 + tid;
      const int srow = G >> 3, sl0 = G & 7;
      const int gsl = sl0 ^ (srow & 7);
      const int dst = G * 8;
      const size_t ra = (size_t)srow * lda + kk + gsl * 8;
      gload16(Ab + ra, &sAh[dst]);
      if constexpr (ALO) gload16(Ab + ra + aLoff, &sAl[dst]);
      gload16(Wb + (size_t)srow * ldw + kk + gsl * 8, &sBh[dst]);
    }
    __syncthreads();
#pragma unroll
    for (int ks = 0; ks < 2; ++ks) {
      f16x8 aH[4], bH[4];
#pragma unroll
      for (int m = 0; m < 4; ++m) {
        const int r = wr + m * 16 + lr;
        aH[m] = *(const f16x8*)&sAh[r * 64 + (((ks * 4 + sl) ^ (r & 7)) * 8)];
      }
#pragma unroll
      for (int n = 0; n < 4; ++n) {
        const int r = wc + n * 16 + lr;
        bH[n] = *(const f16x8*)&sBh[r * 64 + (((ks * 4 + sl) ^ (r & 7)) * 8)];
      }
#pragma unroll
      for (int m = 0; m < 4; ++m)
#pragma unroll
        for (int n = 0; n < 4; ++n)
          acc[m][n] = __builtin_amdgcn_mfma_f32_16x16x32_f16(aH[m], bH[n],
                                                             acc[m][n], 0, 0, 0);
      if constexpr (ALO) {
        f16x8 aL[4];
#pragma unroll
        for (int m = 0; m < 4; ++m) {
          const int r = wr + m * 16 + lr;
          aL[m] =
              *(const f16x8*)&sAl[r * 64 + (((ks * 4 + sl) ^ (r & 7)) * 8)];
        }
#pragma unroll
        for (int m = 0; m < 4; ++m)
#pragma unroll
          for (int n = 0; n < 4; ++n)
            acc[m][n] = __builtin_amdgcn_mfma_f32_16x16x32_f16(
                aL[m], bH[n], acc[m][n], 0, 0, 0);
      }
    }
    __syncthreads();
  }
  const int r4 = sl * 4;
#pragma unroll
  for (int m = 0; m < 4; ++m) {
#pragma unroll
    for (int r = 0; r < 4; ++r) {
      const int mm = bm + wr + m * 16 + r4 + r;
#pragma unroll
      for (int n = 0; n < 4; ++n) {
        const int col = bn + wc + n * 16 + lr;
        if (OMODE == 2) {
          (C + (ptrdiff_t)kz * pstride)[(size_t)mm * ldc + col] = acc[m][n][r];
        } else {
          float v = acc[m][n][r] + bias[col];
          if (RELU) v = fmaxf(v, 0.f);
          short hi, lo;
          split_f16(v, hi, lo);
          ph[(size_t)mm * ldp + col] = hi;
          if constexpr (ALO) pl[(size_t)mm * ldp + col] = lo;
        }
      }
    }
  }
}

// =========================================================================
// Conv z-pair, single-product fp16: block does scales (zp*2, zp*2+1),
// K = 3 taps x 512 each; accF = sum_z alpha[b,z]*(conv_z + cb_z) -> P[zp].
// hp: (BS, 512) hi pack.  wt: (12, 512, 512) hi.  grid 768, 3 blocks/CU.
// =========================================================================
__global__ __launch_bounds__(256, 3) void conv_zp_k(
    const short* __restrict__ hp, const short* __restrict__ wt,
    const float* __restrict__ cb, const float* __restrict__ alpha,
    const short* __restrict__ zpadS, float* __restrict__ P) {
  __shared__ alignas(16) short sAh[8192], sBh[8192];
  const int tid = threadIdx.x;
  const unsigned lin = blockIdx.x;
  const unsigned swz = (lin & 7) * 96 + (lin >> 3);
  const int zp = (int)(swz / 384);
  const unsigned rem = swz % 384;
  const int bn = (int)(rem & 3) * 128;
  const int bmt = (int)(rem >> 2);
  const int b = bmt / 6, s0 = (bmt % 6) * 128, gm0 = bmt * 128;
  const int wave = tid >> 6, lane = tid & 63;
  const int wr = (wave >> 1) * 64, wc = (wave & 1) * 64;
  const int lr = lane & 15, sl = lane >> 4;
  const short* hb = hp + (size_t)b * S * 512;
  f32x4 accF[4][4] = {};
#pragma unroll
  for (int zi = 0; zi < 2; ++zi) {
    const int z = zp * 2 + zi;
    f32x4 acc[4][4] = {};
    for (int kk = 0; kk < 1536; kk += 64) {
      const int tap = kk >> 9;
      const int koff = kk & 511;
      const int off = (tap - 1) << z;
#pragma unroll
      for (int jj = 0; jj < 4; ++jj) {
        const int G = jj * 256 + tid;
        const int srow = G >> 3, sl0 = G & 7;
        const int gsl = sl0 ^ (srow & 7);
        const int dst = G * 8;
        const int gs = s0 + srow + off;
        const bool inb = ((unsigned)gs < (unsigned)S);
        const short* aBase = hb + (size_t)gs * 512 + koff + gsl * 8;
        gload16(inb ? aBase : zpadS, &sAh[dst]);
        gload16(wt + ((size_t)((z * 3 + tap) * 512 + bn + srow)) * 512 + koff +
                    gsl * 8,
                &sBh[dst]);
      }
      __syncthreads();
#pragma unroll
      for (int ks = 0; ks < 2; ++ks) {
        f16x8 aH[4], bH[4];
#pragma unroll
        for (int m = 0; m < 4; ++m) {
          const int r = wr + m * 16 + lr;
          aH[m] =
              *(const f16x8*)&sAh[r * 64 + (((ks * 4 + sl) ^ (r & 7)) * 8)];
        }
#pragma unroll
        for (int n = 0; n < 4; ++n) {
          const int r = wc + n * 16 + lr;
          bH[n] =
              *(const f16x8*)&sBh[r * 64 + (((ks * 4 + sl) ^ (r & 7)) * 8)];
        }
#pragma unroll
        for (int m = 0; m < 4; ++m)
#pragma unroll
          for (int n = 0; n < 4; ++n)
            acc[m][n] = __builtin_amdgcn_mfma_f32_16x16x32_f16(
                aH[m], bH[n], acc[m][n], 0, 0, 0);
      }
      __syncthreads();
    }
    const float al = alpha[b * 4 + z];
#pragma unroll
    for (int n = 0; n < 4; ++n) {
      const float cbv = cb[z * D + bn + wc + n * 16 + lr];
#pragma unroll
      for (int m = 0; m < 4; ++m)
#pragma unroll
        for (int r = 0; r < 4; ++r)
          accF[m][n][r] += al * (acc[m][n][r] + cbv);
    }
  }
  float* Pz = P + (size_t)zp * ((size_t)BS * D);
  const int r4 = sl * 4;
#pragma unroll
  for (int m = 0; m < 4; ++m)
#pragma unroll
    for (int r = 0; r < 4; ++r) {
      const int mm = gm0 + wr + m * 16 + r4 + r;
#pragma unroll
      for (int n = 0; n < 4; ++n)
        Pz[(size_t)mm * D + bn + wc + n * 16 + lr] = accF[m][n][r];
    }
}

// ---- combine: v = P0+P1+bias; relu?; +resid?; -> f32 / fp16 pack ---------
template <bool RELU, bool PACK, bool FOUT, bool LO>
__global__ __launch_bounds__(256) void comb2_k(
    const float* __restrict__ P0, const float* __restrict__ P1,
    const float* __restrict__ bias, const float* __restrict__ resid, int ldr,
    int rmod, float* __restrict__ fout, short* __restrict__ ph,
    short* __restrict__ pl, int ldp, int ln2N) {
  const size_t e = ((size_t)blockIdx.x * 256 + threadIdx.x) * 4;
  const int col = (int)(e & ((1u << ln2N) - 1));
  const size_t row = e >> ln2N;
  f32x4 v = *(const f32x4*)(P0 + e);
  const f32x4 w = *(const f32x4*)(P1 + e);
  const f32x4 bb = *(const f32x4*)(bias + col);
#pragma unroll
  for (int j = 0; j < 4; ++j) {
    v[j] += w[j] + bb[j];
    if (RELU) v[j] = fmaxf(v[j], 0.f);
  }
  if (resid) {
    const size_t rr = rmod ? (row % (size_t)rmod) : row;
    const f32x4 rv = *(const f32x4*)(resid + rr * ldr + col);
#pragma unroll
    for (int j = 0; j < 4; ++j) v[j] += rv[j];
  }
  if (FOUT) *(f32x4*)(fout + e) = v;
  if (PACK) {
    short4v h4, l4;
#pragma unroll
    for (int j = 0; j < 4; ++j) {
      short hh, ll;
      split_f16(v[j], hh, ll);
      h4[j] = hh;
      l4[j] = ll;
    }
    *(short4v*)(ph + row * ldp + col) = h4;
    if (LO) *(short4v*)(pl + row * ldp + col) = l4;
  }
}

// ---- fused conv-combine + LN1 -> LN2: v = P0+P1+resid, double LN ---------
__global__ __launch_bounds__(256) void ln3_k(
    const float* __restrict__ P0, const float* __restrict__ P1,
    const float* __restrict__ resid, const float* __restrict__ g1,
    const float* __restrict__ b1, const float* __restrict__ g2,
    const float* __restrict__ b2, float* __restrict__ fout,
    short* __restrict__ pout) {
  const int row = blockIdx.x * 4 + (threadIdx.x >> 6);
  const int lane = threadIdx.x & 63;
  const size_t base = (size_t)row * D;
  float v[8];
  float s = 0.f;
#pragma unroll
  for (int j = 0; j < 8; ++j) {
    const int c = lane + 64 * j;
    v[j] = P0[base + c] + P1[base + c] + resid[base + c];
    s += v[j];
  }
  s = wave_sum(s);
  const float m1 = s * (1.f / D);
  float q = 0.f;
#pragma unroll
  for (int j = 0; j < 8; ++j) { const float d = v[j] - m1; q += d * d; }
  q = wave_sum(q);
  const float r1 = rsqrtf(q * (1.f / D) + EPS);
  float y[8];
  float s2 = 0.f;
#pragma unroll
  for (int j = 0; j < 8; ++j) {
    const int c = lane + 64 * j;
    y[j] = (v[j] - m1) * r1 * g1[c] + b1[c];
    s2 += y[j];
  }
  s2 = wave_sum(s2);
  const float m2 = s2 * (1.f / D);
  float q2 = 0.f;
#pragma unroll
  for (int j = 0; j < 8; ++j) { const float d = y[j] - m2; q2 += d * d; }
  q2 = wave_sum(q2);
  const float r2 = rsqrtf(q2 * (1.f / D) + EPS);
  float* frow = fout + base;
  short* prow = pout + (size_t)row * 512;
#pragma unroll
  for (int j = 0; j < 8; ++j) {
    const int c = lane + 64 * j;
    const float o = (y[j] - m2) * r2 * g2[c] + b2[c];
    frow[c] = o;
    const _Float16 h = (_Float16)o;
    prow[c] = __builtin_bit_cast(short, h);
  }
}

// ---- partial column sums over S (read-only) ------------------------------
__global__ __launch_bounds__(256) void colmean_part_k(
    const float* __restrict__ x, float* __restrict__ part) {
  const int b = blockIdx.x, c = blockIdx.y;
  const int s0 = c * 96;
  for (int d = threadIdx.x; d < D; d += 256) {
    float s = 0.f;
    for (int si = 0; si < 96; ++si)
      s += x[((size_t)b * S + s0 + si) * D + d];
    part[((size_t)b * 8 + c) * D + d] = s;
  }
}

// ---- W-pack hi-only: (K,N) f32 -> (N,K) fp16 bits ------------------------
__global__ __launch_bounds__(256) void pack_wh_k(const float* __restrict__ W,
                                                 short* __restrict__ out,
                                                 int K, int N, int ln2N) {
  const int idx = blockIdx.x * 256 + threadIdx.x;
  const int n = idx & (N - 1), k = idx >> ln2N;
  if (k >= K) return;
  const _Float16 h = (_Float16)W[(size_t)k * N + n];
  out[(size_t)n * K + k] = __builtin_bit_cast(short, h);
}

// ---- conv W-pack hi-only: (4,O,I,3) -> (12, O, I) fp16 bits --------------
__global__ __launch_bounds__(256) void pack_convw_k(
    const float* __restrict__ cw, short* __restrict__ out) {
  const int idx = blockIdx.x * 256 + threadIdx.x;  // 12*512*512
  const int c = idx & 511, o = (idx >> 9) & 511, seg = idx >> 18;
  const int i = seg / 3, t = seg % 3;
  const _Float16 h = (_Float16)cw[(((size_t)i * D + o) * D + c) * 3 + t];
  out[((size_t)seg * D + o) * D + c] = __builtin_bit_cast(short, h);
}

__global__ __launch_bounds__(256) void zero_k(float* __restrict__ p) {
  p[threadIdx.x] = 0.f;
  p[threadIdx.x + 256] = 0.f;
}

// ---- alpha = softmax(mean_s(h) @ wmw + wmb) ------------------------------
__global__ __launch_bounds__(64) void alpha_k(const float* __restrict__ part,
                                              const float* __restrict__ wmw,
                                              const float* __restrict__ wmb,
                                              float* __restrict__ alpha) {
  const int b = blockIdx.x, t = threadIdx.x;
  float p0 = 0, p1 = 0, p2 = 0, p3 = 0;
  for (int d = t; d < D; d += 64) {
    float xm = 0;
#pragma unroll
    for (int c = 0; c < 8; ++c) xm += part[((size_t)b * 8 + c) * D + d];
    xm *= (1.f / S);
    p0 += xm * wmw[d * 4 + 0];
    p1 += xm * wmw[d * 4 + 1];
    p2 += xm * wmw[d * 4 + 2];
    p3 += xm * wmw[d * 4 + 3];
  }
  p0 = wave_sum(p0); p1 = wave_sum(p1);
  p2 = wave_sum(p2); p3 = wave_sum(p3);
  if (t == 0) {
    const float l0 = p0 + wmb[0], l1 = p1 + wmb[1];
    const float l2 = p2 + wmb[2], l3 = p3 + wmb[3];
    const float mx = fmaxf(fmaxf(l0, l1), fmaxf(l2, l3));
    const float e0 = expf(l0 - mx), e1 = expf(l1 - mx);
    const float e2 = expf(l2 - mx), e3 = expf(l3 - mx);
    const float inv = 1.f / (e0 + e1 + e2 + e3);
    alpha[b * 4 + 0] = e0 * inv;
    alpha[b * 4 + 1] = e1 * inv;
    alpha[b * 4 + 2] = e2 * inv;
    alpha[b * 4 + 3] = e3 * inv;
  }
}

// ---- embedding gather-mean, packed out (hi+lo, frontend) -----------------
__global__ __launch_bounds__(256) void embed_k(const int* __restrict__ xe,
                                               const float* __restrict__ emb,
                                               short* __restrict__ out) {
  const int r = blockIdx.x;
  int idx[8];
#pragma unroll
  for (int j = 0; j < 8; ++j) idx[j] = xe[r * 8 + j];
  short* o = out + (size_t)r * 1024;
  for (int d = threadIdx.x; d < D; d += 256) {
    float s = 0.f;
#pragma unroll
    for (int j = 0; j < 8; ++j) s += emb[(size_t)idx[j] * D + d];
    short hi, lo;
    split_f16(s * 0.125f, hi, lo);
    o[d] = hi;
    o[D + d] = lo;
  }
}

// ---- L2-normalize rows of (BS,64), packed out (hi+lo) --------------------
__global__ __launch_bounds__(256) void norml2_k(const float* __restrict__ x,
                                                short* __restrict__ out) {
  const int r = blockIdx.x * 4 + (threadIdx.x >> 6);
  const int lane = threadIdx.x & 63;
  const float v = x[(size_t)r * 64 + lane];
  const float s = wave_sum(v * v);
  const float nrm = fmaxf(sqrtf(s), 1e-12f);
  short hi, lo;
  split_f16(v / nrm, hi, lo);
  out[(size_t)r * 128 + lane] = hi;
  out[(size_t)r * 128 + 64 + lane] = lo;
}

// ---- classifier head -----------------------------------------------------
__global__ __launch_bounds__(256) void head_k(
    const float* __restrict__ part, const float* __restrict__ pw1,
    const float* __restrict__ pb1, const float* __restrict__ pw2,
    const float* __restrict__ pb2, float* __restrict__ out) {
  __shared__ float hg[D];
  __shared__ float red[256];
  const int b = blockIdx.x, t = threadIdx.x;
  for (int d = t; d < D; d += 256) {
    float s = 0.f;
#pragma unroll
    for (int c = 0; c < 8; ++c) s += part[((size_t)b * 8 + c) * D + d];
    hg[d] = s * (1.f / S);
  }
  __syncthreads();
  float s = pb1[t];
  for (int d = 0; d < D; ++d) s = fmaf(hg[d], pw1[(size_t)d * 256 + t], s);
  s = fmaxf(s, 0.f);
  red[t] = s * pw2[t];
  __syncthreads();
  for (int o = 128; o > 0; o >>= 1) {
    if (t < o) red[t] += red[t + o];
    __syncthreads();
  }
  if (t == 0) out[b] = red[0] + pb2[0];
}

}  // namespace

extern "C" void kernel_launch(void* const* d_in, const int* in_sizes, int n_in,
                              void* d_out, int out_size, void* d_ws,
                              size_t ws_size, hipStream_t stream) {
  const float* x_cog = (const float*)d_in[0];
  const float* cw1 = (const float*)d_in[1];
  const float* cb1 = (const float*)d_in[2];
  const float* cw2 = (const float*)d_in[3];
  const float* cb2 = (const float*)d_in[4];
  const float* env_emb = (const float*)d_in[5];
  const float* ew1 = (const float*)d_in[6];
  const float* eb1 = (const float*)d_in[7];
  const float* ew2 = (const float*)d_in[8];
  const float* eb2 = (const float*)d_in[9];
  const float* fw1 = (const float*)d_in[10];
  const float* fb1 = (const float*)d_in[11];
  const float* fw2 = (const float*)d_in[12];
  const float* fb2 = (const float*)d_in[13];
  const float* pos_enc = (const float*)d_in[14];
  const float* conv_w = (const float*)d_in[15];
  const float* conv_b = (const float*)d_in[16];
  const float* wm_w = (const float*)d_in[17];
  const float* wm_b = (const float*)d_in[18];
  // d_in[19..21] = ssm_w/ssm_b/A_log: no-ops (y scalar-per-row cancels in LN2)
  const float* ffw1 = (const float*)d_in[22];
  const float* ffb1 = (const float*)d_in[23];
  const float* ffw2 = (const float*)d_in[24];
  const float* ffb2 = (const float*)d_in[25];
  const float* g1 = (const float*)d_in[26];
  const float* be1 = (const float*)d_in[27];
  const float* g2 = (const float*)d_in[28];
  const float* be2 = (const float*)d_in[29];
  const float* pw1 = (const float*)d_in[30];
  const float* pb1 = (const float*)d_in[31];
  const float* pw2 = (const float*)d_in[32];
  const float* pb2 = (const float*)d_in[33];
  const int* x_env = (const int*)d_in[34];
  float* out = (float*)d_out;

  // ---- arena --------------------------------------------------------------
  float* ws = (float*)d_ws;
  float* Hbuf = ws;                        // 6,291,456 f32 (running h)
  float* TBuf = Hbuf + 6291456;            // 6,291,456 f32 (h2 / partial)
  float* PARTb = TBuf + 6291456;           // 65,536
  float* ALPHAB = PARTb + 65536;           // 64
  float* ZPADF = ALPHAB + 64;              // 512 (zero page)
  short* WPB = (short*)(ZPADF + 512);      // 3,145,728 shorts (W packs)
  short* R = WPB + 3145728;                // 62,914,560 shorts aliased region
  // frontend:  CONC[0,25165824) | PK1[25165824,37748736) | PK2[37748736,50331648)
  short* CONC = R;
  short* PK1 = R + 25165824;
  short* PK2 = R + 37748736;
  // layers:
  float* convP = (float*)R;                // 2 x 6,291,456 f32 [0,25165824) sh
  short* APFF = R;                         // 12288x2048 hi [0,25165824)
  float* ff2P0 = (float*)(R + 25165824);   // 6,291,456 f32
  float* ff2P1 = (float*)(R + 37748736);   // 6,291,456 f32
  short* HPACK = R + 50331648;             // 12288x512 hi (persistent in-layer)
  short* APD = R + 56623104;               // 12288x512 hi (h2 pack)

  const dim3 blk(256);
  const dim3 gS1(4, 96, 1);   // N=512 direct
  const dim3 gS2(4, 96, 2);   // N=512 split-K
  const dim3 gF1(16, 96, 1);  // N=2048 direct
  const ptrdiff_t PSfr = 6291456;  // Hbuf->TBuf partial stride

  zero_k<<<1, blk, 0, stream>>>(ZPADF);

  // ---- frontend (2-product: A hi+lo) -------------------------------------
  norml2_k<<<BS / 4, blk, 0, stream>>>(x_cog, PK1);
  pack_wh_k<<<64 * 512 / 256, blk, 0, stream>>>(cw1, WPB, 64, 512, 9);
  gemm_h<true, 1, true><<<gS1, blk, 0, stream>>>(PK1, 128, 64, WPB, 64, 64,
                                                 cb1, nullptr, 0, 0, PK2,
                                                 PK2 + 512, 1024);
  pack_wh_k<<<512 * 512 / 256, blk, 0, stream>>>(cw2, WPB, 512, 512, 9);
  gemm_h<false, 2, true><<<gS2, blk, 0, stream>>>(PK2, 1024, 512, WPB, 512,
                                                  256, nullptr, Hbuf, 512,
                                                  PSfr, nullptr, nullptr, 0);
  comb2_k<false, true, false, true><<<6144, blk, 0, stream>>>(
      Hbuf, TBuf, cb2, nullptr, 0, 0, nullptr, CONC, CONC + 1024, 2048, 9);
  embed_k<<<BS, blk, 0, stream>>>(x_env, env_emb, PK1);
  pack_wh_k<<<512 * 512 / 256, blk, 0, stream>>>(ew1, WPB, 512, 512, 9);
  gemm_h<false, 2, true><<<gS2, blk, 0, stream>>>(PK1, 1024, 512, WPB, 512,
                                                  256, nullptr, Hbuf, 512,
                                                  PSfr, nullptr, nullptr, 0);
  comb2_k<true, true, false, true><<<6144, blk, 0, stream>>>(
      Hbuf, TBuf, eb1, nullptr, 0, 0, nullptr, PK2, PK2 + 512, 1024, 9);
  pack_wh_k<<<512 * 512 / 256, blk, 0, stream>>>(ew2, WPB, 512, 512, 9);
  gemm_h<false, 2, true><<<gS2, blk, 0, stream>>>(PK2, 1024, 512, WPB, 512,
                                                  256, nullptr, Hbuf, 512,
                                                  PSfr, nullptr, nullptr, 0);
  comb2_k<false, true, false, true><<<6144, blk, 0, stream>>>(
      Hbuf, TBuf, eb2, nullptr, 0, 0, nullptr, CONC + 512, CONC + 1536, 2048,
      9);
  pack_wh_k<<<1024 * 512 / 256, blk, 0, stream>>>(fw1, WPB, 1024, 512, 9);
  gemm_h<false, 2, true><<<gS2, blk, 0, stream>>>(CONC, 2048, 1024, WPB, 1024,
                                                  512, nullptr, Hbuf, 512,
                                                  PSfr, nullptr, nullptr, 0);
  comb2_k<true, true, false, true><<<6144, blk, 0, stream>>>(
      Hbuf, TBuf, fb1, nullptr, 0, 0, nullptr, PK1, PK1 + 512, 1024, 9);
  pack_wh_k<<<512 * 512 / 256, blk, 0, stream>>>(fw2, WPB, 512, 512, 9);
  gemm_h<false, 2, true><<<gS2, blk, 0, stream>>>(PK1, 1024, 512, WPB, 512,
                                                  256, nullptr, Hbuf, 512,
                                                  PSfr, nullptr, nullptr, 0);
  // final: h = P0+P1+fb2+pos_enc -> Hbuf f32 + HPACK hi
  comb2_k<false, true, true, false><<<6144, blk, 0, stream>>>(
      Hbuf, TBuf, fb2, pos_enc, D, S, Hbuf, HPACK, nullptr, 512, 9);

  // ---- layers (single-product fp16) ---------------------------------------
  for (int l = 0; l < L; ++l) {
    colmean_part_k<<<dim3(B, 8), blk, 0, stream>>>(Hbuf, PARTb);
    alpha_k<<<B, dim3(64), 0, stream>>>(PARTb, wm_w + (size_t)l * D * 4,
                                        wm_b + l * 4, ALPHAB);
    pack_convw_k<<<12 * 512 * 512 / 256, blk, 0, stream>>>(
        conv_w + (size_t)l * 4 * D * D * 3, WPB);
    conv_zp_k<<<768, blk, 0, stream>>>(HPACK, WPB, conv_b + (size_t)l * 4 * D,
                                       ALPHAB, (const short*)ZPADF, convP);
    // h2 = LN2(LN1(P0+P1+h)) -> TBuf f32 + APD hi
    ln3_k<<<BS / 4, blk, 0, stream>>>(convP, convP + 6291456, Hbuf, g1 + l * D,
                                      be1 + l * D, g2 + l * D, be2 + l * D,
                                      TBuf, APD);
    pack_wh_k<<<512 * 2048 / 256, blk, 0, stream>>>(ffw1 + (size_t)l * D * FF,
                                                    WPB, 512, 2048, 11);
    gemm_h<true, 1, false><<<gF1, blk, 0, stream>>>(APD, 512, 0, WPB, 512, 512,
                                                    ffb1 + (size_t)l * FF,
                                                    nullptr, 0, 0, APFF,
                                                    nullptr, 2048);
    pack_wh_k<<<2048 * 512 / 256, blk, 0, stream>>>(ffw2 + (size_t)l * FF * D,
                                                    WPB, 2048, 512, 9);
    gemm_h<false, 2, false><<<gS2, blk, 0, stream>>>(
        APFF, 2048, 0, WPB, 2048, 1024, nullptr, ff2P0, 512,
        (ptrdiff_t)(ff2P1 - ff2P0), nullptr, nullptr, 0);
    // new h = P0+P1+ffb2+h2 -> Hbuf f32 + HPACK hi (next layer's conv input)
    comb2_k<false, true, true, false><<<6144, blk, 0, stream>>>(
        ff2P0, ff2P1, ffb2 + (size_t)l * D, TBuf, D, 0, Hbuf, HPACK, nullptr,
        512, 9);
  }

  // ---- head ---------------------------------------------------------------
  colmean_part_k<<<dim3(B, 8), blk, 0, stream>>>(Hbuf, PARTb);
  head_k<<<B, blk, 0, stream>>>(PARTb, pw1, pb1, pw2, pb2, out);
}

// Round 7
// 1546.204 us; speedup vs baseline: 3.0953x; 1.0363x over previous
//
#include <hip/hip_runtime.h>
#include <cstdint>
#include <cstddef>

namespace {

constexpr int B = 16, S = 768, BS = B * S, D = 512, FF = 2048, L = 6;
constexpr float EPS = 1e-5f;

typedef float f32x4 __attribute__((ext_vector_type(4)));
typedef _Float16 f16x8 __attribute__((ext_vector_type(8)));

__device__ __forceinline__ float wave_sum(float v) {
#pragma unroll
  for (int o = 32; o > 0; o >>= 1) v += __shfl_xor(v, o, 64);
  return v;
}

__device__ __forceinline__ short f16b(float x) {
  const _Float16 h = (_Float16)x;
  return __builtin_bit_cast(short, h);
}

// ---- async global->LDS, 16B per lane ------------------------------------
__device__ __forceinline__ void gload16(const void* g, void* l) {
  __builtin_amdgcn_global_load_lds(
      (const __attribute__((address_space(1))) void*)g,
      (__attribute__((address_space(3))) void*)l, 16, 0, 0);
}

// LDS tile [128 rows][8 slots of 16B] (BK=64 halfs). Bank fix: global slot
// gsl = sl0 ^ (row&7); LDS stays linear (rule #21: swizzle SOURCE, match on
// READ). Proven conflicts=0 (rounds 3/5/6).

// =========================================================================
// fp16 GEMM, direct (no split-K). A: (M,lda) fp16-bits hi. Wt: (N,ldw) hi
// (B^T N-major). Epilogue: v = acc + bias[col]; RELU?; RESID? (+resid[
// (rmod? mm%rmod : mm)*ldr + col]); FOUT? fout f32; PACK? ph fp16.
// Tile 128x128, BK=64, 4 waves, 64 MFMA/barrier-pair/wave. XCD swizzle.
// =========================================================================
template <bool RELU, bool RESID, bool FOUT, bool PACK>
__global__ __launch_bounds__(256, 3) void gemm_h(
    const short* __restrict__ A, int lda, const short* __restrict__ Wt,
    int ldw, int Klen, const float* __restrict__ bias,
    const float* __restrict__ resid, int ldr, int rmod,
    float* __restrict__ fout, int ldc, short* __restrict__ ph, int ldp) {
  __shared__ alignas(16) short sAh[8192], sBh[8192];
  const int tid = threadIdx.x;
  const unsigned Nt = gridDim.x;
  const unsigned lin = blockIdx.y * Nt + blockIdx.x;
  const unsigned cpx = (Nt * gridDim.y) >> 3;
  const unsigned swz = (lin & 7) * cpx + (lin >> 3);
  const int bn = (int)(swz % Nt) * 128, bm = (int)(swz / Nt) * 128;
  const int wave = tid >> 6, lane = tid & 63;
  const int wr = (wave >> 1) * 64, wc = (wave & 1) * 64;
  const int lr = lane & 15, sl = lane >> 4;
  const short* Ab = A + (size_t)bm * lda;
  const short* Wb = Wt + (size_t)bn * ldw;
  f32x4 acc[4][4] = {};
  for (int kk = 0; kk < Klen; kk += 64) {
#pragma unroll
    for (int jj = 0; jj < 4; ++jj) {
      const int G = jj * 256 + tid;
      const int srow = G >> 3, sl0 = G & 7;
      const int gsl = sl0 ^ (srow & 7);
      const int dst = G * 8;
      gload16(Ab + (size_t)srow * lda + kk + gsl * 8, &sAh[dst]);
      gload16(Wb + (size_t)srow * ldw + kk + gsl * 8, &sBh[dst]);
    }
    __syncthreads();
#pragma unroll
    for (int ks = 0; ks < 2; ++ks) {
      f16x8 aH[4], bH[4];
#pragma unroll
      for (int m = 0; m < 4; ++m) {
        const int r = wr + m * 16 + lr;
        aH[m] = *(const f16x8*)&sAh[r * 64 + (((ks * 4 + sl) ^ (r & 7)) * 8)];
      }
#pragma unroll
      for (int n = 0; n < 4; ++n) {
        const int r = wc + n * 16 + lr;
        bH[n] = *(const f16x8*)&sBh[r * 64 + (((ks * 4 + sl) ^ (r & 7)) * 8)];
      }
#pragma unroll
      for (int m = 0; m < 4; ++m)
#pragma unroll
        for (int n = 0; n < 4; ++n)
          acc[m][n] = __builtin_amdgcn_mfma_f32_16x16x32_f16(aH[m], bH[n],
                                                             acc[m][n], 0, 0, 0);
    }
    __syncthreads();
  }
  const int r4 = sl * 4;
#pragma unroll
  for (int m = 0; m < 4; ++m) {
#pragma unroll
    for (int r = 0; r < 4; ++r) {
      const int mm = bm + wr + m * 16 + r4 + r;
#pragma unroll
      for (int n = 0; n < 4; ++n) {
        const int col = bn + wc + n * 16 + lr;
        float v = acc[m][n][r] + bias[col];
        if (RELU) v = fmaxf(v, 0.f);
        if (RESID) {
          const int rr = rmod ? (mm % rmod) : mm;
          v += resid[(size_t)rr * ldr + col];
        }
        if (FOUT) fout[(size_t)mm * ldc + col] = v;
        if (PACK) ph[(size_t)mm * ldp + col] = f16b(v);
      }
    }
  }
}

// =========================================================================
// Conv z-pair, fp16: block does scales (zp*2, zp*2+1), K = 3 taps x 512
// each; accF = sum_z alpha[b,z]*(conv_z + cb_z) -> P[zp] f32 partial.
// hp: (BS,512) hi pack. wt: (12,512,512) hi. grid 768, 3 blocks/CU.
// (unchanged from round 6: 84.5 us/layer, MfmaUtil ~40%, conflicts 0)
// =========================================================================
__global__ __launch_bounds__(256, 3) void conv_zp_k(
    const short* __restrict__ hp, const short* __restrict__ wt,
    const float* __restrict__ cb, const float* __restrict__ alpha,
    const short* __restrict__ zpadS, float* __restrict__ P) {
  __shared__ alignas(16) short sAh[8192], sBh[8192];
  const int tid = threadIdx.x;
  const unsigned lin = blockIdx.x;
  const unsigned swz = (lin & 7) * 96 + (lin >> 3);
  const int zp = (int)(swz / 384);
  const unsigned rem = swz % 384;
  const int bn = (int)(rem & 3) * 128;
  const int bmt = (int)(rem >> 2);
  const int b = bmt / 6, s0 = (bmt % 6) * 128, gm0 = bmt * 128;
  const int wave = tid >> 6, lane = tid & 63;
  const int wr = (wave >> 1) * 64, wc = (wave & 1) * 64;
  const int lr = lane & 15, sl = lane >> 4;
  const short* hb = hp + (size_t)b * S * 512;
  f32x4 accF[4][4] = {};
#pragma unroll
  for (int zi = 0; zi < 2; ++zi) {
    const int z = zp * 2 + zi;
    f32x4 acc[4][4] = {};
    for (int kk = 0; kk < 1536; kk += 64) {
      const int tap = kk >> 9;
      const int koff = kk & 511;
      const int off = (tap - 1) << z;
#pragma unroll
      for (int jj = 0; jj < 4; ++jj) {
        const int G = jj * 256 + tid;
        const int srow = G >> 3, sl0 = G & 7;
        const int gsl = sl0 ^ (srow & 7);
        const int dst = G * 8;
        const int gs = s0 + srow + off;
        const bool inb = ((unsigned)gs < (unsigned)S);
        const short* aBase = hb + (size_t)gs * 512 + koff + gsl * 8;
        gload16(inb ? aBase : zpadS, &sAh[dst]);
        gload16(wt + ((size_t)((z * 3 + tap) * 512 + bn + srow)) * 512 + koff +
                    gsl * 8,
                &sBh[dst]);
      }
      __syncthreads();
#pragma unroll
      for (int ks = 0; ks < 2; ++ks) {
        f16x8 aH[4], bH[4];
#pragma unroll
        for (int m = 0; m < 4; ++m) {
          const int r = wr + m * 16 + lr;
          aH[m] =
              *(const f16x8*)&sAh[r * 64 + (((ks * 4 + sl) ^ (r & 7)) * 8)];
        }
#pragma unroll
        for (int n = 0; n < 4; ++n) {
          const int r = wc + n * 16 + lr;
          bH[n] =
              *(const f16x8*)&sBh[r * 64 + (((ks * 4 + sl) ^ (r & 7)) * 8)];
        }
#pragma unroll
        for (int m = 0; m < 4; ++m)
#pragma unroll
          for (int n = 0; n < 4; ++n)
            acc[m][n] = __builtin_amdgcn_mfma_f32_16x16x32_f16(
                aH[m], bH[n], acc[m][n], 0, 0, 0);
      }
      __syncthreads();
    }
    const float al = alpha[b * 4 + z];
#pragma unroll
    for (int n = 0; n < 4; ++n) {
      const float cbv = cb[z * D + bn + wc + n * 16 + lr];
#pragma unroll
      for (int m = 0; m < 4; ++m)
#pragma unroll
        for (int r = 0; r < 4; ++r)
          accF[m][n][r] += al * (acc[m][n][r] + cbv);
    }
  }
  float* Pz = P + (size_t)zp * ((size_t)BS * D);
  const int r4 = sl * 4;
#pragma unroll
  for (int m = 0; m < 4; ++m)
#pragma unroll
    for (int r = 0; r < 4; ++r) {
      const int mm = gm0 + wr + m * 16 + r4 + r;
#pragma unroll
      for (int n = 0; n < 4; ++n)
        Pz[(size_t)mm * D + bn + wc + n * 16 + lr] = accF[m][n][r];
    }
}

// ---- fused conv-combine + LN1 -> LN2 (SSM y cancels: shift-invariance) ---
// v = P0+P1+resid; h2 = LN2(LN1(v)); -> fout f32 + hi-pack to pout.
__global__ __launch_bounds__(256) void ln3_k(
    const float* __restrict__ P0, const float* __restrict__ P1,
    const float* __restrict__ resid, const float* __restrict__ g1,
    const float* __restrict__ b1, const float* __restrict__ g2,
    const float* __restrict__ b2, float* __restrict__ fout,
    short* __restrict__ pout) {
  const int row = blockIdx.x * 4 + (threadIdx.x >> 6);
  const int lane = threadIdx.x & 63;
  const size_t base = (size_t)row * D;
  float v[8];
  float s = 0.f;
#pragma unroll
  for (int j = 0; j < 8; ++j) {
    const int c = lane + 64 * j;
    v[j] = P0[base + c] + P1[base + c] + resid[base + c];
    s += v[j];
  }
  s = wave_sum(s);
  const float m1 = s * (1.f / D);
  float q = 0.f;
#pragma unroll
  for (int j = 0; j < 8; ++j) { const float d = v[j] - m1; q += d * d; }
  q = wave_sum(q);
  const float r1 = rsqrtf(q * (1.f / D) + EPS);
  float y[8];
  float s2 = 0.f;
#pragma unroll
  for (int j = 0; j < 8; ++j) {
    const int c = lane + 64 * j;
    y[j] = (v[j] - m1) * r1 * g1[c] + b1[c];
    s2 += y[j];
  }
  s2 = wave_sum(s2);
  const float m2 = s2 * (1.f / D);
  float q2 = 0.f;
#pragma unroll
  for (int j = 0; j < 8; ++j) { const float d = y[j] - m2; q2 += d * d; }
  q2 = wave_sum(q2);
  const float r2 = rsqrtf(q2 * (1.f / D) + EPS);
  float* frow = fout + base;
  short* prow = pout + (size_t)row * 512;
#pragma unroll
  for (int j = 0; j < 8; ++j) {
    const int c = lane + 64 * j;
    const float o = (y[j] - m2) * r2 * g2[c] + b2[c];
    frow[c] = o;
    prow[c] = f16b(o);
  }
}

// ---- partial column sums over S ------------------------------------------
__global__ __launch_bounds__(256) void colmean_part_k(
    const float* __restrict__ x, float* __restrict__ part) {
  const int b = blockIdx.x, c = blockIdx.y;
  const int s0 = c * 96;
  for (int d = threadIdx.x; d < D; d += 256) {
    float s = 0.f;
    for (int si = 0; si < 96; ++si)
      s += x[((size_t)b * S + s0 + si) * D + d];
    part[((size_t)b * 8 + c) * D + d] = s;
  }
}

// ---- W-pack hi-only: (K,N) f32 -> (N,K) fp16 bits ------------------------
__global__ __launch_bounds__(256) void pack_wh_k(const float* __restrict__ W,
                                                 short* __restrict__ out,
                                                 int K, int N, int ln2N) {
  const int idx = blockIdx.x * 256 + threadIdx.x;
  const int n = idx & (N - 1), k = idx >> ln2N;
  if (k >= K) return;
  out[(size_t)n * K + k] = f16b(W[(size_t)k * N + n]);
}

// ---- conv W-pack hi-only: (4,O,I,3) -> (12, O, I) fp16 bits --------------
__global__ __launch_bounds__(256) void pack_convw_k(
    const float* __restrict__ cw, short* __restrict__ out) {
  const int idx = blockIdx.x * 256 + threadIdx.x;  // 12*512*512
  const int c = idx & 511, o = (idx >> 9) & 511, seg = idx >> 18;
  const int i = seg / 3, t = seg % 3;
  out[((size_t)seg * D + o) * D + c] =
      f16b(cw[(((size_t)i * D + o) * D + c) * 3 + t]);
}

__global__ __launch_bounds__(256) void zero_k(float* __restrict__ p) {
  p[threadIdx.x] = 0.f;
  p[threadIdx.x + 256] = 0.f;
}

// ---- alpha = softmax(mean_s(h) @ wmw + wmb) ------------------------------
__global__ __launch_bounds__(64) void alpha_k(const float* __restrict__ part,
                                              const float* __restrict__ wmw,
                                              const float* __restrict__ wmb,
                                              float* __restrict__ alpha) {
  const int b = blockIdx.x, t = threadIdx.x;
  float p0 = 0, p1 = 0, p2 = 0, p3 = 0;
  for (int d = t; d < D; d += 64) {
    float xm = 0;
#pragma unroll
    for (int c = 0; c < 8; ++c) xm += part[((size_t)b * 8 + c) * D + d];
    xm *= (1.f / S);
    p0 += xm * wmw[d * 4 + 0];
    p1 += xm * wmw[d * 4 + 1];
    p2 += xm * wmw[d * 4 + 2];
    p3 += xm * wmw[d * 4 + 3];
  }
  p0 = wave_sum(p0); p1 = wave_sum(p1);
  p2 = wave_sum(p2); p3 = wave_sum(p3);
  if (t == 0) {
    const float l0 = p0 + wmb[0], l1 = p1 + wmb[1];
    const float l2 = p2 + wmb[2], l3 = p3 + wmb[3];
    const float mx = fmaxf(fmaxf(l0, l1), fmaxf(l2, l3));
    const float e0 = expf(l0 - mx), e1 = expf(l1 - mx);
    const float e2 = expf(l2 - mx), e3 = expf(l3 - mx);
    const float inv = 1.f / (e0 + e1 + e2 + e3);
    alpha[b * 4 + 0] = e0 * inv;
    alpha[b * 4 + 1] = e1 * inv;
    alpha[b * 4 + 2] = e2 * inv;
    alpha[b * 4 + 3] = e3 * inv;
  }
}

// ---- embedding gather-mean, hi-pack out ----------------------------------
__global__ __launch_bounds__(256) void embed_k(const int* __restrict__ xe,
                                               const float* __restrict__ emb,
                                               short* __restrict__ out) {
  const int r = blockIdx.x;
  int idx[8];
#pragma unroll
  for (int j = 0; j < 8; ++j) idx[j] = xe[r * 8 + j];
  short* o = out + (size_t)r * 512;
  for (int d = threadIdx.x; d < D; d += 256) {
    float s = 0.f;
#pragma unroll
    for (int j = 0; j < 8; ++j) s += emb[(size_t)idx[j] * D + d];
    o[d] = f16b(s * 0.125f);
  }
}

// ---- L2-normalize rows of (BS,64), hi-pack out ---------------------------
__global__ __launch_bounds__(256) void norml2_k(const float* __restrict__ x,
                                                short* __restrict__ out) {
  const int r = blockIdx.x * 4 + (threadIdx.x >> 6);
  const int lane = threadIdx.x & 63;
  const float v = x[(size_t)r * 64 + lane];
  const float s = wave_sum(v * v);
  const float nrm = fmaxf(sqrtf(s), 1e-12f);
  out[(size_t)r * 64 + lane] = f16b(v / nrm);
}

// ---- classifier head -----------------------------------------------------
__global__ __launch_bounds__(256) void head_k(
    const float* __restrict__ part, const float* __restrict__ pw1,
    const float* __restrict__ pb1, const float* __restrict__ pw2,
    const float* __restrict__ pb2, float* __restrict__ out) {
  __shared__ float hg[D];
  __shared__ float red[256];
  const int b = blockIdx.x, t = threadIdx.x;
  for (int d = t; d < D; d += 256) {
    float s = 0.f;
#pragma unroll
    for (int c = 0; c < 8; ++c) s += part[((size_t)b * 8 + c) * D + d];
    hg[d] = s * (1.f / S);
  }
  __syncthreads();
  float s = pb1[t];
  for (int d = 0; d < D; ++d) s = fmaf(hg[d], pw1[(size_t)d * 256 + t], s);
  s = fmaxf(s, 0.f);
  red[t] = s * pw2[t];
  __syncthreads();
  for (int o = 128; o > 0; o >>= 1) {
    if (t < o) red[t] += red[t + o];
    __syncthreads();
  }
  if (t == 0) out[b] = red[0] + pb2[0];
}

}  // namespace

extern "C" void kernel_launch(void* const* d_in, const int* in_sizes, int n_in,
                              void* d_out, int out_size, void* d_ws,
                              size_t ws_size, hipStream_t stream) {
  const float* x_cog = (const float*)d_in[0];
  const float* cw1 = (const float*)d_in[1];
  const float* cb1 = (const float*)d_in[2];
  const float* cw2 = (const float*)d_in[3];
  const float* cb2 = (const float*)d_in[4];
  const float* env_emb = (const float*)d_in[5];
  const float* ew1 = (const float*)d_in[6];
  const float* eb1 = (const float*)d_in[7];
  const float* ew2 = (const float*)d_in[8];
  const float* eb2 = (const float*)d_in[9];
  const float* fw1 = (const float*)d_in[10];
  const float* fb1 = (const float*)d_in[11];
  const float* fw2 = (const float*)d_in[12];
  const float* fb2 = (const float*)d_in[13];
  const float* pos_enc = (const float*)d_in[14];
  const float* conv_w = (const float*)d_in[15];
  const float* conv_b = (const float*)d_in[16];
  const float* wm_w = (const float*)d_in[17];
  const float* wm_b = (const float*)d_in[18];
  // d_in[19..21] = ssm_w/ssm_b/A_log: no-ops (y scalar-per-row cancels in LN2)
  const float* ffw1 = (const float*)d_in[22];
  const float* ffb1 = (const float*)d_in[23];
  const float* ffw2 = (const float*)d_in[24];
  const float* ffb2 = (const float*)d_in[25];
  const float* g1 = (const float*)d_in[26];
  const float* be1 = (const float*)d_in[27];
  const float* g2 = (const float*)d_in[28];
  const float* be2 = (const float*)d_in[29];
  const float* pw1 = (const float*)d_in[30];
  const float* pb1 = (const float*)d_in[31];
  const float* pw2 = (const float*)d_in[32];
  const float* pb2 = (const float*)d_in[33];
  const int* x_env = (const int*)d_in[34];
  float* out = (float*)d_out;

  // ---- arena (~141 MB) ----------------------------------------------------
  float* ws = (float*)d_ws;
  float* Hbuf = ws;                        // 6,291,456 f32 (running h)
  float* TBuf = Hbuf + 6291456;            // 6,291,456 f32 (h2)
  float* PARTb = TBuf + 6291456;           // 65,536
  float* ALPHAB = PARTb + 65536;           // 64
  float* ZPADF = ALPHAB + 64;              // 512 zero page
  short* R = (short*)(ZPADF + 512);
  // frontend regions (dead during layers):
  short* CONC = R;                         // 12288x2048 hi  [0, 25165824)
  short* PK1 = R + 25165824;               // 12288x512 hi   [25165824, 31457280)
  short* PK2 = R + 31457280;               // 12288x512 hi   [31457280, 37748736)
  short* WPBF = R + 37748736;              // frontend W pack [37748736, 38797312)
  // persistent across frontend->layers:
  short* HPACK = R + 38797312;             // 12288x512 hi   [38797312, 45088768)
  // layer regions (alias frontend regions):
  short* WCONV = R;                        // 12x512x512     [0, 3145728)
  short* WFFP = R + 3145728;               // 2048x512       [3145728, 4718592)
  float* convP = (float*)(R + 4718592);    // 2 x 6,291,456 f32 [4718592, 29884416)
  short* APFF = R + 4718592;               // 12288x2048 hi (aliases convP)

  const dim3 blk(256);
  const dim3 gS(4, 96, 1);    // N=512 tiles
  const dim3 gF(16, 96, 1);   // N=2048 tiles

  zero_k<<<1, blk, 0, stream>>>(ZPADF);

  // ---- frontend (all direct, fused epilogues) ----------------------------
  norml2_k<<<BS / 4, blk, 0, stream>>>(x_cog, PK1);
  pack_wh_k<<<64 * 512 / 256, blk, 0, stream>>>(cw1, WPBF, 64, 512, 9);
  gemm_h<true, false, false, true><<<gS, blk, 0, stream>>>(
      PK1, 64, WPBF, 64, 64, cb1, nullptr, 0, 0, nullptr, 0, PK2, 512);
  pack_wh_k<<<512 * 512 / 256, blk, 0, stream>>>(cw2, WPBF, 512, 512, 9);
  gemm_h<false, false, false, true><<<gS, blk, 0, stream>>>(
      PK2, 512, WPBF, 512, 512, cb2, nullptr, 0, 0, nullptr, 0, CONC, 2048);
  embed_k<<<BS, blk, 0, stream>>>(x_env, env_emb, PK1);
  pack_wh_k<<<512 * 512 / 256, blk, 0, stream>>>(ew1, WPBF, 512, 512, 9);
  gemm_h<true, false, false, true><<<gS, blk, 0, stream>>>(
      PK1, 512, WPBF, 512, 512, eb1, nullptr, 0, 0, nullptr, 0, PK2, 512);
  pack_wh_k<<<512 * 512 / 256, blk, 0, stream>>>(ew2, WPBF, 512, 512, 9);
  gemm_h<false, false, false, true><<<gS, blk, 0, stream>>>(
      PK2, 512, WPBF, 512, 512, eb2, nullptr, 0, 0, nullptr, 0, CONC + 512,
      2048);
  pack_wh_k<<<1024 * 512 / 256, blk, 0, stream>>>(fw1, WPBF, 1024, 512, 9);
  gemm_h<true, false, false, true><<<gS, blk, 0, stream>>>(
      CONC, 2048, WPBF, 1024, 1024, fb1, nullptr, 0, 0, nullptr, 0, PK1, 512);
  pack_wh_k<<<512 * 512 / 256, blk, 0, stream>>>(fw2, WPBF, 512, 512, 9);
  // h = relu-less(PK1@fw2 + fb2) + pos_enc -> Hbuf f32 + HPACK hi
  gemm_h<false, true, true, true><<<gS, blk, 0, stream>>>(
      PK1, 512, WPBF, 512, 512, fb2, pos_enc, 512, S, Hbuf, 512, HPACK, 512);

  // ---- layers -------------------------------------------------------------
  for (int l = 0; l < L; ++l) {
    colmean_part_k<<<dim3(B, 8), blk, 0, stream>>>(Hbuf, PARTb);
    alpha_k<<<B, dim3(64), 0, stream>>>(PARTb, wm_w + (size_t)l * D * 4,
                                        wm_b + l * 4, ALPHAB);
    pack_convw_k<<<12 * 512 * 512 / 256, blk, 0, stream>>>(
        conv_w + (size_t)l * 4 * D * D * 3, WCONV);
    conv_zp_k<<<768, blk, 0, stream>>>(HPACK, WCONV,
                                       conv_b + (size_t)l * 4 * D, ALPHAB,
                                       (const short*)ZPADF, convP);
    // h2 = LN2(LN1(P0+P1+h)) -> TBuf f32 + h2 hi-pack into HPACK slot
    ln3_k<<<BS / 4, blk, 0, stream>>>(convP, convP + 6291456, Hbuf, g1 + l * D,
                                      be1 + l * D, g2 + l * D, be2 + l * D,
                                      TBuf, HPACK);
    pack_wh_k<<<512 * 2048 / 256, blk, 0, stream>>>(ffw1 + (size_t)l * D * FF,
                                                    WFFP, 512, 2048, 11);
    gemm_h<true, false, false, true><<<gF, blk, 0, stream>>>(
        HPACK, 512, WFFP, 512, 512, ffb1 + (size_t)l * FF, nullptr, 0, 0,
        nullptr, 0, APFF, 2048);
    pack_wh_k<<<2048 * 512 / 256, blk, 0, stream>>>(ffw2 + (size_t)l * FF * D,
                                                    WFFP, 2048, 512, 9);
    // new h = APFF@ffw2 + ffb2 + h2 -> Hbuf f32 + next HPACK hi
    gemm_h<false, true, true, true><<<gS, blk, 0, stream>>>(
        APFF, 2048, WFFP, 2048, 2048, ffb2 + (size_t)l * D, TBuf, 512, 0,
        Hbuf, 512, HPACK, 512);
  }

  // ---- head ---------------------------------------------------------------
  colmean_part_k<<<dim3(B, 8), blk, 0, stream>>>(Hbuf, PARTb);
  head_k<<<B, blk, 0, stream>>>(PARTb, pw1, pb1, pw2, pb2, out);
}

// Round 8
// 1462.992 us; speedup vs baseline: 3.2713x; 1.0569x over previous
//
#include <hip/hip_runtime.h>
#include <cstdint>
#include <cstddef>

namespace {

constexpr int B = 16, S = 768, BS = B * S, D = 512, FF = 2048, L = 6;
constexpr float EPS = 1e-5f;

typedef float f32x4 __attribute__((ext_vector_type(4)));
typedef _Float16 f16x8 __attribute__((ext_vector_type(8)));

__device__ __forceinline__ float wave_sum(float v) {
#pragma unroll
  for (int o = 32; o > 0; o >>= 1) v += __shfl_xor(v, o, 64);
  return v;
}

__device__ __forceinline__ short f16b(float x) {
  const _Float16 h = (_Float16)x;
  return __builtin_bit_cast(short, h);
}

// ---- async global->LDS, 16B per lane ------------------------------------
__device__ __forceinline__ void gload16(const void* g, void* l) {
  __builtin_amdgcn_global_load_lds(
      (const __attribute__((address_space(1))) void*)g,
      (__attribute__((address_space(3))) void*)l, 16, 0, 0);
}

// LDS tile [rows][8 slots of 16B] (BK=64 halfs). Bank fix: global slot
// gsl = sl0 ^ (row&7); LDS stays linear (rule #21). Conflicts=0 proven.

// =========================================================================
// fp16 GEMM 128x128 (used for FF1, N=2048: grid 1536 = balanced 3/CU x2).
// Epilogue: bias, RELU?, RESID?, FOUT? f32, PACK? fp16.
// =========================================================================
template <bool RELU, bool RESID, bool FOUT, bool PACK>
__global__ __launch_bounds__(256, 3) void gemm_h(
    const short* __restrict__ A, int lda, const short* __restrict__ Wt,
    int ldw, int Klen, const float* __restrict__ bias,
    const float* __restrict__ resid, int ldr, int rmod,
    float* __restrict__ fout, int ldc, short* __restrict__ ph, int ldp) {
  __shared__ alignas(16) short sAh[8192], sBh[8192];
  const int tid = threadIdx.x;
  const unsigned Nt = gridDim.x;
  const unsigned lin = blockIdx.y * Nt + blockIdx.x;
  const unsigned cpx = (Nt * gridDim.y) >> 3;
  const unsigned swz = (lin & 7) * cpx + (lin >> 3);
  const int bn = (int)(swz % Nt) * 128, bm = (int)(swz / Nt) * 128;
  const int wave = tid >> 6, lane = tid & 63;
  const int wr = (wave >> 1) * 64, wc = (wave & 1) * 64;
  const int lr = lane & 15, sl = lane >> 4;
  const short* Ab = A + (size_t)bm * lda;
  const short* Wb = Wt + (size_t)bn * ldw;
  f32x4 acc[4][4] = {};
  for (int kk = 0; kk < Klen; kk += 64) {
#pragma unroll
    for (int jj = 0; jj < 4; ++jj) {
      const int G = jj * 256 + tid;
      const int srow = G >> 3, sl0 = G & 7;
      const int gsl = sl0 ^ (srow & 7);
      const int dst = G * 8;
      gload16(Ab + (size_t)srow * lda + kk + gsl * 8, &sAh[dst]);
      gload16(Wb + (size_t)srow * ldw + kk + gsl * 8, &sBh[dst]);
    }
    __syncthreads();
#pragma unroll
    for (int ks = 0; ks < 2; ++ks) {
      f16x8 aH[4], bH[4];
#pragma unroll
      for (int m = 0; m < 4; ++m) {
        const int r = wr + m * 16 + lr;
        aH[m] = *(const f16x8*)&sAh[r * 64 + (((ks * 4 + sl) ^ (r & 7)) * 8)];
      }
#pragma unroll
      for (int n = 0; n < 4; ++n) {
        const int r = wc + n * 16 + lr;
        bH[n] = *(const f16x8*)&sBh[r * 64 + (((ks * 4 + sl) ^ (r & 7)) * 8)];
      }
#pragma unroll
      for (int m = 0; m < 4; ++m)
#pragma unroll
        for (int n = 0; n < 4; ++n)
          acc[m][n] = __builtin_amdgcn_mfma_f32_16x16x32_f16(aH[m], bH[n],
                                                             acc[m][n], 0, 0, 0);
    }
    __syncthreads();
  }
  const int r4 = sl * 4;
#pragma unroll
  for (int m = 0; m < 4; ++m) {
#pragma unroll
    for (int r = 0; r < 4; ++r) {
      const int mm = bm + wr + m * 16 + r4 + r;
#pragma unroll
      for (int n = 0; n < 4; ++n) {
        const int col = bn + wc + n * 16 + lr;
        float v = acc[m][n][r] + bias[col];
        if (RELU) v = fmaxf(v, 0.f);
        if (RESID) {
          const int rr = rmod ? (mm % rmod) : mm;
          v += resid[(size_t)rr * ldr + col];
        }
        if (FOUT) fout[(size_t)mm * ldc + col] = v;
        if (PACK) ph[(size_t)mm * ldp + col] = f16b(v);
      }
    }
  }
}

// =========================================================================
// fp16 GEMM 128x64 (for all N=512 GEMMs: grid (8,96)=768 = 3 blocks/CU,
// balanced, vs 384 = 1.5/CU with 128x128). Waves 2x2, wave-tile 64x32.
// LDS 24KB. Same source-swizzled staging, same epilogue options.
// =========================================================================
template <bool RELU, bool RESID, bool FOUT, bool PACK>
__global__ __launch_bounds__(256, 3) void gemm_h64(
    const short* __restrict__ A, int lda, const short* __restrict__ Wt,
    int ldw, int Klen, const float* __restrict__ bias,
    const float* __restrict__ resid, int ldr, int rmod,
    float* __restrict__ fout, int ldc, short* __restrict__ ph, int ldp) {
  __shared__ alignas(16) short sAh[8192], sBh[4096];
  const int tid = threadIdx.x;
  const unsigned Nt = gridDim.x;  // 8
  const unsigned lin = blockIdx.y * Nt + blockIdx.x;
  const unsigned cpx = (Nt * gridDim.y) >> 3;
  const unsigned swz = (lin & 7) * cpx + (lin >> 3);
  const int bn = (int)(swz % Nt) * 64, bm = (int)(swz / Nt) * 128;
  const int wave = tid >> 6, lane = tid & 63;
  const int wr = (wave >> 1) * 64, wc = (wave & 1) * 32;
  const int lr = lane & 15, sl = lane >> 4;
  const short* Ab = A + (size_t)bm * lda;
  const short* Wb = Wt + (size_t)bn * ldw;
  f32x4 acc[4][2] = {};
  for (int kk = 0; kk < Klen; kk += 64) {
#pragma unroll
    for (int jj = 0; jj < 4; ++jj) {
      const int G = jj * 256 + tid;
      const int srow = G >> 3, sl0 = G & 7;
      const int gsl = sl0 ^ (srow & 7);
      gload16(Ab + (size_t)srow * lda + kk + gsl * 8, &sAh[G * 8]);
    }
#pragma unroll
    for (int jj = 0; jj < 2; ++jj) {
      const int G = jj * 256 + tid;
      const int srow = G >> 3, sl0 = G & 7;
      const int gsl = sl0 ^ (srow & 7);
      gload16(Wb + (size_t)srow * ldw + kk + gsl * 8, &sBh[G * 8]);
    }
    __syncthreads();
#pragma unroll
    for (int ks = 0; ks < 2; ++ks) {
      f16x8 aH[4], bH[2];
#pragma unroll
      for (int m = 0; m < 4; ++m) {
        const int r = wr + m * 16 + lr;
        aH[m] = *(const f16x8*)&sAh[r * 64 + (((ks * 4 + sl) ^ (r & 7)) * 8)];
      }
#pragma unroll
      for (int n = 0; n < 2; ++n) {
        const int r = wc + n * 16 + lr;
        bH[n] = *(const f16x8*)&sBh[r * 64 + (((ks * 4 + sl) ^ (r & 7)) * 8)];
      }
#pragma unroll
      for (int m = 0; m < 4; ++m)
#pragma unroll
        for (int n = 0; n < 2; ++n)
          acc[m][n] = __builtin_amdgcn_mfma_f32_16x16x32_f16(aH[m], bH[n],
                                                             acc[m][n], 0, 0, 0);
    }
    __syncthreads();
  }
  const int r4 = sl * 4;
#pragma unroll
  for (int m = 0; m < 4; ++m) {
#pragma unroll
    for (int r = 0; r < 4; ++r) {
      const int mm = bm + wr + m * 16 + r4 + r;
#pragma unroll
      for (int n = 0; n < 2; ++n) {
        const int col = bn + wc + n * 16 + lr;
        float v = acc[m][n][r] + bias[col];
        if (RELU) v = fmaxf(v, 0.f);
        if (RESID) {
          const int rr = rmod ? (mm % rmod) : mm;
          v += resid[(size_t)rr * ldr + col];
        }
        if (FOUT) fout[(size_t)mm * ldc + col] = v;
        if (PACK) ph[(size_t)mm * ldp + col] = f16b(v);
      }
    }
  }
}

// =========================================================================
// Conv z-pair, fp16 (unchanged: 84.5 us/layer, 914 TF, conflicts 0).
// =========================================================================
__global__ __launch_bounds__(256, 3) void conv_zp_k(
    const short* __restrict__ hp, const short* __restrict__ wt,
    const float* __restrict__ cb, const float* __restrict__ alpha,
    const short* __restrict__ zpadS, float* __restrict__ P) {
  __shared__ alignas(16) short sAh[8192], sBh[8192];
  const int tid = threadIdx.x;
  const unsigned lin = blockIdx.x;
  const unsigned swz = (lin & 7) * 96 + (lin >> 3);
  const int zp = (int)(swz / 384);
  const unsigned rem = swz % 384;
  const int bn = (int)(rem & 3) * 128;
  const int bmt = (int)(rem >> 2);
  const int b = bmt / 6, s0 = (bmt % 6) * 128, gm0 = bmt * 128;
  const int wave = tid >> 6, lane = tid & 63;
  const int wr = (wave >> 1) * 64, wc = (wave & 1) * 64;
  const int lr = lane & 15, sl = lane >> 4;
  const short* hb = hp + (size_t)b * S * 512;
  f32x4 accF[4][4] = {};
#pragma unroll
  for (int zi = 0; zi < 2; ++zi) {
    const int z = zp * 2 + zi;
    f32x4 acc[4][4] = {};
    for (int kk = 0; kk < 1536; kk += 64) {
      const int tap = kk >> 9;
      const int koff = kk & 511;
      const int off = (tap - 1) << z;
#pragma unroll
      for (int jj = 0; jj < 4; ++jj) {
        const int G = jj * 256 + tid;
        const int srow = G >> 3, sl0 = G & 7;
        const int gsl = sl0 ^ (srow & 7);
        const int dst = G * 8;
        const int gs = s0 + srow + off;
        const bool inb = ((unsigned)gs < (unsigned)S);
        const short* aBase = hb + (size_t)gs * 512 + koff + gsl * 8;
        gload16(inb ? aBase : zpadS, &sAh[dst]);
        gload16(wt + ((size_t)((z * 3 + tap) * 512 + bn + srow)) * 512 + koff +
                    gsl * 8,
                &sBh[dst]);
      }
      __syncthreads();
#pragma unroll
      for (int ks = 0; ks < 2; ++ks) {
        f16x8 aH[4], bH[4];
#pragma unroll
        for (int m = 0; m < 4; ++m) {
          const int r = wr + m * 16 + lr;
          aH[m] =
              *(const f16x8*)&sAh[r * 64 + (((ks * 4 + sl) ^ (r & 7)) * 8)];
        }
#pragma unroll
        for (int n = 0; n < 4; ++n) {
          const int r = wc + n * 16 + lr;
          bH[n] =
              *(const f16x8*)&sBh[r * 64 + (((ks * 4 + sl) ^ (r & 7)) * 8)];
        }
#pragma unroll
        for (int m = 0; m < 4; ++m)
#pragma unroll
          for (int n = 0; n < 4; ++n)
            acc[m][n] = __builtin_amdgcn_mfma_f32_16x16x32_f16(
                aH[m], bH[n], acc[m][n], 0, 0, 0);
      }
      __syncthreads();
    }
    const float al = alpha[b * 4 + z];
#pragma unroll
    for (int n = 0; n < 4; ++n) {
      const float cbv = cb[z * D + bn + wc + n * 16 + lr];
#pragma unroll
      for (int m = 0; m < 4; ++m)
#pragma unroll
        for (int r = 0; r < 4; ++r)
          accF[m][n][r] += al * (acc[m][n][r] + cbv);
    }
  }
  float* Pz = P + (size_t)zp * ((size_t)BS * D);
  const int r4 = sl * 4;
#pragma unroll
  for (int m = 0; m < 4; ++m)
#pragma unroll
    for (int r = 0; r < 4; ++r) {
      const int mm = gm0 + wr + m * 16 + r4 + r;
#pragma unroll
      for (int n = 0; n < 4; ++n)
        Pz[(size_t)mm * D + bn + wc + n * 16 + lr] = accF[m][n][r];
    }
}

// ---- fused conv-combine + LN1 -> LN2 (SSM y cancels: shift-invariance) ---
__global__ __launch_bounds__(256) void ln3_k(
    const float* __restrict__ P0, const float* __restrict__ P1,
    const float* __restrict__ resid, const float* __restrict__ g1,
    const float* __restrict__ b1, const float* __restrict__ g2,
    const float* __restrict__ b2, float* __restrict__ fout,
    short* __restrict__ pout) {
  const int row = blockIdx.x * 4 + (threadIdx.x >> 6);
  const int lane = threadIdx.x & 63;
  const size_t base = (size_t)row * D;
  float v[8];
  float s = 0.f;
#pragma unroll
  for (int j = 0; j < 8; ++j) {
    const int c = lane + 64 * j;
    v[j] = P0[base + c] + P1[base + c] + resid[base + c];
    s += v[j];
  }
  s = wave_sum(s);
  const float m1 = s * (1.f / D);
  float q = 0.f;
#pragma unroll
  for (int j = 0; j < 8; ++j) { const float d = v[j] - m1; q += d * d; }
  q = wave_sum(q);
  const float r1 = rsqrtf(q * (1.f / D) + EPS);
  float y[8];
  float s2 = 0.f;
#pragma unroll
  for (int j = 0; j < 8; ++j) {
    const int c = lane + 64 * j;
    y[j] = (v[j] - m1) * r1 * g1[c] + b1[c];
    s2 += y[j];
  }
  s2 = wave_sum(s2);
  const float m2 = s2 * (1.f / D);
  float q2 = 0.f;
#pragma unroll
  for (int j = 0; j < 8; ++j) { const float d = y[j] - m2; q2 += d * d; }
  q2 = wave_sum(q2);
  const float r2 = rsqrtf(q2 * (1.f / D) + EPS);
  float* frow = fout + base;
  short* prow = pout + (size_t)row * 512;
#pragma unroll
  for (int j = 0; j < 8; ++j) {
    const int c = lane + 64 * j;
    const float o = (y[j] - m2) * r2 * g2[c] + b2[c];
    frow[c] = o;
    prow[c] = f16b(o);
  }
}

// ---- partial column sums over S ------------------------------------------
__global__ __launch_bounds__(256) void colmean_part_k(
    const float* __restrict__ x, float* __restrict__ part) {
  const int b = blockIdx.x, c = blockIdx.y;
  const int s0 = c * 96;
  for (int d = threadIdx.x; d < D; d += 256) {
    float s = 0.f;
    for (int si = 0; si < 96; ++si)
      s += x[((size_t)b * S + s0 + si) * D + d];
    part[((size_t)b * 8 + c) * D + d] = s;
  }
}

// ---- W-pack hi-only: (K,N) f32 -> (N,K) fp16 bits ------------------------
__global__ __launch_bounds__(256) void pack_wh_k(const float* __restrict__ W,
                                                 short* __restrict__ out,
                                                 int K, int N, int ln2N) {
  const int idx = blockIdx.x * 256 + threadIdx.x;
  const int n = idx & (N - 1), k = idx >> ln2N;
  if (k >= K) return;
  out[(size_t)n * K + k] = f16b(W[(size_t)k * N + n]);
}

// ---- conv W-pack hi-only: (4,O,I,3) -> (12, O, I) fp16 bits --------------
__global__ __launch_bounds__(256) void pack_convw_k(
    const float* __restrict__ cw, short* __restrict__ out) {
  const int idx = blockIdx.x * 256 + threadIdx.x;  // 12*512*512
  const int c = idx & 511, o = (idx >> 9) & 511, seg = idx >> 18;
  const int i = seg / 3, t = seg % 3;
  out[((size_t)seg * D + o) * D + c] =
      f16b(cw[(((size_t)i * D + o) * D + c) * 3 + t]);
}

__global__ __launch_bounds__(256) void zero_k(float* __restrict__ p) {
  p[threadIdx.x] = 0.f;
  p[threadIdx.x + 256] = 0.f;
}

// ---- alpha = softmax(mean_s(h) @ wmw + wmb) ------------------------------
__global__ __launch_bounds__(64) void alpha_k(const float* __restrict__ part,
                                              const float* __restrict__ wmw,
                                              const float* __restrict__ wmb,
                                              float* __restrict__ alpha) {
  const int b = blockIdx.x, t = threadIdx.x;
  float p0 = 0, p1 = 0, p2 = 0, p3 = 0;
  for (int d = t; d < D; d += 64) {
    float xm = 0;
#pragma unroll
    for (int c = 0; c < 8; ++c) xm += part[((size_t)b * 8 + c) * D + d];
    xm *= (1.f / S);
    p0 += xm * wmw[d * 4 + 0];
    p1 += xm * wmw[d * 4 + 1];
    p2 += xm * wmw[d * 4 + 2];
    p3 += xm * wmw[d * 4 + 3];
  }
  p0 = wave_sum(p0); p1 = wave_sum(p1);
  p2 = wave_sum(p2); p3 = wave_sum(p3);
  if (t == 0) {
    const float l0 = p0 + wmb[0], l1 = p1 + wmb[1];
    const float l2 = p2 + wmb[2], l3 = p3 + wmb[3];
    const float mx = fmaxf(fmaxf(l0, l1), fmaxf(l2, l3));
    const float e0 = expf(l0 - mx), e1 = expf(l1 - mx);
    const float e2 = expf(l2 - mx), e3 = expf(l3 - mx);
    const float inv = 1.f / (e0 + e1 + e2 + e3);
    alpha[b * 4 + 0] = e0 * inv;
    alpha[b * 4 + 1] = e1 * inv;
    alpha[b * 4 + 2] = e2 * inv;
    alpha[b * 4 + 3] = e3 * inv;
  }
}

// ---- embedding gather-mean, hi-pack out ----------------------------------
__global__ __launch_bounds__(256) void embed_k(const int* __restrict__ xe,
                                               const float* __restrict__ emb,
                                               short* __restrict__ out) {
  const int r = blockIdx.x;
  int idx[8];
#pragma unroll
  for (int j = 0; j < 8; ++j) idx[j] = xe[r * 8 + j];
  short* o = out + (size_t)r * 512;
  for (int d = threadIdx.x; d < D; d += 256) {
    float s = 0.f;
#pragma unroll
    for (int j = 0; j < 8; ++j) s += emb[(size_t)idx[j] * D + d];
    o[d] = f16b(s * 0.125f);
  }
}

// ---- L2-normalize rows of (BS,64), hi-pack out ---------------------------
__global__ __launch_bounds__(256) void norml2_k(const float* __restrict__ x,
                                                short* __restrict__ out) {
  const int r = blockIdx.x * 4 + (threadIdx.x >> 6);
  const int lane = threadIdx.x & 63;
  const float v = x[(size_t)r * 64 + lane];
  const float s = wave_sum(v * v);
  const float nrm = fmaxf(sqrtf(s), 1e-12f);
  out[(size_t)r * 64 + lane] = f16b(v / nrm);
}

// ---- classifier head -----------------------------------------------------
__global__ __launch_bounds__(256) void head_k(
    const float* __restrict__ part, const float* __restrict__ pw1,
    const float* __restrict__ pb1, const float* __restrict__ pw2,
    const float* __restrict__ pb2, float* __restrict__ out) {
  __shared__ float hg[D];
  __shared__ float red[256];
  const int b = blockIdx.x, t = threadIdx.x;
  for (int d = t; d < D; d += 256) {
    float s = 0.f;
#pragma unroll
    for (int c = 0; c < 8; ++c) s += part[((size_t)b * 8 + c) * D + d];
    hg[d] = s * (1.f / S);
  }
  __syncthreads();
  float s = pb1[t];
  for (int d = 0; d < D; ++d) s = fmaf(hg[d], pw1[(size_t)d * 256 + t], s);
  s = fmaxf(s, 0.f);
  red[t] = s * pw2[t];
  __syncthreads();
  for (int o = 128; o > 0; o >>= 1) {
    if (t < o) red[t] += red[t + o];
    __syncthreads();
  }
  if (t == 0) out[b] = red[0] + pb2[0];
}

}  // namespace

extern "C" void kernel_launch(void* const* d_in, const int* in_sizes, int n_in,
                              void* d_out, int out_size, void* d_ws,
                              size_t ws_size, hipStream_t stream) {
  const float* x_cog = (const float*)d_in[0];
  const float* cw1 = (const float*)d_in[1];
  const float* cb1 = (const float*)d_in[2];
  const float* cw2 = (const float*)d_in[3];
  const float* cb2 = (const float*)d_in[4];
  const float* env_emb = (const float*)d_in[5];
  const float* ew1 = (const float*)d_in[6];
  const float* eb1 = (const float*)d_in[7];
  const float* ew2 = (const float*)d_in[8];
  const float* eb2 = (const float*)d_in[9];
  const float* fw1 = (const float*)d_in[10];
  const float* fb1 = (const float*)d_in[11];
  const float* fw2 = (const float*)d_in[12];
  const float* fb2 = (const float*)d_in[13];
  const float* pos_enc = (const float*)d_in[14];
  const float* conv_w = (const float*)d_in[15];
  const float* conv_b = (const float*)d_in[16];
  const float* wm_w = (const float*)d_in[17];
  const float* wm_b = (const float*)d_in[18];
  // d_in[19..21] = ssm_w/ssm_b/A_log: no-ops (y scalar-per-row cancels in LN2)
  const float* ffw1 = (const float*)d_in[22];
  const float* ffb1 = (const float*)d_in[23];
  const float* ffw2 = (const float*)d_in[24];
  const float* ffb2 = (const float*)d_in[25];
  const float* g1 = (const float*)d_in[26];
  const float* be1 = (const float*)d_in[27];
  const float* g2 = (const float*)d_in[28];
  const float* be2 = (const float*)d_in[29];
  const float* pw1 = (const float*)d_in[30];
  const float* pb1 = (const float*)d_in[31];
  const float* pw2 = (const float*)d_in[32];
  const float* pb2 = (const float*)d_in[33];
  const int* x_env = (const int*)d_in[34];
  float* out = (float*)d_out;

  // ---- arena (~141 MB) ----------------------------------------------------
  float* ws = (float*)d_ws;
  float* Hbuf = ws;                        // 6,291,456 f32 (running h)
  float* TBuf = Hbuf + 6291456;            // 6,291,456 f32 (h2)
  float* PARTb = TBuf + 6291456;           // 65,536
  float* ALPHAB = PARTb + 65536;           // 64
  float* ZPADF = ALPHAB + 64;              // 512 zero page
  short* R = (short*)(ZPADF + 512);
  // frontend regions (dead during layers):
  short* CONC = R;                         // 12288x2048 hi  [0, 25165824)
  short* PK1 = R + 25165824;               // 12288x512 hi
  short* PK2 = R + 31457280;               // 12288x512 hi
  short* WPBF = R + 37748736;              // frontend W pack
  // persistent across frontend->layers:
  short* HPACK = R + 38797312;             // 12288x512 hi
  // layer regions (alias frontend regions):
  short* WCONV = R;                        // 12x512x512
  short* WFFP = R + 3145728;               // 2048x512
  float* convP = (float*)(R + 4718592);    // 2 x 6,291,456 f32
  short* APFF = R + 4718592;               // 12288x2048 hi (aliases convP)

  const dim3 blk(256);
  const dim3 gS(8, 96, 1);    // N=512, BN=64 tiles -> 768 blocks (3/CU)
  const dim3 gF(16, 96, 1);   // N=2048, BN=128 tiles -> 1536 blocks

  zero_k<<<1, blk, 0, stream>>>(ZPADF);

  // ---- frontend (all direct, fused epilogues, balanced grids) ------------
  norml2_k<<<BS / 4, blk, 0, stream>>>(x_cog, PK1);
  pack_wh_k<<<64 * 512 / 256, blk, 0, stream>>>(cw1, WPBF, 64, 512, 9);
  gemm_h64<true, false, false, true><<<gS, blk, 0, stream>>>(
      PK1, 64, WPBF, 64, 64, cb1, nullptr, 0, 0, nullptr, 0, PK2, 512);
  pack_wh_k<<<512 * 512 / 256, blk, 0, stream>>>(cw2, WPBF, 512, 512, 9);
  gemm_h64<false, false, false, true><<<gS, blk, 0, stream>>>(
      PK2, 512, WPBF, 512, 512, cb2, nullptr, 0, 0, nullptr, 0, CONC, 2048);
  embed_k<<<BS, blk, 0, stream>>>(x_env, env_emb, PK1);
  pack_wh_k<<<512 * 512 / 256, blk, 0, stream>>>(ew1, WPBF, 512, 512, 9);
  gemm_h64<true, false, false, true><<<gS, blk, 0, stream>>>(
      PK1, 512, WPBF, 512, 512, eb1, nullptr, 0, 0, nullptr, 0, PK2, 512);
  pack_wh_k<<<512 * 512 / 256, blk, 0, stream>>>(ew2, WPBF, 512, 512, 9);
  gemm_h64<false, false, false, true><<<gS, blk, 0, stream>>>(
      PK2, 512, WPBF, 512, 512, eb2, nullptr, 0, 0, nullptr, 0, CONC + 512,
      2048);
  pack_wh_k<<<1024 * 512 / 256, blk, 0, stream>>>(fw1, WPBF, 1024, 512, 9);
  gemm_h64<true, false, false, true><<<gS, blk, 0, stream>>>(
      CONC, 2048, WPBF, 1024, 1024, fb1, nullptr, 0, 0, nullptr, 0, PK1, 512);
  pack_wh_k<<<512 * 512 / 256, blk, 0, stream>>>(fw2, WPBF, 512, 512, 9);
  // h = (PK1@fw2 + fb2) + pos_enc -> Hbuf f32 + HPACK hi
  gemm_h64<false, true, true, true><<<gS, blk, 0, stream>>>(
      PK1, 512, WPBF, 512, 512, fb2, pos_enc, 512, S, Hbuf, 512, HPACK, 512);

  // ---- layers -------------------------------------------------------------
  for (int l = 0; l < L; ++l) {
    colmean_part_k<<<dim3(B, 8), blk, 0, stream>>>(Hbuf, PARTb);
    alpha_k<<<B, dim3(64), 0, stream>>>(PARTb, wm_w + (size_t)l * D * 4,
                                        wm_b + l * 4, ALPHAB);
    pack_convw_k<<<12 * 512 * 512 / 256, blk, 0, stream>>>(
        conv_w + (size_t)l * 4 * D * D * 3, WCONV);
    conv_zp_k<<<768, blk, 0, stream>>>(HPACK, WCONV,
                                       conv_b + (size_t)l * 4 * D, ALPHAB,
                                       (const short*)ZPADF, convP);
    // h2 = LN2(LN1(P0+P1+h)) -> TBuf f32 + h2 hi-pack into HPACK slot
    ln3_k<<<BS / 4, blk, 0, stream>>>(convP, convP + 6291456, Hbuf, g1 + l * D,
                                      be1 + l * D, g2 + l * D, be2 + l * D,
                                      TBuf, HPACK);
    pack_wh_k<<<512 * 2048 / 256, blk, 0, stream>>>(ffw1 + (size_t)l * D * FF,
                                                    WFFP, 512, 2048, 11);
    gemm_h<true, false, false, true><<<gF, blk, 0, stream>>>(
        HPACK, 512, WFFP, 512, 512, ffb1 + (size_t)l * FF, nullptr, 0, 0,
        nullptr, 0, APFF, 2048);
    pack_wh_k<<<2048 * 512 / 256, blk, 0, stream>>>(ffw2 + (size_t)l * FF * D,
                                                    WFFP, 2048, 512, 9);
    // new h = APFF@ffw2 + ffb2 + h2 -> Hbuf f32 + next HPACK hi
    gemm_h64<false, true, true, true><<<gS, blk, 0, stream>>>(
        APFF, 2048, WFFP, 2048, 2048, ffb2 + (size_t)l * D, TBuf, 512, 0,
        Hbuf, 512, HPACK, 512);
  }

  // ---- head ---------------------------------------------------------------
  colmean_part_k<<<dim3(B, 8), blk, 0, stream>>>(Hbuf, PARTb);
  head_k<<<B, blk, 0, stream>>>(PARTb, pw1, pb1, pw2, pb2, out);
}

// Round 9
// 1376.251 us; speedup vs baseline: 3.4775x; 1.0630x over previous
//
#include <hip/hip_runtime.h>
#include <cstdint>
#include <cstddef>

namespace {

constexpr int B = 16, S = 768, BS = B * S, D = 512, FF = 2048, L = 6;
constexpr float EPS = 1e-5f;

typedef float f32x4 __attribute__((ext_vector_type(4)));
typedef _Float16 f16x8 __attribute__((ext_vector_type(8)));

__device__ __forceinline__ float wave_sum(float v) {
#pragma unroll
  for (int o = 32; o > 0; o >>= 1) v += __shfl_xor(v, o, 64);
  return v;
}

__device__ __forceinline__ short f16b(float x) {
  const _Float16 h = (_Float16)x;
  return __builtin_bit_cast(short, h);
}

// ---- async global->LDS, 16B per lane ------------------------------------
__device__ __forceinline__ void gload16(const void* g, void* l) {
  __builtin_amdgcn_global_load_lds(
      (const __attribute__((address_space(1))) void*)g,
      (__attribute__((address_space(3))) void*)l, 16, 0, 0);
}

// LDS tile [rows][8 slots of 16B] (BK=64 halfs). Bank fix: global slot
// gsl = sl0 ^ (row&7); LDS stays linear (rule #21). Conflicts=0 proven.

// =========================================================================
// fp16 GEMM 128x128 (FF1, N=2048: grid 1536, balanced).
// =========================================================================
template <bool RELU, bool RESID, bool FOUT, bool PACK>
__global__ __launch_bounds__(256, 3) void gemm_h(
    const short* __restrict__ A, int lda, const short* __restrict__ Wt,
    int ldw, int Klen, const float* __restrict__ bias,
    const float* __restrict__ resid, int ldr, int rmod,
    float* __restrict__ fout, int ldc, short* __restrict__ ph, int ldp) {
  __shared__ alignas(16) short sAh[8192], sBh[8192];
  const int tid = threadIdx.x;
  const unsigned Nt = gridDim.x;
  const unsigned lin = blockIdx.y * Nt + blockIdx.x;
  const unsigned cpx = (Nt * gridDim.y) >> 3;
  const unsigned swz = (lin & 7) * cpx + (lin >> 3);
  const int bn = (int)(swz % Nt) * 128, bm = (int)(swz / Nt) * 128;
  const int wave = tid >> 6, lane = tid & 63;
  const int wr = (wave >> 1) * 64, wc = (wave & 1) * 64;
  const int lr = lane & 15, sl = lane >> 4;
  const short* Ab = A + (size_t)bm * lda;
  const short* Wb = Wt + (size_t)bn * ldw;
  f32x4 acc[4][4] = {};
  for (int kk = 0; kk < Klen; kk += 64) {
#pragma unroll
    for (int jj = 0; jj < 4; ++jj) {
      const int G = jj * 256 + tid;
      const int srow = G >> 3, sl0 = G & 7;
      const int gsl = sl0 ^ (srow & 7);
      const int dst = G * 8;
      gload16(Ab + (size_t)srow * lda + kk + gsl * 8, &sAh[dst]);
      gload16(Wb + (size_t)srow * ldw + kk + gsl * 8, &sBh[dst]);
    }
    __syncthreads();
#pragma unroll
    for (int ks = 0; ks < 2; ++ks) {
      f16x8 aH[4], bH[4];
#pragma unroll
      for (int m = 0; m < 4; ++m) {
        const int r = wr + m * 16 + lr;
        aH[m] = *(const f16x8*)&sAh[r * 64 + (((ks * 4 + sl) ^ (r & 7)) * 8)];
      }
#pragma unroll
      for (int n = 0; n < 4; ++n) {
        const int r = wc + n * 16 + lr;
        bH[n] = *(const f16x8*)&sBh[r * 64 + (((ks * 4 + sl) ^ (r & 7)) * 8)];
      }
#pragma unroll
      for (int m = 0; m < 4; ++m)
#pragma unroll
        for (int n = 0; n < 4; ++n)
          acc[m][n] = __builtin_amdgcn_mfma_f32_16x16x32_f16(aH[m], bH[n],
                                                             acc[m][n], 0, 0, 0);
    }
    __syncthreads();
  }
  const int r4 = sl * 4;
#pragma unroll
  for (int m = 0; m < 4; ++m) {
#pragma unroll
    for (int r = 0; r < 4; ++r) {
      const int mm = bm + wr + m * 16 + r4 + r;
#pragma unroll
      for (int n = 0; n < 4; ++n) {
        const int col = bn + wc + n * 16 + lr;
        float v = acc[m][n][r] + bias[col];
        if (RELU) v = fmaxf(v, 0.f);
        if (RESID) {
          const int rr = rmod ? (mm % rmod) : mm;
          v += resid[(size_t)rr * ldr + col];
        }
        if (FOUT) fout[(size_t)mm * ldc + col] = v;
        if (PACK) ph[(size_t)mm * ldp + col] = f16b(v);
      }
    }
  }
}

// =========================================================================
// fp16 GEMM 128x64 (all N=512 GEMMs: grid 768 = 3 blocks/CU balanced).
// =========================================================================
template <bool RELU, bool RESID, bool FOUT, bool PACK>
__global__ __launch_bounds__(256, 3) void gemm_h64(
    const short* __restrict__ A, int lda, const short* __restrict__ Wt,
    int ldw, int Klen, const float* __restrict__ bias,
    const float* __restrict__ resid, int ldr, int rmod,
    float* __restrict__ fout, int ldc, short* __restrict__ ph, int ldp) {
  __shared__ alignas(16) short sAh[8192], sBh[4096];
  const int tid = threadIdx.x;
  const unsigned Nt = gridDim.x;  // 8
  const unsigned lin = blockIdx.y * Nt + blockIdx.x;
  const unsigned cpx = (Nt * gridDim.y) >> 3;
  const unsigned swz = (lin & 7) * cpx + (lin >> 3);
  const int bn = (int)(swz % Nt) * 64, bm = (int)(swz / Nt) * 128;
  const int wave = tid >> 6, lane = tid & 63;
  const int wr = (wave >> 1) * 64, wc = (wave & 1) * 32;
  const int lr = lane & 15, sl = lane >> 4;
  const short* Ab = A + (size_t)bm * lda;
  const short* Wb = Wt + (size_t)bn * ldw;
  f32x4 acc[4][2] = {};
  for (int kk = 0; kk < Klen; kk += 64) {
#pragma unroll
    for (int jj = 0; jj < 4; ++jj) {
      const int G = jj * 256 + tid;
      const int srow = G >> 3, sl0 = G & 7;
      const int gsl = sl0 ^ (srow & 7);
      gload16(Ab + (size_t)srow * lda + kk + gsl * 8, &sAh[G * 8]);
    }
#pragma unroll
    for (int jj = 0; jj < 2; ++jj) {
      const int G = jj * 256 + tid;
      const int srow = G >> 3, sl0 = G & 7;
      const int gsl = sl0 ^ (srow & 7);
      gload16(Wb + (size_t)srow * ldw + kk + gsl * 8, &sBh[G * 8]);
    }
    __syncthreads();
#pragma unroll
    for (int ks = 0; ks < 2; ++ks) {
      f16x8 aH[4], bH[2];
#pragma unroll
      for (int m = 0; m < 4; ++m) {
        const int r = wr + m * 16 + lr;
        aH[m] = *(const f16x8*)&sAh[r * 64 + (((ks * 4 + sl) ^ (r & 7)) * 8)];
      }
#pragma unroll
      for (int n = 0; n < 2; ++n) {
        const int r = wc + n * 16 + lr;
        bH[n] = *(const f16x8*)&sBh[r * 64 + (((ks * 4 + sl) ^ (r & 7)) * 8)];
      }
#pragma unroll
      for (int m = 0; m < 4; ++m)
#pragma unroll
        for (int n = 0; n < 2; ++n)
          acc[m][n] = __builtin_amdgcn_mfma_f32_16x16x32_f16(aH[m], bH[n],
                                                             acc[m][n], 0, 0, 0);
    }
    __syncthreads();
  }
  const int r4 = sl * 4;
#pragma unroll
  for (int m = 0; m < 4; ++m) {
#pragma unroll
    for (int r = 0; r < 4; ++r) {
      const int mm = bm + wr + m * 16 + r4 + r;
#pragma unroll
      for (int n = 0; n < 2; ++n) {
        const int col = bn + wc + n * 16 + lr;
        float v = acc[m][n][r] + bias[col];
        if (RELU) v = fmaxf(v, 0.f);
        if (RESID) {
          const int rr = rmod ? (mm % rmod) : mm;
          v += resid[(size_t)rr * ldr + col];
        }
        if (FOUT) fout[(size_t)mm * ldc + col] = v;
        if (PACK) ph[(size_t)mm * ldp + col] = f16b(v);
      }
    }
  }
}

// =========================================================================
// Conv z-pair with center-merged weights.
// Per zp block: side taps (t = -d, +d) for z = zp*2, zp*2+1 (alpha-scaled)
// + HALF of the merged-center GEMM (K slice [zp*256, zp*256+256), weights
// W_mix[b] = sum_z alpha[b,z] * W[z,center], alpha baked in).
// P[zp] f32 partial; ln3 sums P0+P1+h+cb_mix. grid 768 = 3/CU.
// =========================================================================
__global__ __launch_bounds__(256, 3) void conv_zp_k(
    const short* __restrict__ hp, const short* __restrict__ wt8,
    const short* __restrict__ wmix, const float* __restrict__ alpha,
    const short* __restrict__ zpadS, float* __restrict__ P) {
  __shared__ alignas(16) short sAh[8192], sBh[8192];
  const int tid = threadIdx.x;
  const unsigned lin = blockIdx.x;
  const unsigned swz = (lin & 7) * 96 + (lin >> 3);
  const int zp = (int)(swz / 384);
  const unsigned rem = swz % 384;
  const int bn = (int)(rem & 3) * 128;
  const int bmt = (int)(rem >> 2);
  const int b = bmt / 6, s0 = (bmt % 6) * 128, gm0 = bmt * 128;
  const int wave = tid >> 6, lane = tid & 63;
  const int wr = (wave >> 1) * 64, wc = (wave & 1) * 64;
  const int lr = lane & 15, sl = lane >> 4;
  const short* hb = hp + (size_t)b * S * 512;
  f32x4 accF[4][4] = {};
  // ---- side taps, alpha-scaled per z ----
#pragma unroll
  for (int zi = 0; zi < 2; ++zi) {
    const int z = zp * 2 + zi;
    const int dd = 1 << z;
    f32x4 acc[4][4] = {};
    for (int kk = 0; kk < 1024; kk += 64) {
      const int tap = kk >> 9;  // 0: -d, 1: +d
      const int koff = kk & 511;
      const int off = tap ? dd : -dd;
#pragma unroll
      for (int jj = 0; jj < 4; ++jj) {
        const int G = jj * 256 + tid;
        const int srow = G >> 3, sl0 = G & 7;
        const int gsl = sl0 ^ (srow & 7);
        const int dst = G * 8;
        const int gs = s0 + srow + off;
        const bool inb = ((unsigned)gs < (unsigned)S);
        const short* aBase = hb + (size_t)gs * 512 + koff + gsl * 8;
        gload16(inb ? aBase : zpadS, &sAh[dst]);
        gload16(wt8 + ((size_t)((z * 2 + tap) * 512 + bn + srow)) * 512 +
                    koff + gsl * 8,
                &sBh[dst]);
      }
      __syncthreads();
#pragma unroll
      for (int ks = 0; ks < 2; ++ks) {
        f16x8 aH[4], bH[4];
#pragma unroll
        for (int m = 0; m < 4; ++m) {
          const int r = wr + m * 16 + lr;
          aH[m] =
              *(const f16x8*)&sAh[r * 64 + (((ks * 4 + sl) ^ (r & 7)) * 8)];
        }
#pragma unroll
        for (int n = 0; n < 4; ++n) {
          const int r = wc + n * 16 + lr;
          bH[n] =
              *(const f16x8*)&sBh[r * 64 + (((ks * 4 + sl) ^ (r & 7)) * 8)];
        }
#pragma unroll
        for (int m = 0; m < 4; ++m)
#pragma unroll
          for (int n = 0; n < 4; ++n)
            acc[m][n] = __builtin_amdgcn_mfma_f32_16x16x32_f16(
                aH[m], bH[n], acc[m][n], 0, 0, 0);
      }
      __syncthreads();
    }
    const float al = alpha[b * 4 + z];
#pragma unroll
    for (int m = 0; m < 4; ++m)
#pragma unroll
      for (int n = 0; n < 4; ++n)
#pragma unroll
        for (int r = 0; r < 4; ++r) accF[m][n][r] += al * acc[m][n][r];
  }
  // ---- merged-center K-half (alpha inside W_mix), accumulate into accF ---
  const short* Wm = wmix + (size_t)b * 512 * 512;
  for (int kc = 0; kc < 256; kc += 64) {
    const int koff = zp * 256 + kc;
#pragma unroll
    for (int jj = 0; jj < 4; ++jj) {
      const int G = jj * 256 + tid;
      const int srow = G >> 3, sl0 = G & 7;
      const int gsl = sl0 ^ (srow & 7);
      const int dst = G * 8;
      gload16(hb + (size_t)(s0 + srow) * 512 + koff + gsl * 8, &sAh[dst]);
      gload16(Wm + (size_t)(bn + srow) * 512 + koff + gsl * 8, &sBh[dst]);
    }
    __syncthreads();
#pragma unroll
    for (int ks = 0; ks < 2; ++ks) {
      f16x8 aH[4], bH[4];
#pragma unroll
      for (int m = 0; m < 4; ++m) {
        const int r = wr + m * 16 + lr;
        aH[m] = *(const f16x8*)&sAh[r * 64 + (((ks * 4 + sl) ^ (r & 7)) * 8)];
      }
#pragma unroll
      for (int n = 0; n < 4; ++n) {
        const int r = wc + n * 16 + lr;
        bH[n] = *(const f16x8*)&sBh[r * 64 + (((ks * 4 + sl) ^ (r & 7)) * 8)];
      }
#pragma unroll
      for (int m = 0; m < 4; ++m)
#pragma unroll
        for (int n = 0; n < 4; ++n)
          accF[m][n] = __builtin_amdgcn_mfma_f32_16x16x32_f16(
              aH[m], bH[n], accF[m][n], 0, 0, 0);
    }
    __syncthreads();
  }
  float* Pz = P + (size_t)zp * ((size_t)BS * D);
  const int r4 = sl * 4;
#pragma unroll
  for (int m = 0; m < 4; ++m)
#pragma unroll
    for (int r = 0; r < 4; ++r) {
      const int mm = gm0 + wr + m * 16 + r4 + r;
#pragma unroll
      for (int n = 0; n < 4; ++n)
        Pz[(size_t)mm * D + bn + wc + n * 16 + lr] = accF[m][n][r];
    }
}

// ---- fused conv-combine + LN1 -> LN2 (SSM y cancels: shift-invariance) ---
// v = P0 + P1 + h + cb_mix[b]; h2 = LN2(LN1(v)) -> f32 + hi-pack.
__global__ __launch_bounds__(256) void ln3_k(
    const float* __restrict__ P0, const float* __restrict__ P1,
    const float* __restrict__ resid, const float* __restrict__ cbmix,
    const float* __restrict__ g1, const float* __restrict__ b1,
    const float* __restrict__ g2, const float* __restrict__ b2,
    float* __restrict__ fout, short* __restrict__ pout) {
  const int row = blockIdx.x * 4 + (threadIdx.x >> 6);
  const int lane = threadIdx.x & 63;
  const int bb = row / S;
  const size_t base = (size_t)row * D;
  float v[8];
  float s = 0.f;
#pragma unroll
  for (int j = 0; j < 8; ++j) {
    const int c = lane + 64 * j;
    v[j] = P0[base + c] + P1[base + c] + resid[base + c] +
           cbmix[(size_t)bb * D + c];
    s += v[j];
  }
  s = wave_sum(s);
  const float m1 = s * (1.f / D);
  float q = 0.f;
#pragma unroll
  for (int j = 0; j < 8; ++j) { const float d = v[j] - m1; q += d * d; }
  q = wave_sum(q);
  const float r1 = rsqrtf(q * (1.f / D) + EPS);
  float y[8];
  float s2 = 0.f;
#pragma unroll
  for (int j = 0; j < 8; ++j) {
    const int c = lane + 64 * j;
    y[j] = (v[j] - m1) * r1 * g1[c] + b1[c];
    s2 += y[j];
  }
  s2 = wave_sum(s2);
  const float m2 = s2 * (1.f / D);
  float q2 = 0.f;
#pragma unroll
  for (int j = 0; j < 8; ++j) { const float d = y[j] - m2; q2 += d * d; }
  q2 = wave_sum(q2);
  const float r2 = rsqrtf(q2 * (1.f / D) + EPS);
  float* frow = fout + base;
  short* prow = pout + (size_t)row * 512;
#pragma unroll
  for (int j = 0; j < 8; ++j) {
    const int c = lane + 64 * j;
    const float o = (y[j] - m2) * r2 * g2[c] + b2[c];
    frow[c] = o;
    prow[c] = f16b(o);
  }
}

// ---- partial column sums over S ------------------------------------------
__global__ __launch_bounds__(256) void colmean_part_k(
    const float* __restrict__ x, float* __restrict__ part) {
  const int b = blockIdx.x, c = blockIdx.y;
  const int s0 = c * 96;
  for (int d = threadIdx.x; d < D; d += 256) {
    float s = 0.f;
    for (int si = 0; si < 96; ++si)
      s += x[((size_t)b * S + s0 + si) * D + d];
    part[((size_t)b * 8 + c) * D + d] = s;
  }
}

// ---- W-pack hi-only: (K,N) f32 -> (N,K) fp16 bits ------------------------
__global__ __launch_bounds__(256) void pack_wh_k(const float* __restrict__ W,
                                                 short* __restrict__ out,
                                                 int K, int N, int ln2N) {
  const int idx = blockIdx.x * 256 + threadIdx.x;
  const int n = idx & (N - 1), k = idx >> ln2N;
  if (k >= K) return;
  out[(size_t)n * K + k] = f16b(W[(size_t)k * N + n]);
}

// ---- conv side-tap pack: (4,O,I,3) taps {0,2} -> (8, O, I) fp16 ----------
__global__ __launch_bounds__(256) void pack_convw8_k(
    const float* __restrict__ cw, short* __restrict__ out) {
  const int idx = blockIdx.x * 256 + threadIdx.x;  // 8*512*512
  const int c = idx & 511, o = (idx >> 9) & 511, seg = idx >> 18;  // 0..7
  const int z = seg >> 1, t = (seg & 1) * 2;
  out[((size_t)seg * D + o) * D + c] =
      f16b(cw[(((size_t)z * D + o) * D + c) * 3 + t]);
}

// ---- W_mix[b] = sum_z alpha[b,z] * W[z,center]  (f32 mix -> fp16) --------
__global__ __launch_bounds__(256) void wmix_k(const float* __restrict__ cw,
                                              const float* __restrict__ alpha,
                                              short* __restrict__ wm) {
  __shared__ float sal[64];
  if (threadIdx.x < 64) sal[threadIdx.x] = alpha[threadIdx.x];
  __syncthreads();
  const int idx = blockIdx.x * 256 + threadIdx.x;  // 262144 (o,c)
  const int c = idx & 511, o = idx >> 9;
  float w[4];
#pragma unroll
  for (int z = 0; z < 4; ++z)
    w[z] = cw[(((size_t)z * D + o) * D + c) * 3 + 1];
#pragma unroll
  for (int b = 0; b < 16; ++b) {
    const float v = sal[b * 4 + 0] * w[0] + sal[b * 4 + 1] * w[1] +
                    sal[b * 4 + 2] * w[2] + sal[b * 4 + 3] * w[3];
    wm[((size_t)b * D + o) * D + c] = f16b(v);
  }
}

__global__ __launch_bounds__(256) void zero_k(float* __restrict__ p) {
  p[threadIdx.x] = 0.f;
  p[threadIdx.x + 256] = 0.f;
}

// ---- alpha = softmax(mean_s(h)@wmw + wmb); also cb_mix[b] = sum a_z cb_z -
__global__ __launch_bounds__(64) void alpha_k(const float* __restrict__ part,
                                              const float* __restrict__ wmw,
                                              const float* __restrict__ wmb,
                                              const float* __restrict__ cb,
                                              float* __restrict__ alpha,
                                              float* __restrict__ cbmix) {
  const int b = blockIdx.x, t = threadIdx.x;
  float p0 = 0, p1 = 0, p2 = 0, p3 = 0;
  for (int d = t; d < D; d += 64) {
    float xm = 0;
#pragma unroll
    for (int c = 0; c < 8; ++c) xm += part[((size_t)b * 8 + c) * D + d];
    xm *= (1.f / S);
    p0 += xm * wmw[d * 4 + 0];
    p1 += xm * wmw[d * 4 + 1];
    p2 += xm * wmw[d * 4 + 2];
    p3 += xm * wmw[d * 4 + 3];
  }
  p0 = wave_sum(p0); p1 = wave_sum(p1);
  p2 = wave_sum(p2); p3 = wave_sum(p3);
  const float l0 = p0 + wmb[0], l1 = p1 + wmb[1];
  const float l2 = p2 + wmb[2], l3 = p3 + wmb[3];
  const float mx = fmaxf(fmaxf(l0, l1), fmaxf(l2, l3));
  const float e0 = expf(l0 - mx), e1 = expf(l1 - mx);
  const float e2 = expf(l2 - mx), e3 = expf(l3 - mx);
  const float inv = 1.f / (e0 + e1 + e2 + e3);
  const float a0 = e0 * inv, a1 = e1 * inv, a2 = e2 * inv, a3 = e3 * inv;
  if (t == 0) {
    alpha[b * 4 + 0] = a0;
    alpha[b * 4 + 1] = a1;
    alpha[b * 4 + 2] = a2;
    alpha[b * 4 + 3] = a3;
  }
  for (int c = t; c < D; c += 64)
    cbmix[(size_t)b * D + c] =
        a0 * cb[c] + a1 * cb[D + c] + a2 * cb[2 * D + c] + a3 * cb[3 * D + c];
}

// ---- embedding gather-mean, hi-pack out ----------------------------------
__global__ __launch_bounds__(256) void embed_k(const int* __restrict__ xe,
                                               const float* __restrict__ emb,
                                               short* __restrict__ out) {
  const int r = blockIdx.x;
  int idx[8];
#pragma unroll
  for (int j = 0; j < 8; ++j) idx[j] = xe[r * 8 + j];
  short* o = out + (size_t)r * 512;
  for (int d = threadIdx.x; d < D; d += 256) {
    float s = 0.f;
#pragma unroll
    for (int j = 0; j < 8; ++j) s += emb[(size_t)idx[j] * D + d];
    o[d] = f16b(s * 0.125f);
  }
}

// ---- L2-normalize rows of (BS,64), hi-pack out ---------------------------
__global__ __launch_bounds__(256) void norml2_k(const float* __restrict__ x,
                                                short* __restrict__ out) {
  const int r = blockIdx.x * 4 + (threadIdx.x >> 6);
  const int lane = threadIdx.x & 63;
  const float v = x[(size_t)r * 64 + lane];
  const float s = wave_sum(v * v);
  const float nrm = fmaxf(sqrtf(s), 1e-12f);
  out[(size_t)r * 64 + lane] = f16b(v / nrm);
}

// ---- classifier head -----------------------------------------------------
__global__ __launch_bounds__(256) void head_k(
    const float* __restrict__ part, const float* __restrict__ pw1,
    const float* __restrict__ pb1, const float* __restrict__ pw2,
    const float* __restrict__ pb2, float* __restrict__ out) {
  __shared__ float hg[D];
  __shared__ float red[256];
  const int b = blockIdx.x, t = threadIdx.x;
  for (int d = t; d < D; d += 256) {
    float s = 0.f;
#pragma unroll
    for (int c = 0; c < 8; ++c) s += part[((size_t)b * 8 + c) * D + d];
    hg[d] = s * (1.f / S);
  }
  __syncthreads();
  float s = pb1[t];
  for (int d = 0; d < D; ++d) s = fmaf(hg[d], pw1[(size_t)d * 256 + t], s);
  s = fmaxf(s, 0.f);
  red[t] = s * pw2[t];
  __syncthreads();
  for (int o = 128; o > 0; o >>= 1) {
    if (t < o) red[t] += red[t + o];
    __syncthreads();
  }
  if (t == 0) out[b] = red[0] + pb2[0];
}

}  // namespace

extern "C" void kernel_launch(void* const* d_in, const int* in_sizes, int n_in,
                              void* d_out, int out_size, void* d_ws,
                              size_t ws_size, hipStream_t stream) {
  const float* x_cog = (const float*)d_in[0];
  const float* cw1 = (const float*)d_in[1];
  const float* cb1 = (const float*)d_in[2];
  const float* cw2 = (const float*)d_in[3];
  const float* cb2 = (const float*)d_in[4];
  const float* env_emb = (const float*)d_in[5];
  const float* ew1 = (const float*)d_in[6];
  const float* eb1 = (const float*)d_in[7];
  const float* ew2 = (const float*)d_in[8];
  const float* eb2 = (const float*)d_in[9];
  const float* fw1 = (const float*)d_in[10];
  const float* fb1 = (const float*)d_in[11];
  const float* fw2 = (const float*)d_in[12];
  const float* fb2 = (const float*)d_in[13];
  const float* pos_enc = (const float*)d_in[14];
  const float* conv_w = (const float*)d_in[15];
  const float* conv_b = (const float*)d_in[16];
  const float* wm_w = (const float*)d_in[17];
  const float* wm_b = (const float*)d_in[18];
  // d_in[19..21] = ssm_w/ssm_b/A_log: no-ops (y scalar-per-row cancels in LN2)
  const float* ffw1 = (const float*)d_in[22];
  const float* ffb1 = (const float*)d_in[23];
  const float* ffw2 = (const float*)d_in[24];
  const float* ffb2 = (const float*)d_in[25];
  const float* g1 = (const float*)d_in[26];
  const float* be1 = (const float*)d_in[27];
  const float* g2 = (const float*)d_in[28];
  const float* be2 = (const float*)d_in[29];
  const float* pw1 = (const float*)d_in[30];
  const float* pb1 = (const float*)d_in[31];
  const float* pw2 = (const float*)d_in[32];
  const float* pb2 = (const float*)d_in[33];
  const int* x_env = (const int*)d_in[34];
  float* out = (float*)d_out;

  // ---- arena (~179 MB) ----------------------------------------------------
  float* ws = (float*)d_ws;
  float* Hbuf = ws;                        // 6,291,456 f32 (running h)
  float* TBuf = Hbuf + 6291456;            // 6,291,456 f32 (h2)
  float* PARTb = TBuf + 6291456;           // 65,536
  float* ALPHAB = PARTb + 65536;           // 64
  float* ZPADF = ALPHAB + 64;              // 512 zero page
  float* CBMIX = ZPADF + 512;              // 16x512 f32
  short* R = (short*)(CBMIX + 8192);
  // frontend regions (dead during layers):
  short* CONC = R;                         // 12288x2048 hi  [0, 25165824)
  short* PK1 = R + 25165824;               // 12288x512 hi
  short* PK2 = R + 31457280;               // 12288x512 hi
  short* WPBF = R + 37748736;              // frontend W pack (<=524288)
  // layer regions (alias frontend):
  short* WCONV8 = R;                       // 8x512x512   [0, 2097152)
  short* WFFP = R + 2097152;               // 2048x512    [2097152, 3145728)
  short* WMIX = R + 3145728;               // 16x512x512  [3145728, 7340032)
  float* convP = (float*)(R + 7340032);    // 2 x 6,291,456 f32 -> 57671680
  short* APFF = R + 7340032;               // 12288x2048 hi (aliases convP)
  // persistent across frontend->layers:
  short* HPACK = R + 57671680;             // 12288x512 hi

  const dim3 blk(256);
  const dim3 gS(8, 96, 1);    // N=512, BN=64 -> 768 blocks (3/CU)
  const dim3 gF(16, 96, 1);   // N=2048, BN=128 -> 1536 blocks

  zero_k<<<1, blk, 0, stream>>>(ZPADF);

  // ---- frontend (all direct, fused epilogues, balanced grids) ------------
  norml2_k<<<BS / 4, blk, 0, stream>>>(x_cog, PK1);
  pack_wh_k<<<64 * 512 / 256, blk, 0, stream>>>(cw1, WPBF, 64, 512, 9);
  gemm_h64<true, false, false, true><<<gS, blk, 0, stream>>>(
      PK1, 64, WPBF, 64, 64, cb1, nullptr, 0, 0, nullptr, 0, PK2, 512);
  pack_wh_k<<<512 * 512 / 256, blk, 0, stream>>>(cw2, WPBF, 512, 512, 9);
  gemm_h64<false, false, false, true><<<gS, blk, 0, stream>>>(
      PK2, 512, WPBF, 512, 512, cb2, nullptr, 0, 0, nullptr, 0, CONC, 2048);
  embed_k<<<BS, blk, 0, stream>>>(x_env, env_emb, PK1);
  pack_wh_k<<<512 * 512 / 256, blk, 0, stream>>>(ew1, WPBF, 512, 512, 9);
  gemm_h64<true, false, false, true><<<gS, blk, 0, stream>>>(
      PK1, 512, WPBF, 512, 512, eb1, nullptr, 0, 0, nullptr, 0, PK2, 512);
  pack_wh_k<<<512 * 512 / 256, blk, 0, stream>>>(ew2, WPBF, 512, 512, 9);
  gemm_h64<false, false, false, true><<<gS, blk, 0, stream>>>(
      PK2, 512, WPBF, 512, 512, eb2, nullptr, 0, 0, nullptr, 0, CONC + 512,
      2048);
  pack_wh_k<<<1024 * 512 / 256, blk, 0, stream>>>(fw1, WPBF, 1024, 512, 9);
  gemm_h64<true, false, false, true><<<gS, blk, 0, stream>>>(
      CONC, 2048, WPBF, 1024, 1024, fb1, nullptr, 0, 0, nullptr, 0, PK1, 512);
  pack_wh_k<<<512 * 512 / 256, blk, 0, stream>>>(fw2, WPBF, 512, 512, 9);
  // h = (PK1@fw2 + fb2) + pos_enc -> Hbuf f32 + HPACK hi
  gemm_h64<false, true, true, true><<<gS, blk, 0, stream>>>(
      PK1, 512, WPBF, 512, 512, fb2, pos_enc, 512, S, Hbuf, 512, HPACK, 512);

  // ---- layers -------------------------------------------------------------
  for (int l = 0; l < L; ++l) {
    const float* cwl = conv_w + (size_t)l * 4 * D * D * 3;
    colmean_part_k<<<dim3(B, 8), blk, 0, stream>>>(Hbuf, PARTb);
    alpha_k<<<B, dim3(64), 0, stream>>>(PARTb, wm_w + (size_t)l * D * 4,
                                        wm_b + l * 4,
                                        conv_b + (size_t)l * 4 * D, ALPHAB,
                                        CBMIX);
    wmix_k<<<1024, blk, 0, stream>>>(cwl, ALPHAB, WMIX);
    pack_convw8_k<<<8 * 512 * 512 / 256, blk, 0, stream>>>(cwl, WCONV8);
    conv_zp_k<<<768, blk, 0, stream>>>(HPACK, WCONV8, WMIX, ALPHAB,
                                       (const short*)ZPADF, convP);
    // h2 = LN2(LN1(P0+P1+h+cb_mix)) -> TBuf f32 + hi-pack into HPACK
    ln3_k<<<BS / 4, blk, 0, stream>>>(convP, convP + 6291456, Hbuf, CBMIX,
                                      g1 + l * D, be1 + l * D, g2 + l * D,
                                      be2 + l * D, TBuf, HPACK);
    pack_wh_k<<<512 * 2048 / 256, blk, 0, stream>>>(ffw1 + (size_t)l * D * FF,
                                                    WFFP, 512, 2048, 11);
    gemm_h<true, false, false, true><<<gF, blk, 0, stream>>>(
        HPACK, 512, WFFP, 512, 512, ffb1 + (size_t)l * FF, nullptr, 0, 0,
        nullptr, 0, APFF, 2048);
    pack_wh_k<<<2048 * 512 / 256, blk, 0, stream>>>(ffw2 + (size_t)l * FF * D,
                                                    WFFP, 2048, 512, 9);
    // new h = APFF@ffw2 + ffb2 + h2 -> Hbuf f32 + next HPACK hi
    gemm_h64<false, true, true, true><<<gS, blk, 0, stream>>>(
        APFF, 2048, WFFP, 2048, 2048, ffb2 + (size_t)l * D, TBuf, 512, 0,
        Hbuf, 512, HPACK, 512);
  }

  // ---- head ---------------------------------------------------------------
  colmean_part_k<<<dim3(B, 8), blk, 0, stream>>>(Hbuf, PARTb);
  head_k<<<B, blk, 0, stream>>>(PARTb, pw1, pb1, pw2, pb2, out);
}

// Round 10
// 1211.754 us; speedup vs baseline: 3.9496x; 1.1358x over previous
//
#include <hip/hip_runtime.h>
#include <cstdint>
#include <cstddef>

namespace {

constexpr int B = 16, S = 768, BS = B * S, D = 512, FF = 2048, L = 6;
constexpr float EPS = 1e-5f;

typedef float f32x4 __attribute__((ext_vector_type(4)));
typedef _Float16 f16x8 __attribute__((ext_vector_type(8)));

__device__ __forceinline__ float wave_sum(float v) {
#pragma unroll
  for (int o = 32; o > 0; o >>= 1) v += __shfl_xor(v, o, 64);
  return v;
}

__device__ __forceinline__ short f16b(float x) {
  const _Float16 h = (_Float16)x;
  return __builtin_bit_cast(short, h);
}
__device__ __forceinline__ float h2f(short s) {
  return (float)__builtin_bit_cast(_Float16, s);
}

// ---- async global->LDS, 16B per lane ------------------------------------
__device__ __forceinline__ void gload16(const void* g, void* l) {
  __builtin_amdgcn_global_load_lds(
      (const __attribute__((address_space(1))) void*)g,
      (__attribute__((address_space(3))) void*)l, 16, 0, 0);
}

// LDS tile [rows][8 slots of 16B] (BK=64 halfs). Bank fix: global slot
// gsl = sl0 ^ (row&7); LDS stays linear (rule #21). Conflicts=0 proven.

// =========================================================================
// fp16 GEMM 128x128 (FF1, N=2048: grid 1536, balanced).
// =========================================================================
template <bool RELU, bool RESID, bool FOUT, bool PACK>
__global__ __launch_bounds__(256, 3) void gemm_h(
    const short* __restrict__ A, int lda, const short* __restrict__ Wt,
    int ldw, int Klen, const float* __restrict__ bias,
    const float* __restrict__ resid, int ldr, int rmod,
    float* __restrict__ fout, int ldc, short* __restrict__ ph, int ldp) {
  __shared__ alignas(16) short sAh[8192], sBh[8192];
  const int tid = threadIdx.x;
  const unsigned Nt = gridDim.x;
  const unsigned lin = blockIdx.y * Nt + blockIdx.x;
  const unsigned cpx = (Nt * gridDim.y) >> 3;
  const unsigned swz = (lin & 7) * cpx + (lin >> 3);
  const int bn = (int)(swz % Nt) * 128, bm = (int)(swz / Nt) * 128;
  const int wave = tid >> 6, lane = tid & 63;
  const int wr = (wave >> 1) * 64, wc = (wave & 1) * 64;
  const int lr = lane & 15, sl = lane >> 4;
  const short* Ab = A + (size_t)bm * lda;
  const short* Wb = Wt + (size_t)bn * ldw;
  f32x4 acc[4][4] = {};
  for (int kk = 0; kk < Klen; kk += 64) {
#pragma unroll
    for (int jj = 0; jj < 4; ++jj) {
      const int G = jj * 256 + tid;
      const int srow = G >> 3, sl0 = G & 7;
      const int gsl = sl0 ^ (srow & 7);
      const int dst = G * 8;
      gload16(Ab + (size_t)srow * lda + kk + gsl * 8, &sAh[dst]);
      gload16(Wb + (size_t)srow * ldw + kk + gsl * 8, &sBh[dst]);
    }
    __syncthreads();
#pragma unroll
    for (int ks = 0; ks < 2; ++ks) {
      f16x8 aH[4], bH[4];
#pragma unroll
      for (int m = 0; m < 4; ++m) {
        const int r = wr + m * 16 + lr;
        aH[m] = *(const f16x8*)&sAh[r * 64 + (((ks * 4 + sl) ^ (r & 7)) * 8)];
      }
#pragma unroll
      for (int n = 0; n < 4; ++n) {
        const int r = wc + n * 16 + lr;
        bH[n] = *(const f16x8*)&sBh[r * 64 + (((ks * 4 + sl) ^ (r & 7)) * 8)];
      }
#pragma unroll
      for (int m = 0; m < 4; ++m)
#pragma unroll
        for (int n = 0; n < 4; ++n)
          acc[m][n] = __builtin_amdgcn_mfma_f32_16x16x32_f16(aH[m], bH[n],
                                                             acc[m][n], 0, 0, 0);
    }
    __syncthreads();
  }
  const int r4 = sl * 4;
#pragma unroll
  for (int m = 0; m < 4; ++m) {
#pragma unroll
    for (int r = 0; r < 4; ++r) {
      const int mm = bm + wr + m * 16 + r4 + r;
#pragma unroll
      for (int n = 0; n < 4; ++n) {
        const int col = bn + wc + n * 16 + lr;
        float v = acc[m][n][r] + bias[col];
        if (RELU) v = fmaxf(v, 0.f);
        if (RESID) {
          const int rr = rmod ? (mm % rmod) : mm;
          v += resid[(size_t)rr * ldr + col];
        }
        if (FOUT) fout[(size_t)mm * ldc + col] = v;
        if (PACK) ph[(size_t)mm * ldp + col] = f16b(v);
      }
    }
  }
}

// =========================================================================
// fp16 GEMM 128x64 (all N=512 GEMMs: grid 768 = 3/CU balanced).
// CSUM: emit deterministic per-block column partials part[bmt*512 + col]
// (sum of v over the block's 128 rows) — replaces colmean_part_k.
// =========================================================================
template <bool RELU, bool RESID, bool FOUT, bool PACK, bool CSUM>
__global__ __launch_bounds__(256, 3) void gemm_h64(
    const short* __restrict__ A, int lda, const short* __restrict__ Wt,
    int ldw, int Klen, const float* __restrict__ bias,
    const float* __restrict__ resid, int ldr, int rmod,
    float* __restrict__ fout, int ldc, short* __restrict__ ph, int ldp,
    float* __restrict__ part) {
  __shared__ alignas(16) short sAh[8192], sBh[4096];
  __shared__ float csLds[2][64];
  const int tid = threadIdx.x;
  const unsigned Nt = gridDim.x;  // 8
  const unsigned lin = blockIdx.y * Nt + blockIdx.x;
  const unsigned cpx = (Nt * gridDim.y) >> 3;
  const unsigned swz = (lin & 7) * cpx + (lin >> 3);
  const int bn = (int)(swz % Nt) * 64, bmt = (int)(swz / Nt);
  const int bm = bmt * 128;
  const int wave = tid >> 6, lane = tid & 63;
  const int wr = (wave >> 1) * 64, wc = (wave & 1) * 32;
  const int lr = lane & 15, sl = lane >> 4;
  const short* Ab = A + (size_t)bm * lda;
  const short* Wb = Wt + (size_t)bn * ldw;
  f32x4 acc[4][2] = {};
  for (int kk = 0; kk < Klen; kk += 64) {
#pragma unroll
    for (int jj = 0; jj < 4; ++jj) {
      const int G = jj * 256 + tid;
      const int srow = G >> 3, sl0 = G & 7;
      const int gsl = sl0 ^ (srow & 7);
      gload16(Ab + (size_t)srow * lda + kk + gsl * 8, &sAh[G * 8]);
    }
#pragma unroll
    for (int jj = 0; jj < 2; ++jj) {
      const int G = jj * 256 + tid;
      const int srow = G >> 3, sl0 = G & 7;
      const int gsl = sl0 ^ (srow & 7);
      gload16(Wb + (size_t)srow * ldw + kk + gsl * 8, &sBh[G * 8]);
    }
    __syncthreads();
#pragma unroll
    for (int ks = 0; ks < 2; ++ks) {
      f16x8 aH[4], bH[2];
#pragma unroll
      for (int m = 0; m < 4; ++m) {
        const int r = wr + m * 16 + lr;
        aH[m] = *(const f16x8*)&sAh[r * 64 + (((ks * 4 + sl) ^ (r & 7)) * 8)];
      }
#pragma unroll
      for (int n = 0; n < 2; ++n) {
        const int r = wc + n * 16 + lr;
        bH[n] = *(const f16x8*)&sBh[r * 64 + (((ks * 4 + sl) ^ (r & 7)) * 8)];
      }
#pragma unroll
      for (int m = 0; m < 4; ++m)
#pragma unroll
        for (int n = 0; n < 2; ++n)
          acc[m][n] = __builtin_amdgcn_mfma_f32_16x16x32_f16(aH[m], bH[n],
                                                             acc[m][n], 0, 0, 0);
    }
    __syncthreads();
  }
  const int r4 = sl * 4;
  float cs[2] = {0.f, 0.f};
#pragma unroll
  for (int m = 0; m < 4; ++m) {
#pragma unroll
    for (int r = 0; r < 4; ++r) {
      const int mm = bm + wr + m * 16 + r4 + r;
#pragma unroll
      for (int n = 0; n < 2; ++n) {
        const int col = bn + wc + n * 16 + lr;
        float v = acc[m][n][r] + bias[col];
        if (RELU) v = fmaxf(v, 0.f);
        if (RESID) {
          const int rr = rmod ? (mm % rmod) : mm;
          v += resid[(size_t)rr * ldr + col];
        }
        if (FOUT) fout[(size_t)mm * ldc + col] = v;
        if (PACK) ph[(size_t)mm * ldp + col] = f16b(v);
        if (CSUM) cs[n] += v;
      }
    }
  }
  if constexpr (CSUM) {
#pragma unroll
    for (int n = 0; n < 2; ++n) {
      cs[n] += __shfl_xor(cs[n], 16, 64);
      cs[n] += __shfl_xor(cs[n], 32, 64);
    }
    if (sl == 0) {
      csLds[wave >> 1][wc + lr] = cs[0];
      csLds[wave >> 1][wc + 16 + lr] = cs[1];
    }
    __syncthreads();
    if (tid < 64)
      part[(size_t)bmt * 512 + bn + tid] = csLds[0][tid] + csLds[1][tid];
  }
}

// =========================================================================
// Conv z-pair with center-merged weights; f16 partial output.
// Side taps (t=-d,+d) per z (alpha-scaled) + half the merged-center GEMM.
// grid 768 = 3/CU. P[zp]: f16 partial (BSxD each).
// =========================================================================
__global__ __launch_bounds__(256, 3) void conv_zp_k(
    const short* __restrict__ hp, const short* __restrict__ wt8,
    const short* __restrict__ wmix, const float* __restrict__ alpha,
    const short* __restrict__ zpadS, short* __restrict__ P) {
  __shared__ alignas(16) short sAh[8192], sBh[8192];
  const int tid = threadIdx.x;
  const unsigned lin = blockIdx.x;
  const unsigned swz = (lin & 7) * 96 + (lin >> 3);
  const int zp = (int)(swz / 384);
  const unsigned rem = swz % 384;
  const int bn = (int)(rem & 3) * 128;
  const int bmt = (int)(rem >> 2);
  const int b = bmt / 6, s0 = (bmt % 6) * 128, gm0 = bmt * 128;
  const int wave = tid >> 6, lane = tid & 63;
  const int wr = (wave >> 1) * 64, wc = (wave & 1) * 64;
  const int lr = lane & 15, sl = lane >> 4;
  const short* hb = hp + (size_t)b * S * 512;
  f32x4 accF[4][4] = {};
#pragma unroll
  for (int zi = 0; zi < 2; ++zi) {
    const int z = zp * 2 + zi;
    const int dd = 1 << z;
    f32x4 acc[4][4] = {};
    for (int kk = 0; kk < 1024; kk += 64) {
      const int tap = kk >> 9;  // 0: -d, 1: +d
      const int koff = kk & 511;
      const int off = tap ? dd : -dd;
#pragma unroll
      for (int jj = 0; jj < 4; ++jj) {
        const int G = jj * 256 + tid;
        const int srow = G >> 3, sl0 = G & 7;
        const int gsl = sl0 ^ (srow & 7);
        const int dst = G * 8;
        const int gs = s0 + srow + off;
        const bool inb = ((unsigned)gs < (unsigned)S);
        const short* aBase = hb + (size_t)gs * 512 + koff + gsl * 8;
        gload16(inb ? aBase : zpadS, &sAh[dst]);
        gload16(wt8 + ((size_t)((z * 2 + tap) * 512 + bn + srow)) * 512 +
                    koff + gsl * 8,
                &sBh[dst]);
      }
      __syncthreads();
#pragma unroll
      for (int ks = 0; ks < 2; ++ks) {
        f16x8 aH[4], bH[4];
#pragma unroll
        for (int m = 0; m < 4; ++m) {
          const int r = wr + m * 16 + lr;
          aH[m] =
              *(const f16x8*)&sAh[r * 64 + (((ks * 4 + sl) ^ (r & 7)) * 8)];
        }
#pragma unroll
        for (int n = 0; n < 4; ++n) {
          const int r = wc + n * 16 + lr;
          bH[n] =
              *(const f16x8*)&sBh[r * 64 + (((ks * 4 + sl) ^ (r & 7)) * 8)];
        }
#pragma unroll
        for (int m = 0; m < 4; ++m)
#pragma unroll
          for (int n = 0; n < 4; ++n)
            acc[m][n] = __builtin_amdgcn_mfma_f32_16x16x32_f16(
                aH[m], bH[n], acc[m][n], 0, 0, 0);
      }
      __syncthreads();
    }
    const float al = alpha[b * 4 + z];
#pragma unroll
    for (int m = 0; m < 4; ++m)
#pragma unroll
      for (int n = 0; n < 4; ++n)
#pragma unroll
        for (int r = 0; r < 4; ++r) accF[m][n][r] += al * acc[m][n][r];
  }
  // merged-center K-half (alpha baked into W_mix)
  const short* Wm = wmix + (size_t)b * 512 * 512;
  for (int kc = 0; kc < 256; kc += 64) {
    const int koff = zp * 256 + kc;
#pragma unroll
    for (int jj = 0; jj < 4; ++jj) {
      const int G = jj * 256 + tid;
      const int srow = G >> 3, sl0 = G & 7;
      const int gsl = sl0 ^ (srow & 7);
      const int dst = G * 8;
      gload16(hb + (size_t)(s0 + srow) * 512 + koff + gsl * 8, &sAh[dst]);
      gload16(Wm + (size_t)(bn + srow) * 512 + koff + gsl * 8, &sBh[dst]);
    }
    __syncthreads();
#pragma unroll
    for (int ks = 0; ks < 2; ++ks) {
      f16x8 aH[4], bH[4];
#pragma unroll
      for (int m = 0; m < 4; ++m) {
        const int r = wr + m * 16 + lr;
        aH[m] = *(const f16x8*)&sAh[r * 64 + (((ks * 4 + sl) ^ (r & 7)) * 8)];
      }
#pragma unroll
      for (int n = 0; n < 4; ++n) {
        const int r = wc + n * 16 + lr;
        bH[n] = *(const f16x8*)&sBh[r * 64 + (((ks * 4 + sl) ^ (r & 7)) * 8)];
      }
#pragma unroll
      for (int m = 0; m < 4; ++m)
#pragma unroll
        for (int n = 0; n < 4; ++n)
          accF[m][n] = __builtin_amdgcn_mfma_f32_16x16x32_f16(
              aH[m], bH[n], accF[m][n], 0, 0, 0);
    }
    __syncthreads();
  }
  short* Pz = P + (size_t)zp * ((size_t)BS * D);
  const int r4 = sl * 4;
#pragma unroll
  for (int m = 0; m < 4; ++m)
#pragma unroll
    for (int r = 0; r < 4; ++r) {
      const int mm = gm0 + wr + m * 16 + r4 + r;
#pragma unroll
      for (int n = 0; n < 4; ++n)
        Pz[(size_t)mm * D + bn + wc + n * 16 + lr] = f16b(accF[m][n][r]);
    }
}

// ---- fused conv-combine + LN1 -> LN2 (SSM y cancels: shift-invariance) ---
// v = h2f(P0)+h2f(P1)+h+cb_mix[b]; h2 = LN2(LN1(v)) -> f32 + hi-pack.
__global__ __launch_bounds__(256) void ln3_k(
    const short* __restrict__ P0, const short* __restrict__ P1,
    const float* __restrict__ resid, const float* __restrict__ cbmix,
    const float* __restrict__ g1, const float* __restrict__ b1,
    const float* __restrict__ g2, const float* __restrict__ b2,
    float* __restrict__ fout, short* __restrict__ pout) {
  const int row = blockIdx.x * 4 + (threadIdx.x >> 6);
  const int lane = threadIdx.x & 63;
  const int bb = row / S;
  const size_t base = (size_t)row * D;
  float v[8];
  float s = 0.f;
#pragma unroll
  for (int j = 0; j < 8; ++j) {
    const int c = lane + 64 * j;
    v[j] = h2f(P0[base + c]) + h2f(P1[base + c]) + resid[base + c] +
           cbmix[(size_t)bb * D + c];
    s += v[j];
  }
  s = wave_sum(s);
  const float m1 = s * (1.f / D);
  float q = 0.f;
#pragma unroll
  for (int j = 0; j < 8; ++j) { const float d = v[j] - m1; q += d * d; }
  q = wave_sum(q);
  const float r1 = rsqrtf(q * (1.f / D) + EPS);
  float y[8];
  float s2 = 0.f;
#pragma unroll
  for (int j = 0; j < 8; ++j) {
    const int c = lane + 64 * j;
    y[j] = (v[j] - m1) * r1 * g1[c] + b1[c];
    s2 += y[j];
  }
  s2 = wave_sum(s2);
  const float m2 = s2 * (1.f / D);
  float q2 = 0.f;
#pragma unroll
  for (int j = 0; j < 8; ++j) { const float d = y[j] - m2; q2 += d * d; }
  q2 = wave_sum(q2);
  const float r2 = rsqrtf(q2 * (1.f / D) + EPS);
  float* frow = fout + base;
  short* prow = pout + (size_t)row * 512;
#pragma unroll
  for (int j = 0; j < 8; ++j) {
    const int c = lane + 64 * j;
    const float o = (y[j] - m2) * r2 * g2[c] + b2[c];
    frow[c] = o;
    prow[c] = f16b(o);
  }
}

// ---- W transpose-pack via LDS: (K,N) f32 -> (N,K) fp16, both coalesced ---
__global__ __launch_bounds__(256) void pack_wt_k(const float* __restrict__ W,
                                                 short* __restrict__ out,
                                                 int K, int N) {
  __shared__ short t[64][68];
  const int n0 = blockIdx.x * 64, k0 = blockIdx.y * 64;
  const int ln = threadIdx.x & 63, w4 = threadIdx.x >> 6;
#pragma unroll
  for (int it = 0; it < 16; ++it) {
    const int kr = it * 4 + w4;
    t[kr][ln] = f16b(W[(size_t)(k0 + kr) * N + n0 + ln]);
  }
  __syncthreads();
#pragma unroll
  for (int it = 0; it < 16; ++it) {
    const int nr = it * 4 + w4;
    out[(size_t)(n0 + nr) * K + k0 + ln] = t[ln][nr];
  }
}

// ---- merged conv-weight prep: side-tap pack (8192 blocks) + W_mix (1024) -
__global__ __launch_bounds__(256) void convprep_k(
    const float* __restrict__ cw, const float* __restrict__ alpha,
    short* __restrict__ out8, short* __restrict__ wm) {
  const int bid = blockIdx.x;
  if (bid < 8192) {
    const int idx = bid * 256 + threadIdx.x;  // 8*512*512
    const int c = idx & 511, o = (idx >> 9) & 511, seg = idx >> 18;  // 0..7
    const int z = seg >> 1, t = (seg & 1) * 2;
    out8[((size_t)seg * D + o) * D + c] =
        f16b(cw[(((size_t)z * D + o) * D + c) * 3 + t]);
  } else {
    __shared__ float sal[64];
    if (threadIdx.x < 64) sal[threadIdx.x] = alpha[threadIdx.x];
    __syncthreads();
    const int idx = (bid - 8192) * 256 + threadIdx.x;  // 262144 (o,c)
    const int c = idx & 511, o = idx >> 9;
    float w[4];
#pragma unroll
    for (int z = 0; z < 4; ++z)
      w[z] = cw[(((size_t)z * D + o) * D + c) * 3 + 1];
#pragma unroll
    for (int b = 0; b < 16; ++b) {
      const float v = sal[b * 4 + 0] * w[0] + sal[b * 4 + 1] * w[1] +
                      sal[b * 4 + 2] * w[2] + sal[b * 4 + 3] * w[3];
      wm[((size_t)b * D + o) * D + c] = f16b(v);
    }
  }
}

__global__ __launch_bounds__(256) void zero_k(float* __restrict__ p) {
  p[threadIdx.x] = 0.f;
  p[threadIdx.x + 256] = 0.f;
}

// ---- alpha from GEMM-emitted column partials (6 chunks of 128 rows/batch);
//      also cb_mix[b] = sum_z alpha_z * cb_z --------------------------------
__global__ __launch_bounds__(64) void alpha_k(const float* __restrict__ part,
                                              const float* __restrict__ wmw,
                                              const float* __restrict__ wmb,
                                              const float* __restrict__ cb,
                                              float* __restrict__ alpha,
                                              float* __restrict__ cbmix) {
  const int b = blockIdx.x, t = threadIdx.x;
  float p0 = 0, p1 = 0, p2 = 0, p3 = 0;
  for (int d = t; d < D; d += 64) {
    float xm = 0;
#pragma unroll
    for (int c = 0; c < 6; ++c) xm += part[((size_t)(b * 6 + c)) * D + d];
    xm *= (1.f / S);
    p0 += xm * wmw[d * 4 + 0];
    p1 += xm * wmw[d * 4 + 1];
    p2 += xm * wmw[d * 4 + 2];
    p3 += xm * wmw[d * 4 + 3];
  }
  p0 = wave_sum(p0); p1 = wave_sum(p1);
  p2 = wave_sum(p2); p3 = wave_sum(p3);
  const float l0 = p0 + wmb[0], l1 = p1 + wmb[1];
  const float l2 = p2 + wmb[2], l3 = p3 + wmb[3];
  const float mx = fmaxf(fmaxf(l0, l1), fmaxf(l2, l3));
  const float e0 = expf(l0 - mx), e1 = expf(l1 - mx);
  const float e2 = expf(l2 - mx), e3 = expf(l3 - mx);
  const float inv = 1.f / (e0 + e1 + e2 + e3);
  const float a0 = e0 * inv, a1 = e1 * inv, a2 = e2 * inv, a3 = e3 * inv;
  if (t == 0) {
    alpha[b * 4 + 0] = a0;
    alpha[b * 4 + 1] = a1;
    alpha[b * 4 + 2] = a2;
    alpha[b * 4 + 3] = a3;
  }
  for (int c = t; c < D; c += 64)
    cbmix[(size_t)b * D + c] =
        a0 * cb[c] + a1 * cb[D + c] + a2 * cb[2 * D + c] + a3 * cb[3 * D + c];
}

// ---- embedding gather-mean, hi-pack out ----------------------------------
__global__ __launch_bounds__(256) void embed_k(const int* __restrict__ xe,
                                               const float* __restrict__ emb,
                                               short* __restrict__ out) {
  const int r = blockIdx.x;
  int idx[8];
#pragma unroll
  for (int j = 0; j < 8; ++j) idx[j] = xe[r * 8 + j];
  short* o = out + (size_t)r * 512;
  for (int d = threadIdx.x; d < D; d += 256) {
    float s = 0.f;
#pragma unroll
    for (int j = 0; j < 8; ++j) s += emb[(size_t)idx[j] * D + d];
    o[d] = f16b(s * 0.125f);
  }
}

// ---- L2-normalize rows of (BS,64), hi-pack out ---------------------------
__global__ __launch_bounds__(256) void norml2_k(const float* __restrict__ x,
                                                short* __restrict__ out) {
  const int r = blockIdx.x * 4 + (threadIdx.x >> 6);
  const int lane = threadIdx.x & 63;
  const float v = x[(size_t)r * 64 + lane];
  const float s = wave_sum(v * v);
  const float nrm = fmaxf(sqrtf(s), 1e-12f);
  out[(size_t)r * 64 + lane] = f16b(v / nrm);
}

// ---- classifier head (reads GEMM column partials) ------------------------
__global__ __launch_bounds__(256) void head_k(
    const float* __restrict__ part, const float* __restrict__ pw1,
    const float* __restrict__ pb1, const float* __restrict__ pw2,
    const float* __restrict__ pb2, float* __restrict__ out) {
  __shared__ float hg[D];
  __shared__ float red[256];
  const int b = blockIdx.x, t = threadIdx.x;
  for (int d = t; d < D; d += 256) {
    float s = 0.f;
#pragma unroll
    for (int c = 0; c < 6; ++c) s += part[((size_t)(b * 6 + c)) * D + d];
    hg[d] = s * (1.f / S);
  }
  __syncthreads();
  float s = pb1[t];
  for (int d = 0; d < D; ++d) s = fmaf(hg[d], pw1[(size_t)d * 256 + t], s);
  s = fmaxf(s, 0.f);
  red[t] = s * pw2[t];
  __syncthreads();
  for (int o = 128; o > 0; o >>= 1) {
    if (t < o) red[t] += red[t + o];
    __syncthreads();
  }
  if (t == 0) out[b] = red[0] + pb2[0];
}

}  // namespace

extern "C" void kernel_launch(void* const* d_in, const int* in_sizes, int n_in,
                              void* d_out, int out_size, void* d_ws,
                              size_t ws_size, hipStream_t stream) {
  const float* x_cog = (const float*)d_in[0];
  const float* cw1 = (const float*)d_in[1];
  const float* cb1 = (const float*)d_in[2];
  const float* cw2 = (const float*)d_in[3];
  const float* cb2 = (const float*)d_in[4];
  const float* env_emb = (const float*)d_in[5];
  const float* ew1 = (const float*)d_in[6];
  const float* eb1 = (const float*)d_in[7];
  const float* ew2 = (const float*)d_in[8];
  const float* eb2 = (const float*)d_in[9];
  const float* fw1 = (const float*)d_in[10];
  const float* fb1 = (const float*)d_in[11];
  const float* fw2 = (const float*)d_in[12];
  const float* fb2 = (const float*)d_in[13];
  const float* pos_enc = (const float*)d_in[14];
  const float* conv_w = (const float*)d_in[15];
  const float* conv_b = (const float*)d_in[16];
  const float* wm_w = (const float*)d_in[17];
  const float* wm_b = (const float*)d_in[18];
  // d_in[19..21] = ssm_w/ssm_b/A_log: no-ops (y scalar-per-row cancels in LN2)
  const float* ffw1 = (const float*)d_in[22];
  const float* ffb1 = (const float*)d_in[23];
  const float* ffw2 = (const float*)d_in[24];
  const float* ffb2 = (const float*)d_in[25];
  const float* g1 = (const float*)d_in[26];
  const float* be1 = (const float*)d_in[27];
  const float* g2 = (const float*)d_in[28];
  const float* be2 = (const float*)d_in[29];
  const float* pw1 = (const float*)d_in[30];
  const float* pb1 = (const float*)d_in[31];
  const float* pw2 = (const float*)d_in[32];
  const float* pb2 = (const float*)d_in[33];
  const int* x_env = (const int*)d_in[34];
  float* out = (float*)d_out;

  // ---- arena (~128 MB) ----------------------------------------------------
  float* ws = (float*)d_ws;
  float* Hbuf = ws;                        // 6,291,456 f32 (running h)
  float* TBuf = Hbuf + 6291456;            // 6,291,456 f32 (h2)
  float* PART2 = TBuf + 6291456;           // 96x512 f32 (col partials)
  float* ALPHAB = PART2 + 65536;           // 64
  float* ZPADF = ALPHAB + 64;              // 512 zero page
  float* CBMIX = ZPADF + 512;              // 16x512 f32
  short* R = (short*)(CBMIX + 8192);
  // layer regions:
  short* WCONV8 = R;                       // 8x512x512   [0, 2097152)
  short* WFFP = R + 2097152;               // 2048x512    [2097152, 3145728)
  short* WMIX = R + 3145728;               // 16x512x512  [3145728, 7340032)
  short* convPh = R + 7340032;             // 2 x 12288x512 f16 (conv partials)
  short* APFF = R + 7340032;               // 12288x2048 hi (aliases convPh)
  short* HPACK = R + 32505856;             // 12288x512 hi (persistent)
  // frontend regions (alias layer regions; dead once layers start):
  short* CONC = R;                         // 12288x2048 hi  [0, 25165824)
  short* PK1 = R + 25165824;               // 12288x512 hi
  short* PK2 = R + 25165824 + 6291456;     // 12288x512 hi (ends 37748736 < HPACK? no:
  // PK2 [31457280, 37748736) overlaps HPACK [32505856,...) — PK2 is dead
  // before HPACK is written (frontend-final GEMM). Liveness-checked.
  short* WPBF = WFFP;                      // frontend W pack (<=1024x512)

  const dim3 blk(256);
  const dim3 gS(8, 96, 1);    // N=512, BN=64 -> 768 blocks (3/CU)
  const dim3 gF(16, 96, 1);   // N=2048, BN=128 -> 1536 blocks

  zero_k<<<1, blk, 0, stream>>>(ZPADF);

  // ---- frontend -----------------------------------------------------------
  norml2_k<<<BS / 4, blk, 0, stream>>>(x_cog, PK1);
  pack_wt_k<<<dim3(8, 1), blk, 0, stream>>>(cw1, WPBF, 64, 512);
  gemm_h64<true, false, false, true, false><<<gS, blk, 0, stream>>>(
      PK1, 64, WPBF, 64, 64, cb1, nullptr, 0, 0, nullptr, 0, PK2, 512,
      nullptr);
  pack_wt_k<<<dim3(8, 8), blk, 0, stream>>>(cw2, WPBF, 512, 512);
  gemm_h64<false, false, false, true, false><<<gS, blk, 0, stream>>>(
      PK2, 512, WPBF, 512, 512, cb2, nullptr, 0, 0, nullptr, 0, CONC, 2048,
      nullptr);
  embed_k<<<BS, blk, 0, stream>>>(x_env, env_emb, PK1);
  pack_wt_k<<<dim3(8, 8), blk, 0, stream>>>(ew1, WPBF, 512, 512);
  gemm_h64<true, false, false, true, false><<<gS, blk, 0, stream>>>(
      PK1, 512, WPBF, 512, 512, eb1, nullptr, 0, 0, nullptr, 0, PK2, 512,
      nullptr);
  pack_wt_k<<<dim3(8, 8), blk, 0, stream>>>(ew2, WPBF, 512, 512);
  gemm_h64<false, false, false, true, false><<<gS, blk, 0, stream>>>(
      PK2, 512, WPBF, 512, 512, eb2, nullptr, 0, 0, nullptr, 0, CONC + 512,
      2048, nullptr);
  pack_wt_k<<<dim3(8, 16), blk, 0, stream>>>(fw1, WPBF, 1024, 512);
  gemm_h64<true, false, false, true, false><<<gS, blk, 0, stream>>>(
      CONC, 2048, WPBF, 1024, 1024, fb1, nullptr, 0, 0, nullptr, 0, PK1, 512,
      nullptr);
  pack_wt_k<<<dim3(8, 8), blk, 0, stream>>>(fw2, WPBF, 512, 512);
  // h = (PK1@fw2 + fb2) + pos_enc -> Hbuf f32 + HPACK hi + PART2 colsums
  gemm_h64<false, true, true, true, true><<<gS, blk, 0, stream>>>(
      PK1, 512, WPBF, 512, 512, fb2, pos_enc, 512, S, Hbuf, 512, HPACK, 512,
      PART2);

  // ---- layers -------------------------------------------------------------
  for (int l = 0; l < L; ++l) {
    const float* cwl = conv_w + (size_t)l * 4 * D * D * 3;
    alpha_k<<<B, dim3(64), 0, stream>>>(PART2, wm_w + (size_t)l * D * 4,
                                        wm_b + l * 4,
                                        conv_b + (size_t)l * 4 * D, ALPHAB,
                                        CBMIX);
    convprep_k<<<9216, blk, 0, stream>>>(cwl, ALPHAB, WCONV8, WMIX);
    conv_zp_k<<<768, blk, 0, stream>>>(HPACK, WCONV8, WMIX, ALPHAB,
                                       (const short*)ZPADF, convPh);
    // h2 = LN2(LN1(P0+P1+h+cb_mix)) -> TBuf f32 + hi-pack into HPACK
    ln3_k<<<BS / 4, blk, 0, stream>>>(convPh, convPh + (size_t)BS * D, Hbuf,
                                      CBMIX, g1 + l * D, be1 + l * D,
                                      g2 + l * D, be2 + l * D, TBuf, HPACK);
    pack_wt_k<<<dim3(32, 8), blk, 0, stream>>>(ffw1 + (size_t)l * D * FF,
                                               WFFP, 512, 2048);
    gemm_h<true, false, false, true><<<gF, blk, 0, stream>>>(
        HPACK, 512, WFFP, 512, 512, ffb1 + (size_t)l * FF, nullptr, 0, 0,
        nullptr, 0, APFF, 2048);
    pack_wt_k<<<dim3(8, 32), blk, 0, stream>>>(ffw2 + (size_t)l * FF * D,
                                               WFFP, 2048, 512);
    // new h = APFF@ffw2 + ffb2 + h2 -> Hbuf f32 + HPACK hi + PART2 colsums
    gemm_h64<false, true, true, true, true><<<gS, blk, 0, stream>>>(
        APFF, 2048, WFFP, 2048, 2048, ffb2 + (size_t)l * D, TBuf, 512, 0,
        Hbuf, 512, HPACK, 512, PART2);
  }

  // ---- head ---------------------------------------------------------------
  head_k<<<B, blk, 0, stream>>>(PART2, pw1, pb1, pw2, pb2, out);
}

// Round 11
// 1128.848 us; speedup vs baseline: 4.2397x; 1.0734x over previous
//
#include <hip/hip_runtime.h>
#include <cstdint>
#include <cstddef>

namespace {

constexpr int B = 16, S = 768, BS = B * S, D = 512, FF = 2048, L = 6;
constexpr float EPS = 1e-5f;

typedef float f32x4 __attribute__((ext_vector_type(4)));
typedef _Float16 f16x8 __attribute__((ext_vector_type(8)));

__device__ __forceinline__ float wave_sum(float v) {
#pragma unroll
  for (int o = 32; o > 0; o >>= 1) v += __shfl_xor(v, o, 64);
  return v;
}

__device__ __forceinline__ short f16b(float x) {
  const _Float16 h = (_Float16)x;
  return __builtin_bit_cast(short, h);
}
__device__ __forceinline__ float h2f(short s) {
  return (float)__builtin_bit_cast(_Float16, s);
}

// ---- async global->LDS, 16B per lane ------------------------------------
__device__ __forceinline__ void gload16(const void* g, void* l) {
  __builtin_amdgcn_global_load_lds(
      (const __attribute__((address_space(1))) void*)g,
      (__attribute__((address_space(3))) void*)l, 16, 0, 0);
}

// LDS tile [rows][8 slots of 16B] (BK=64 halfs). Bank fix: global slot
// gsl = sl0 ^ (row&7); LDS stays linear (rule #21). Conflicts=0 proven.

// =========================================================================
// fp16 GEMM 128x128 (FF1, N=2048: grid 1536, balanced).
// =========================================================================
template <bool RELU, bool PACK>
__global__ __launch_bounds__(256, 3) void gemm_h(
    const short* __restrict__ A, int lda, const short* __restrict__ Wt,
    int ldw, int Klen, const float* __restrict__ bias,
    short* __restrict__ ph, int ldp) {
  __shared__ alignas(16) short sAh[8192], sBh[8192];
  const int tid = threadIdx.x;
  const unsigned Nt = gridDim.x;
  const unsigned lin = blockIdx.y * Nt + blockIdx.x;
  const unsigned cpx = (Nt * gridDim.y) >> 3;
  const unsigned swz = (lin & 7) * cpx + (lin >> 3);
  const int bn = (int)(swz % Nt) * 128, bm = (int)(swz / Nt) * 128;
  const int wave = tid >> 6, lane = tid & 63;
  const int wr = (wave >> 1) * 64, wc = (wave & 1) * 64;
  const int lr = lane & 15, sl = lane >> 4;
  const short* Ab = A + (size_t)bm * lda;
  const short* Wb = Wt + (size_t)bn * ldw;
  f32x4 acc[4][4] = {};
  for (int kk = 0; kk < Klen; kk += 64) {
#pragma unroll
    for (int jj = 0; jj < 4; ++jj) {
      const int G = jj * 256 + tid;
      const int srow = G >> 3, sl0 = G & 7;
      const int gsl = sl0 ^ (srow & 7);
      const int dst = G * 8;
      gload16(Ab + (size_t)srow * lda + kk + gsl * 8, &sAh[dst]);
      gload16(Wb + (size_t)srow * ldw + kk + gsl * 8, &sBh[dst]);
    }
    __syncthreads();
#pragma unroll
    for (int ks = 0; ks < 2; ++ks) {
      f16x8 aH[4], bH[4];
#pragma unroll
      for (int m = 0; m < 4; ++m) {
        const int r = wr + m * 16 + lr;
        aH[m] = *(const f16x8*)&sAh[r * 64 + (((ks * 4 + sl) ^ (r & 7)) * 8)];
      }
#pragma unroll
      for (int n = 0; n < 4; ++n) {
        const int r = wc + n * 16 + lr;
        bH[n] = *(const f16x8*)&sBh[r * 64 + (((ks * 4 + sl) ^ (r & 7)) * 8)];
      }
#pragma unroll
      for (int m = 0; m < 4; ++m)
#pragma unroll
        for (int n = 0; n < 4; ++n)
          acc[m][n] = __builtin_amdgcn_mfma_f32_16x16x32_f16(aH[m], bH[n],
                                                             acc[m][n], 0, 0, 0);
    }
    __syncthreads();
  }
  const int r4 = sl * 4;
#pragma unroll
  for (int m = 0; m < 4; ++m) {
#pragma unroll
    for (int r = 0; r < 4; ++r) {
      const int mm = bm + wr + m * 16 + r4 + r;
#pragma unroll
      for (int n = 0; n < 4; ++n) {
        const int col = bn + wc + n * 16 + lr;
        float v = acc[m][n][r] + bias[col];
        if (RELU) v = fmaxf(v, 0.f);
        if (PACK) ph[(size_t)mm * ldp + col] = f16b(v);
      }
    }
  }
}

// =========================================================================
// fp16 GEMM 128x64 (all N=512 GEMMs: grid 768 = 3/CU balanced).
// RESM: 0 none, 1 f32 resid (rmod), 2 f16 resid.
// CSUM: deterministic per-block column partials part[bmt*512+col].
// =========================================================================
template <bool RELU, int RESM, bool PACK, bool CSUM>
__global__ __launch_bounds__(256, 3) void gemm_h64(
    const short* __restrict__ A, int lda, const short* __restrict__ Wt,
    int ldw, int Klen, const float* __restrict__ bias,
    const float* __restrict__ resid, const short* __restrict__ residS,
    int ldr, int rmod, short* __restrict__ ph, int ldp,
    float* __restrict__ part) {
  __shared__ alignas(16) short sAh[8192], sBh[4096];
  __shared__ float csLds[2][64];
  const int tid = threadIdx.x;
  const unsigned Nt = gridDim.x;  // 8
  const unsigned lin = blockIdx.y * Nt + blockIdx.x;
  const unsigned cpx = (Nt * gridDim.y) >> 3;
  const unsigned swz = (lin & 7) * cpx + (lin >> 3);
  const int bn = (int)(swz % Nt) * 64, bmt = (int)(swz / Nt);
  const int bm = bmt * 128;
  const int wave = tid >> 6, lane = tid & 63;
  const int wr = (wave >> 1) * 64, wc = (wave & 1) * 32;
  const int lr = lane & 15, sl = lane >> 4;
  const short* Ab = A + (size_t)bm * lda;
  const short* Wb = Wt + (size_t)bn * ldw;
  f32x4 acc[4][2] = {};
  for (int kk = 0; kk < Klen; kk += 64) {
#pragma unroll
    for (int jj = 0; jj < 4; ++jj) {
      const int G = jj * 256 + tid;
      const int srow = G >> 3, sl0 = G & 7;
      const int gsl = sl0 ^ (srow & 7);
      gload16(Ab + (size_t)srow * lda + kk + gsl * 8, &sAh[G * 8]);
    }
#pragma unroll
    for (int jj = 0; jj < 2; ++jj) {
      const int G = jj * 256 + tid;
      const int srow = G >> 3, sl0 = G & 7;
      const int gsl = sl0 ^ (srow & 7);
      gload16(Wb + (size_t)srow * ldw + kk + gsl * 8, &sBh[G * 8]);
    }
    __syncthreads();
#pragma unroll
    for (int ks = 0; ks < 2; ++ks) {
      f16x8 aH[4], bH[2];
#pragma unroll
      for (int m = 0; m < 4; ++m) {
        const int r = wr + m * 16 + lr;
        aH[m] = *(const f16x8*)&sAh[r * 64 + (((ks * 4 + sl) ^ (r & 7)) * 8)];
      }
#pragma unroll
      for (int n = 0; n < 2; ++n) {
        const int r = wc + n * 16 + lr;
        bH[n] = *(const f16x8*)&sBh[r * 64 + (((ks * 4 + sl) ^ (r & 7)) * 8)];
      }
#pragma unroll
      for (int m = 0; m < 4; ++m)
#pragma unroll
        for (int n = 0; n < 2; ++n)
          acc[m][n] = __builtin_amdgcn_mfma_f32_16x16x32_f16(aH[m], bH[n],
                                                             acc[m][n], 0, 0, 0);
    }
    __syncthreads();
  }
  const int r4 = sl * 4;
  float cs[2] = {0.f, 0.f};
#pragma unroll
  for (int m = 0; m < 4; ++m) {
#pragma unroll
    for (int r = 0; r < 4; ++r) {
      const int mm = bm + wr + m * 16 + r4 + r;
#pragma unroll
      for (int n = 0; n < 2; ++n) {
        const int col = bn + wc + n * 16 + lr;
        float v = acc[m][n][r] + bias[col];
        if (RELU) v = fmaxf(v, 0.f);
        if (RESM == 1) {
          const int rr = rmod ? (mm % rmod) : mm;
          v += resid[(size_t)rr * ldr + col];
        }
        if (RESM == 2) v += h2f(residS[(size_t)mm * ldr + col]);
        if (PACK) ph[(size_t)mm * ldp + col] = f16b(v);
        if (CSUM) cs[n] += v;
      }
    }
  }
  if constexpr (CSUM) {
#pragma unroll
    for (int n = 0; n < 2; ++n) {
      cs[n] += __shfl_xor(cs[n], 16, 64);
      cs[n] += __shfl_xor(cs[n], 32, 64);
    }
    if (sl == 0) {
      csLds[wave >> 1][wc + lr] = cs[0];
      csLds[wave >> 1][wc + 16 + lr] = cs[1];
    }
    __syncthreads();
    if (tid < 64)
      part[(size_t)bmt * 512 + bn + tid] = csLds[0][tid] + csLds[1][tid];
  }
}

// =========================================================================
// Conv z-pair with center-merged weights; f16 partial output.
// (unchanged from round 10: 66.6 us/layer, conflicts 0)
// =========================================================================
__global__ __launch_bounds__(256, 3) void conv_zp_k(
    const short* __restrict__ hp, const short* __restrict__ wt8,
    const short* __restrict__ wmix, const float* __restrict__ alpha,
    const short* __restrict__ zpadS, short* __restrict__ P) {
  __shared__ alignas(16) short sAh[8192], sBh[8192];
  const int tid = threadIdx.x;
  const unsigned lin = blockIdx.x;
  const unsigned swz = (lin & 7) * 96 + (lin >> 3);
  const int zp = (int)(swz / 384);
  const unsigned rem = swz % 384;
  const int bn = (int)(rem & 3) * 128;
  const int bmt = (int)(rem >> 2);
  const int b = bmt / 6, s0 = (bmt % 6) * 128, gm0 = bmt * 128;
  const int wave = tid >> 6, lane = tid & 63;
  const int wr = (wave >> 1) * 64, wc = (wave & 1) * 64;
  const int lr = lane & 15, sl = lane >> 4;
  const short* hb = hp + (size_t)b * S * 512;
  f32x4 accF[4][4] = {};
#pragma unroll
  for (int zi = 0; zi < 2; ++zi) {
    const int z = zp * 2 + zi;
    const int dd = 1 << z;
    f32x4 acc[4][4] = {};
    for (int kk = 0; kk < 1024; kk += 64) {
      const int tap = kk >> 9;  // 0: -d, 1: +d
      const int koff = kk & 511;
      const int off = tap ? dd : -dd;
#pragma unroll
      for (int jj = 0; jj < 4; ++jj) {
        const int G = jj * 256 + tid;
        const int srow = G >> 3, sl0 = G & 7;
        const int gsl = sl0 ^ (srow & 7);
        const int dst = G * 8;
        const int gs = s0 + srow + off;
        const bool inb = ((unsigned)gs < (unsigned)S);
        const short* aBase = hb + (size_t)gs * 512 + koff + gsl * 8;
        gload16(inb ? aBase : zpadS, &sAh[dst]);
        gload16(wt8 + ((size_t)((z * 2 + tap) * 512 + bn + srow)) * 512 +
                    koff + gsl * 8,
                &sBh[dst]);
      }
      __syncthreads();
#pragma unroll
      for (int ks = 0; ks < 2; ++ks) {
        f16x8 aH[4], bH[4];
#pragma unroll
        for (int m = 0; m < 4; ++m) {
          const int r = wr + m * 16 + lr;
          aH[m] =
              *(const f16x8*)&sAh[r * 64 + (((ks * 4 + sl) ^ (r & 7)) * 8)];
        }
#pragma unroll
        for (int n = 0; n < 4; ++n) {
          const int r = wc + n * 16 + lr;
          bH[n] =
              *(const f16x8*)&sBh[r * 64 + (((ks * 4 + sl) ^ (r & 7)) * 8)];
        }
#pragma unroll
        for (int m = 0; m < 4; ++m)
#pragma unroll
          for (int n = 0; n < 4; ++n)
            acc[m][n] = __builtin_amdgcn_mfma_f32_16x16x32_f16(
                aH[m], bH[n], acc[m][n], 0, 0, 0);
      }
      __syncthreads();
    }
    const float al = alpha[b * 4 + z];
#pragma unroll
    for (int m = 0; m < 4; ++m)
#pragma unroll
      for (int n = 0; n < 4; ++n)
#pragma unroll
        for (int r = 0; r < 4; ++r) accF[m][n][r] += al * acc[m][n][r];
  }
  // merged-center K-half (alpha baked into W_mix)
  const short* Wm = wmix + (size_t)b * 512 * 512;
  for (int kc = 0; kc < 256; kc += 64) {
    const int koff = zp * 256 + kc;
#pragma unroll
    for (int jj = 0; jj < 4; ++jj) {
      const int G = jj * 256 + tid;
      const int srow = G >> 3, sl0 = G & 7;
      const int gsl = sl0 ^ (srow & 7);
      const int dst = G * 8;
      gload16(hb + (size_t)(s0 + srow) * 512 + koff + gsl * 8, &sAh[dst]);
      gload16(Wm + (size_t)(bn + srow) * 512 + koff + gsl * 8, &sBh[dst]);
    }
    __syncthreads();
#pragma unroll
    for (int ks = 0; ks < 2; ++ks) {
      f16x8 aH[4], bH[4];
#pragma unroll
      for (int m = 0; m < 4; ++m) {
        const int r = wr + m * 16 + lr;
        aH[m] = *(const f16x8*)&sAh[r * 64 + (((ks * 4 + sl) ^ (r & 7)) * 8)];
      }
#pragma unroll
      for (int n = 0; n < 4; ++n) {
        const int r = wc + n * 16 + lr;
        bH[n] = *(const f16x8*)&sBh[r * 64 + (((ks * 4 + sl) ^ (r & 7)) * 8)];
      }
#pragma unroll
      for (int m = 0; m < 4; ++m)
#pragma unroll
        for (int n = 0; n < 4; ++n)
          accF[m][n] = __builtin_amdgcn_mfma_f32_16x16x32_f16(
              aH[m], bH[n], accF[m][n], 0, 0, 0);
    }
    __syncthreads();
  }
  short* Pz = P + (size_t)zp * ((size_t)BS * D);
  const int r4 = sl * 4;
#pragma unroll
  for (int m = 0; m < 4; ++m)
#pragma unroll
    for (int r = 0; r < 4; ++r) {
      const int mm = gm0 + wr + m * 16 + r4 + r;
#pragma unroll
      for (int n = 0; n < 4; ++n)
        Pz[(size_t)mm * D + bn + wc + n * 16 + lr] = f16b(accF[m][n][r]);
    }
}

// ---- fused conv-combine + LN1 -> LN2, all-f16 state ----------------------
// v = P0+P1+h(f16)+cb_mix[b]; h2 = LN2(LN1(v)) -> hi-pack (in-place w/ hpk:
// per-lane same-address read-before-write, safe).
__global__ __launch_bounds__(256) void ln3_k(
    const short* __restrict__ P0, const short* __restrict__ P1,
    const short* __restrict__ hpk, const float* __restrict__ cbmix,
    const float* __restrict__ g1, const float* __restrict__ b1,
    const float* __restrict__ g2, const float* __restrict__ b2,
    short* __restrict__ pout) {
  const int row = blockIdx.x * 4 + (threadIdx.x >> 6);
  const int lane = threadIdx.x & 63;
  const int bb = row / S;
  const size_t base = (size_t)row * D;
  float v[8];
  float s = 0.f;
#pragma unroll
  for (int j = 0; j < 8; ++j) {
    const int c = lane + 64 * j;
    v[j] = h2f(P0[base + c]) + h2f(P1[base + c]) + h2f(hpk[base + c]) +
           cbmix[(size_t)bb * D + c];
    s += v[j];
  }
  s = wave_sum(s);
  const float m1 = s * (1.f / D);
  float q = 0.f;
#pragma unroll
  for (int j = 0; j < 8; ++j) { const float d = v[j] - m1; q += d * d; }
  q = wave_sum(q);
  const float r1 = rsqrtf(q * (1.f / D) + EPS);
  float y[8];
  float s2 = 0.f;
#pragma unroll
  for (int j = 0; j < 8; ++j) {
    const int c = lane + 64 * j;
    y[j] = (v[j] - m1) * r1 * g1[c] + b1[c];
    s2 += y[j];
  }
  s2 = wave_sum(s2);
  const float m2 = s2 * (1.f / D);
  float q2 = 0.f;
#pragma unroll
  for (int j = 0; j < 8; ++j) { const float d = y[j] - m2; q2 += d * d; }
  q2 = wave_sum(q2);
  const float r2 = rsqrtf(q2 * (1.f / D) + EPS);
  short* prow = pout + base;
#pragma unroll
  for (int j = 0; j < 8; ++j) {
    const int c = lane + 64 * j;
    prow[c] = f16b((y[j] - m2) * r2 * g2[c] + b2[c]);
  }
}

// ---- W transpose-pack via LDS: (K,N) f32 -> (N,K) fp16, both coalesced ---
__global__ __launch_bounds__(256) void pack_wt_k(const float* __restrict__ W,
                                                 short* __restrict__ out,
                                                 int K, int N) {
  __shared__ short t[64][68];
  const int n0 = blockIdx.x * 64, k0 = blockIdx.y * 64;
  const int ln = threadIdx.x & 63, w4 = threadIdx.x >> 6;
#pragma unroll
  for (int it = 0; it < 16; ++it) {
    const int kr = it * 4 + w4;
    t[kr][ln] = f16b(W[(size_t)(k0 + kr) * N + n0 + ln]);
  }
  __syncthreads();
#pragma unroll
  for (int it = 0; it < 16; ++it) {
    const int nr = it * 4 + w4;
    out[(size_t)(n0 + nr) * K + k0 + ln] = t[ln][nr];
  }
}

// ---- merged conv-weight prep: side-tap pack (8192 blocks) + W_mix (1024) -
__global__ __launch_bounds__(256) void convprep_k(
    const float* __restrict__ cw, const float* __restrict__ alpha,
    short* __restrict__ out8, short* __restrict__ wm) {
  const int bid = blockIdx.x;
  if (bid < 8192) {
    const int idx = bid * 256 + threadIdx.x;  // 8*512*512
    const int c = idx & 511, o = (idx >> 9) & 511, seg = idx >> 18;  // 0..7
    const int z = seg >> 1, t = (seg & 1) * 2;
    out8[((size_t)seg * D + o) * D + c] =
        f16b(cw[(((size_t)z * D + o) * D + c) * 3 + t]);
  } else {
    __shared__ float sal[64];
    if (threadIdx.x < 64) sal[threadIdx.x] = alpha[threadIdx.x];
    __syncthreads();
    const int idx = (bid - 8192) * 256 + threadIdx.x;  // 262144 (o,c)
    const int c = idx & 511, o = idx >> 9;
    float w[4];
#pragma unroll
    for (int z = 0; z < 4; ++z)
      w[z] = cw[(((size_t)z * D + o) * D + c) * 3 + 1];
#pragma unroll
    for (int b = 0; b < 16; ++b) {
      const float v = sal[b * 4 + 0] * w[0] + sal[b * 4 + 1] * w[1] +
                      sal[b * 4 + 2] * w[2] + sal[b * 4 + 3] * w[3];
      wm[((size_t)b * D + o) * D + c] = f16b(v);
    }
  }
}

__global__ __launch_bounds__(256) void zero_k(float* __restrict__ p) {
  p[threadIdx.x] = 0.f;
  p[threadIdx.x + 256] = 0.f;
}

// ---- alpha from GEMM-emitted column partials; cb_mix[b] = sum a_z cb_z ---
__global__ __launch_bounds__(64) void alpha_k(const float* __restrict__ part,
                                              const float* __restrict__ wmw,
                                              const float* __restrict__ wmb,
                                              const float* __restrict__ cb,
                                              float* __restrict__ alpha,
                                              float* __restrict__ cbmix) {
  const int b = blockIdx.x, t = threadIdx.x;
  float p0 = 0, p1 = 0, p2 = 0, p3 = 0;
  for (int d = t; d < D; d += 64) {
    float xm = 0;
#pragma unroll
    for (int c = 0; c < 6; ++c) xm += part[((size_t)(b * 6 + c)) * D + d];
    xm *= (1.f / S);
    p0 += xm * wmw[d * 4 + 0];
    p1 += xm * wmw[d * 4 + 1];
    p2 += xm * wmw[d * 4 + 2];
    p3 += xm * wmw[d * 4 + 3];
  }
  p0 = wave_sum(p0); p1 = wave_sum(p1);
  p2 = wave_sum(p2); p3 = wave_sum(p3);
  const float l0 = p0 + wmb[0], l1 = p1 + wmb[1];
  const float l2 = p2 + wmb[2], l3 = p3 + wmb[3];
  const float mx = fmaxf(fmaxf(l0, l1), fmaxf(l2, l3));
  const float e0 = expf(l0 - mx), e1 = expf(l1 - mx);
  const float e2 = expf(l2 - mx), e3 = expf(l3 - mx);
  const float inv = 1.f / (e0 + e1 + e2 + e3);
  const float a0 = e0 * inv, a1 = e1 * inv, a2 = e2 * inv, a3 = e3 * inv;
  if (t == 0) {
    alpha[b * 4 + 0] = a0;
    alpha[b * 4 + 1] = a1;
    alpha[b * 4 + 2] = a2;
    alpha[b * 4 + 3] = a3;
  }
  for (int c = t; c < D; c += 64)
    cbmix[(size_t)b * D + c] =
        a0 * cb[c] + a1 * cb[D + c] + a2 * cb[2 * D + c] + a3 * cb[3 * D + c];
}

// ---- embedding gather-mean, hi-pack out ----------------------------------
__global__ __launch_bounds__(256) void embed_k(const int* __restrict__ xe,
                                               const float* __restrict__ emb,
                                               short* __restrict__ out) {
  const int r = blockIdx.x;
  int idx[8];
#pragma unroll
  for (int j = 0; j < 8; ++j) idx[j] = xe[r * 8 + j];
  short* o = out + (size_t)r * 512;
  for (int d = threadIdx.x; d < D; d += 256) {
    float s = 0.f;
#pragma unroll
    for (int j = 0; j < 8; ++j) s += emb[(size_t)idx[j] * D + d];
    o[d] = f16b(s * 0.125f);
  }
}

// ---- L2-normalize rows of (BS,64), hi-pack out ---------------------------
__global__ __launch_bounds__(256) void norml2_k(const float* __restrict__ x,
                                                short* __restrict__ out) {
  const int r = blockIdx.x * 4 + (threadIdx.x >> 6);
  const int lane = threadIdx.x & 63;
  const float v = x[(size_t)r * 64 + lane];
  const float s = wave_sum(v * v);
  const float nrm = fmaxf(sqrtf(s), 1e-12f);
  out[(size_t)r * 64 + lane] = f16b(v / nrm);
}

// ---- classifier head (reads GEMM column partials) ------------------------
__global__ __launch_bounds__(256) void head_k(
    const float* __restrict__ part, const float* __restrict__ pw1,
    const float* __restrict__ pb1, const float* __restrict__ pw2,
    const float* __restrict__ pb2, float* __restrict__ out) {
  __shared__ float hg[D];
  __shared__ float red[256];
  const int b = blockIdx.x, t = threadIdx.x;
  for (int d = t; d < D; d += 256) {
    float s = 0.f;
#pragma unroll
    for (int c = 0; c < 6; ++c) s += part[((size_t)(b * 6 + c)) * D + d];
    hg[d] = s * (1.f / S);
  }
  __syncthreads();
  float s = pb1[t];
  for (int d = 0; d < D; ++d) s = fmaf(hg[d], pw1[(size_t)d * 256 + t], s);
  s = fmaxf(s, 0.f);
  red[t] = s * pw2[t];
  __syncthreads();
  for (int o = 128; o > 0; o >>= 1) {
    if (t < o) red[t] += red[t + o];
    __syncthreads();
  }
  if (t == 0) out[b] = red[0] + pb2[0];
}

}  // namespace

extern "C" void kernel_launch(void* const* d_in, const int* in_sizes, int n_in,
                              void* d_out, int out_size, void* d_ws,
                              size_t ws_size, hipStream_t stream) {
  const float* x_cog = (const float*)d_in[0];
  const float* cw1 = (const float*)d_in[1];
  const float* cb1 = (const float*)d_in[2];
  const float* cw2 = (const float*)d_in[3];
  const float* cb2 = (const float*)d_in[4];
  const float* env_emb = (const float*)d_in[5];
  const float* ew1 = (const float*)d_in[6];
  const float* eb1 = (const float*)d_in[7];
  const float* ew2 = (const float*)d_in[8];
  const float* eb2 = (const float*)d_in[9];
  const float* fw1 = (const float*)d_in[10];
  const float* fb1 = (const float*)d_in[11];
  const float* fw2 = (const float*)d_in[12];
  const float* fb2 = (const float*)d_in[13];
  const float* pos_enc = (const float*)d_in[14];
  const float* conv_w = (const float*)d_in[15];
  const float* conv_b = (const float*)d_in[16];
  const float* wm_w = (const float*)d_in[17];
  const float* wm_b = (const float*)d_in[18];
  // d_in[19..21] = ssm_w/ssm_b/A_log: no-ops (y scalar-per-row cancels in LN2)
  const float* ffw1 = (const float*)d_in[22];
  const float* ffb1 = (const float*)d_in[23];
  const float* ffw2 = (const float*)d_in[24];
  const float* ffb2 = (const float*)d_in[25];
  const float* g1 = (const float*)d_in[26];
  const float* be1 = (const float*)d_in[27];
  const float* g2 = (const float*)d_in[28];
  const float* be2 = (const float*)d_in[29];
  const float* pw1 = (const float*)d_in[30];
  const float* pb1 = (const float*)d_in[31];
  const float* pw2 = (const float*)d_in[32];
  const float* pb2 = (const float*)d_in[33];
  const int* x_env = (const int*)d_in[34];
  float* out = (float*)d_out;

  // ---- arena (~79 MB) -----------------------------------------------------
  float* ws = (float*)d_ws;
  float* PART2 = ws;                       // 96x512 f32 (col partials)
  float* ALPHAB = PART2 + 65536;           // 64
  float* ZPADF = ALPHAB + 64;              // 512 zero page
  float* CBMIX = ZPADF + 512;              // 16x512 f32
  short* R = (short*)(CBMIX + 8192);
  // layer regions (shorts):
  short* WCONV8 = R;                       // 8x512x512    [0, 2,097,152)
  short* WFFP = R + 2097152;               // 2048x512     [2,097,152, 3,145,728)
  short* WMIX = R + 3145728;               // 16x512x512   [3,145,728, 7,340,032)
  short* convPh = R + 7340032;             // 2x12288x512  [7,340,032, 19,922,944)
  short* APFF = R + 7340032;               // 12288x2048   [7,340,032, 32,505,856)
  short* HPACK = R + 32505856;             // 12288x512    [32,505,856, 38,797,312)
  // frontend regions (alias layer regions, dead once layers start):
  short* CONC = R;                         // 12288x2048   [0, 25,165,824)
  short* PK1 = R + 25165824;               // 12288x512    [25,165,824, 31,457,280)
  short* PK2 = R + 31457280;               // 12288x512    [31,457,280, 37,748,736)
  //   PK2 overlaps HPACK tail but is dead (last read: ew2-GEMM) before HPACK
  //   is first written (frontend-final GEMM). Liveness-checked.
  short* WPBF = R + 38797312;              // frontend W pack [38,797,312, 39,321,600)
  //   NOTE: dedicated slot OUTSIDE CONC — fixes round-9/10 latent aliasing.

  const dim3 blk(256);
  const dim3 gS(8, 96, 1);    // N=512, BN=64 -> 768 blocks (3/CU)
  const dim3 gF(16, 96, 1);   // N=2048, BN=128 -> 1536 blocks

  zero_k<<<1, blk, 0, stream>>>(ZPADF);

  // ---- frontend -----------------------------------------------------------
  norml2_k<<<BS / 4, blk, 0, stream>>>(x_cog, PK1);
  pack_wt_k<<<dim3(8, 1), blk, 0, stream>>>(cw1, WPBF, 64, 512);
  gemm_h64<true, 0, true, false><<<gS, blk, 0, stream>>>(
      PK1, 64, WPBF, 64, 64, cb1, nullptr, nullptr, 0, 0, PK2, 512, nullptr);
  pack_wt_k<<<dim3(8, 8), blk, 0, stream>>>(cw2, WPBF, 512, 512);
  gemm_h64<false, 0, true, false><<<gS, blk, 0, stream>>>(
      PK2, 512, WPBF, 512, 512, cb2, nullptr, nullptr, 0, 0, CONC, 2048,
      nullptr);
  embed_k<<<BS, blk, 0, stream>>>(x_env, env_emb, PK1);
  pack_wt_k<<<dim3(8, 8), blk, 0, stream>>>(ew1, WPBF, 512, 512);
  gemm_h64<true, 0, true, false><<<gS, blk, 0, stream>>>(
      PK1, 512, WPBF, 512, 512, eb1, nullptr, nullptr, 0, 0, PK2, 512,
      nullptr);
  pack_wt_k<<<dim3(8, 8), blk, 0, stream>>>(ew2, WPBF, 512, 512);
  gemm_h64<false, 0, true, false><<<gS, blk, 0, stream>>>(
      PK2, 512, WPBF, 512, 512, eb2, nullptr, nullptr, 0, 0, CONC + 512, 2048,
      nullptr);
  pack_wt_k<<<dim3(8, 16), blk, 0, stream>>>(fw1, WPBF, 1024, 512);
  gemm_h64<true, 0, true, false><<<gS, blk, 0, stream>>>(
      CONC, 2048, WPBF, 1024, 1024, fb1, nullptr, nullptr, 0, 0, PK1, 512,
      nullptr);
  pack_wt_k<<<dim3(8, 8), blk, 0, stream>>>(fw2, WPBF, 512, 512);
  // h = (PK1@fw2 + fb2) + pos_enc -> HPACK hi + PART2 colsums (f32-accurate)
  gemm_h64<false, 1, true, true><<<gS, blk, 0, stream>>>(
      PK1, 512, WPBF, 512, 512, fb2, pos_enc, nullptr, 512, S, HPACK, 512,
      PART2);

  // ---- layers (all-f16 state) --------------------------------------------
  for (int l = 0; l < L; ++l) {
    const float* cwl = conv_w + (size_t)l * 4 * D * D * 3;
    alpha_k<<<B, dim3(64), 0, stream>>>(PART2, wm_w + (size_t)l * D * 4,
                                        wm_b + l * 4,
                                        conv_b + (size_t)l * 4 * D, ALPHAB,
                                        CBMIX);
    convprep_k<<<9216, blk, 0, stream>>>(cwl, ALPHAB, WCONV8, WMIX);
    conv_zp_k<<<768, blk, 0, stream>>>(HPACK, WCONV8, WMIX, ALPHAB,
                                       (const short*)ZPADF, convPh);
    // h2 = LN2(LN1(P0+P1+h+cb_mix)) -> HPACK (in-place h -> h2)
    ln3_k<<<BS / 4, blk, 0, stream>>>(convPh, convPh + (size_t)BS * D, HPACK,
                                      CBMIX, g1 + l * D, be1 + l * D,
                                      g2 + l * D, be2 + l * D, HPACK);
    pack_wt_k<<<dim3(32, 8), blk, 0, stream>>>(ffw1 + (size_t)l * D * FF,
                                               WFFP, 512, 2048);
    gemm_h<true, true><<<gF, blk, 0, stream>>>(HPACK, 512, WFFP, 512, 512,
                                               ffb1 + (size_t)l * FF, APFF,
                                               2048);
    pack_wt_k<<<dim3(8, 32), blk, 0, stream>>>(ffw2 + (size_t)l * FF * D,
                                               WFFP, 2048, 512);
    // new h = APFF@ffw2 + ffb2 + h2(f16) -> HPACK (in-place) + PART2 colsums
    gemm_h64<false, 2, true, true><<<gS, blk, 0, stream>>>(
        APFF, 2048, WFFP, 2048, 2048, ffb2 + (size_t)l * D, nullptr, HPACK,
        512, 0, HPACK, 512, PART2);
  }

  // ---- head ---------------------------------------------------------------
  head_k<<<B, blk, 0, stream>>>(PART2, pw1, pb1, pw2, pb2, out);
}